// Round 4
// baseline (556.027 us; speedup 1.0000x reference)
//
#include <hip/hip_runtime.h>
#include <cstdint>
#include <cstddef>

#define VAR0_ 0.1f
#define VAR1_ 0.2f
#define KTOP_ 5
#define T1_ 0.35f
#define T2_ 0.5f
#define ALPHA_ 0.25f
#define BETA_ 0.11f
#define BS 256

__device__ __forceinline__ float sl1(float d) {
    float x = fabsf(d);
    return (x >= BETA_) ? (x - 0.5f * BETA_) : (0.5f * x * x / BETA_);
}

// ---------------- K0: zero candidate counters (tiny) ----------------
__global__ void k_init(int* __restrict__ cand_cnt, int nCnt) {
    int i = blockIdx.x * blockDim.x + threadIdx.x;
    if (i < nCnt) cand_cnt[i] = 0;
}

// ---------------- K1: per-prior column maxes + decode + candidate harvest ----------------
// Divide-free max tracking: a/b > c/d  <=>  a*d > c*b  (b,d > 0).
// Merged stage-1/stage-2 n-loop: shared truth reads, two independent IoU chains.
template <int NT>
__global__ void k_per_prior(const float4* __restrict__ loc4, const float4* __restrict__ priors4,
                            const float* __restrict__ targets,
                            float* __restrict__ bt_score, float* __restrict__ cb_score,
                            int* __restrict__ btcb_idx, float* __restrict__ c_score,
                            float* __restrict__ cand_v, int* __restrict__ cand_i,
                            int* __restrict__ cand_cnt,
                            int P, int Nrt, int CAP) {
    const int N = (NT > 0) ? NT : Nrt;
    int b = blockIdx.y;
    int i = blockIdx.x * blockDim.x + threadIdx.x;
    __shared__ float4 tr4[64];
    __shared__ float trA[64];
    for (int t = threadIdx.x; t < N; t += blockDim.x) {
        float x1 = targets[(size_t)(b * N + t) * 5 + 0];
        float y1 = targets[(size_t)(b * N + t) * 5 + 1];
        float x2 = targets[(size_t)(b * N + t) * 5 + 2];
        float y2 = targets[(size_t)(b * N + t) * 5 + 3];
        tr4[t] = make_float4(x1, y1, x2, y2);
        trA[t] = (x2 - x1) * (y2 - y1);
    }
    __syncthreads();
    if (i >= P) return;

    float4 pr = priors4[i];
    size_t bp = (size_t)b * P + i;
    float4 lc = loc4[bp];

    float pcx = pr.x, pcy = pr.y, pw = pr.z, ph = pr.w;
    float px1 = pcx - pw * 0.5f, py1 = pcy - ph * 0.5f;
    float px2 = pcx + pw * 0.5f, py2 = pcy + ph * 0.5f;
    float pa = (px2 - px1) * (py2 - py1);

    // decode(loc, prior)
    float dcx = pcx + lc.x * VAR0_ * pw;
    float dcy = pcy + lc.y * VAR0_ * ph;
    float dw = pw * expf(lc.z * VAR1_);
    float dh = ph * expf(lc.w * VAR1_);
    float dx1 = dcx - dw * 0.5f, dy1 = dcy - dh * 0.5f;
    float dx2 = dcx + dw * 0.5f, dy2 = dcy + dh * 0.5f;
    float da = (dx2 - dx1) * (dy2 - dy1);

    float b_i = -1.f, b_u = 1.f; int bn = 0;
    float c_i = -1.f, c_u = 1.f; int cn = 0;
#pragma unroll
    for (int n = 0; n < N; n++) {
        float4 t4 = tr4[n];
        float ta = trA[n];
        // stage-1: IoU(truth, prior_pt)
        float lx1 = fmaxf(t4.x, px1), ly1 = fmaxf(t4.y, py1);
        float rx1 = fminf(t4.z, px2), ry1 = fminf(t4.w, py2);
        float w1 = fmaxf(rx1 - lx1, 0.f), h1 = fmaxf(ry1 - ly1, 0.f);
        float inter1 = w1 * h1;
        float uni1 = ta + pa - inter1;
        bool bet1 = inter1 * b_u > b_i * uni1;
        b_i = bet1 ? inter1 : b_i; b_u = bet1 ? uni1 : b_u; bn = bet1 ? n : bn;
        // stage-2: IoU(truth, decoded)
        float lx2 = fmaxf(t4.x, dx1), ly2 = fmaxf(t4.y, dy1);
        float rx2 = fminf(t4.z, dx2), ry2 = fminf(t4.w, dy2);
        float w2 = fmaxf(rx2 - lx2, 0.f), h2 = fmaxf(ry2 - ly2, 0.f);
        float inter2 = w2 * h2;
        float uni2 = ta + da - inter2;
        bool bet2 = inter2 * c_u > c_i * uni2;
        c_i = bet2 ? inter2 : c_i; c_u = bet2 ? uni2 : c_u; cn = bet2 ? n : cn;
        if (inter2 >= uni2 * 0.4999990f) {  // conservative pre-test; exact test below
            float v = inter2 / uni2;
            if (v >= T2_) {
                int pos = atomicAdd(&cand_cnt[b * N + n], 1);
                if (pos < CAP) {
                    size_t o = (size_t)(b * N + n) * CAP + pos;
                    cand_v[o] = v; cand_i[o] = i;
                }
            }
        }
    }
    bt_score[bp] = b_i / b_u;
    cb_score[bp] = c_i / c_u;
    btcb_idx[bp] = bn | (cn << 16);
    c_score[bp] = 0.f;
}

// ---------------- K1b: per-(b,n) row max/argmax over all priors ----------------
__global__ void k_row_max(const float4* __restrict__ priors4, const float* __restrict__ targets,
                          float* __restrict__ row_max, int* __restrict__ row_arg,
                          int P, int N) {
    int n = blockIdx.x, b = blockIdx.y;
    float tx1 = targets[(size_t)(b * N + n) * 5 + 0];
    float ty1 = targets[(size_t)(b * N + n) * 5 + 1];
    float tx2 = targets[(size_t)(b * N + n) * 5 + 2];
    float ty2 = targets[(size_t)(b * N + n) * 5 + 3];
    float ta = (tx2 - tx1) * (ty2 - ty1);
    float b_i = -1.f, b_u = 1.f; int bi = 0x7fffffff;
    for (int i = threadIdx.x; i < P; i += blockDim.x) {
        float4 pr = priors4[i];
        float px1 = pr.x - pr.z * 0.5f, py1 = pr.y - pr.w * 0.5f;
        float px2 = pr.x + pr.z * 0.5f, py2 = pr.y + pr.w * 0.5f;
        float lx = fmaxf(tx1, px1), ly = fmaxf(ty1, py1);
        float rx = fminf(tx2, px2), ry = fminf(ty2, py2);
        float w = fmaxf(rx - lx, 0.f), h = fmaxf(ry - ly, 0.f);
        float inter = w * h;
        float uni = ta + (px2 - px1) * (py2 - py1) - inter;
        bool better = inter * b_u > b_i * uni;  // strict >, increasing i -> smallest idx kept
        b_i = better ? inter : b_i; b_u = better ? uni : b_u; bi = better ? i : bi;
    }
    float bv = b_i / b_u;  // one divide; reduce on rounded values (ref semantics)
    int tid = threadIdx.x;
    int lane = tid & 63, wid = tid >> 6;
    // wave-level shuffle reduce: (value desc, idx asc)
#pragma unroll
    for (int off = 32; off > 0; off >>= 1) {
        float ov = __shfl_xor(bv, off);
        int oi = __shfl_xor(bi, off);
        if (ov > bv || (ov == bv && oi < bi)) { bv = ov; bi = oi; }
    }
    __shared__ float swv[BS / 64];
    __shared__ int swi[BS / 64];
    if (lane == 0) { swv[wid] = bv; swi[wid] = bi; }
    __syncthreads();
    if (tid == 0) {
        float fv = swv[0]; int fi = swi[0];
        for (int wv = 1; wv < BS / 64; wv++) {
            if (swv[wv] > fv || (swv[wv] == fv && swi[wv] < fi)) { fv = swv[wv]; fi = swi[wv]; }
        }
        row_max[b * N + n] = fv; row_arg[b * N + n] = fi;
    }
}

// ---------------- K2: greedy bipartite matching — ONE WAVE per image, register rows ----------------
__global__ void k_greedy(const float4* __restrict__ priors4, const float* __restrict__ targets,
                         const float* __restrict__ row_max_in, const int* __restrict__ row_arg_in,
                         float* __restrict__ bt_score, int* __restrict__ btcb_idx,
                         int P, int N) {
    int b = blockIdx.x;
    int lane = threadIdx.x;  // block == 1 wave of 64
    extern __shared__ unsigned int mask[];
    int maskWords = (P + 31) >> 5;
    for (int w = lane; w < maskWords; w += 64) mask[w] = 0u;

    float rmax = -2.f; int rarg = 0x7fffffff; int alive = 0;
    float tx1 = 0.f, ty1 = 0.f, tx2 = 0.f, ty2 = 0.f, ta = 0.f;
    if (lane < N) {
        rmax = row_max_in[b * N + lane];
        rarg = row_arg_in[b * N + lane];
        alive = 1;
        tx1 = targets[(size_t)(b * N + lane) * 5 + 0];
        ty1 = targets[(size_t)(b * N + lane) * 5 + 1];
        tx2 = targets[(size_t)(b * N + lane) * 5 + 2];
        ty2 = targets[(size_t)(b * N + lane) * 5 + 3];
        ta = (tx2 - tx1) * (ty2 - ty1);
    }
    __syncthreads();

    for (int it = 0; it < N; it++) {
        float v = (lane < N && alive) ? rmax : -3.f;
        int idx = lane;
#pragma unroll
        for (int off = 32; off > 0; off >>= 1) {
            float ov = __shfl_xor(v, off);
            int oi = __shfl_xor(idx, off);
            if (ov > v || (ov == v && oi < idx)) { v = ov; idx = oi; }
        }
        int bj = idx;
        float bv = v;
        int sel = __shfl(rarg, bj);
        if (lane == bj) alive = 0;
        if (lane == 0) {
            size_t bpsel = (size_t)b * P + sel;
            bt_score[bpsel] = bv;
            int wrd = btcb_idx[bpsel];
            btcb_idx[bpsel] = (wrd & ~0xFFFF) | bj;
            mask[sel >> 5] |= (1u << (sel & 31));
        }
        __syncthreads();

        unsigned long long coll = __ballot(lane < N && alive && rarg == sel);
        while (coll) {
            int r = __ffsll((long long)coll) - 1;
            coll &= coll - 1;
            float rx1 = __shfl(tx1, r), ry1 = __shfl(ty1, r);
            float rx2 = __shfl(tx2, r), ry2 = __shfl(ty2, r);
            float ra = __shfl(ta, r);
            float n_i = -2.f, n_u = 1.f; int ni = 0x7fffffff;
            for (int i = lane; i < P; i += 64) {
                if (mask[i >> 5] & (1u << (i & 31))) continue;
                float4 pr = priors4[i];
                float px1 = pr.x - pr.z * 0.5f, py1 = pr.y - pr.w * 0.5f;
                float px2 = pr.x + pr.z * 0.5f, py2 = pr.y + pr.w * 0.5f;
                float lx = fmaxf(rx1, px1), ly = fmaxf(ry1, py1);
                float rx = fminf(rx2, px2), ry = fminf(ry2, py2);
                float w = fmaxf(rx - lx, 0.f), h = fmaxf(ry - ly, 0.f);
                float inter = w * h;
                float uni = ra + (px2 - px1) * (py2 - py1) - inter;
                bool better = inter * n_u > n_i * uni;
                n_i = better ? inter : n_i; n_u = better ? uni : n_u; ni = better ? i : ni;
            }
            float nv = n_i / n_u;
#pragma unroll
            for (int off = 32; off > 0; off >>= 1) {
                float ov = __shfl_xor(nv, off);
                int oi = __shfl_xor(ni, off);
                if (ov > nv || (ov == nv && oi < ni)) { nv = ov; ni = oi; }
            }
            if (lane == r) { rmax = nv; rarg = ni; }
        }
        __syncthreads();
    }
}

// ---------------- K3: per-(b,n) top-5 of thresholded c_iou (lax.top_k semantics) ----------------
__global__ void k_topk(const float4* __restrict__ loc4, const float4* __restrict__ priors4,
                       const float* __restrict__ targets,
                       const float* __restrict__ cand_v, const int* __restrict__ cand_i,
                       const int* __restrict__ cand_cnt,
                       float* __restrict__ tk_s, int* __restrict__ tk_i,
                       int P, int N, int CAP) {
    int n = blockIdx.x, b = blockIdx.y;
    int row = b * N + n;
    int tid = threadIdx.x;

    float vals[KTOP_]; int ids[KTOP_];
#pragma unroll
    for (int k = 0; k < KTOP_; k++) { vals[k] = -1.f; ids[k] = 0x7fffffff; }

    int cnt = cand_cnt[row];
    if (cnt <= CAP) {
        for (int k = tid; k < cnt; k += blockDim.x) {
            float cv = cand_v[(size_t)row * CAP + k];
            int ci = cand_i[(size_t)row * CAP + k];
#pragma unroll
            for (int q = 0; q < KTOP_; q++) {
                bool better = (cv > vals[q]) || ((cv == vals[q]) && (ci < ids[q]));
                float tv = better ? cv : vals[q]; int ti = better ? ci : ids[q];
                cv = better ? vals[q] : cv; ci = better ? ids[q] : ci;
                vals[q] = tv; ids[q] = ti;
            }
        }
    } else {
        // deterministic fallback: full rescan of this row (overflowed candidate buffer)
        float tx1 = targets[(size_t)row * 5 + 0], ty1 = targets[(size_t)row * 5 + 1];
        float tx2 = targets[(size_t)row * 5 + 2], ty2 = targets[(size_t)row * 5 + 3];
        float ta = (tx2 - tx1) * (ty2 - ty1);
        for (int i = tid; i < P; i += blockDim.x) {
            float4 pr = priors4[i];
            size_t bp = (size_t)b * P + i;
            float4 lc = loc4[bp];
            float dcx = pr.x + lc.x * VAR0_ * pr.z;
            float dcy = pr.y + lc.y * VAR0_ * pr.w;
            float dw = pr.z * expf(lc.z * VAR1_);
            float dh = pr.w * expf(lc.w * VAR1_);
            float dx1 = dcx - dw * 0.5f, dy1 = dcy - dh * 0.5f;
            float dx2 = dcx + dw * 0.5f, dy2 = dcy + dh * 0.5f;
            float lx = fmaxf(tx1, dx1), ly = fmaxf(ty1, dy1);
            float rx = fminf(tx2, dx2), ry = fminf(ty2, dy2);
            float w = fmaxf(rx - lx, 0.f), h = fmaxf(ry - ly, 0.f);
            float inter = w * h;
            float uni = ta + (dx2 - dx1) * (dy2 - dy1) - inter;
            if (inter >= uni * 0.4999990f) {
                float v = inter / uni;
                if (v >= T2_) {
                    float cv = v; int ci = i;
#pragma unroll
                    for (int q = 0; q < KTOP_; q++) {
                        bool better = (cv > vals[q]) || ((cv == vals[q]) && (ci < ids[q]));
                        float tv = better ? cv : vals[q]; int ti = better ? ci : ids[q];
                        cv = better ? vals[q] : cv; ci = better ? ids[q] : ci;
                        vals[q] = tv; ids[q] = ti;
                    }
                }
            }
        }
    }

    __shared__ float mv[BS * KTOP_];
    __shared__ int mi[BS * KTOP_];
#pragma unroll
    for (int k = 0; k < KTOP_; k++) { mv[tid * KTOP_ + k] = vals[k]; mi[tid * KTOP_ + k] = ids[k]; }
    __syncthreads();
    for (int s = BS / 2; s > 0; s >>= 1) {
        if (tid < s) {
#pragma unroll
            for (int j = 0; j < KTOP_; j++) {
                float cv = mv[(tid + s) * KTOP_ + j];
                int ci = mi[(tid + s) * KTOP_ + j];
#pragma unroll
                for (int q = 0; q < KTOP_; q++) {
                    bool better = (cv > vals[q]) || ((cv == vals[q]) && (ci < ids[q]));
                    float tv = better ? cv : vals[q]; int ti = better ? ci : ids[q];
                    cv = better ? vals[q] : cv; ci = better ? ids[q] : ci;
                    vals[q] = tv; ids[q] = ti;
                }
            }
#pragma unroll
            for (int k = 0; k < KTOP_; k++) { mv[tid * KTOP_ + k] = vals[k]; mi[tid * KTOP_ + k] = ids[k]; }
        }
        __syncthreads();
    }
    if (tid == 0) {
#pragma unroll
        for (int k = 0; k < KTOP_; k++) {
            tk_s[(size_t)row * KTOP_ + k] = (vals[k] > 0.f) ? vals[k] : 0.f;
            tk_i[(size_t)row * KTOP_ + k] = (ids[k] == 0x7fffffff) ? 0 : ids[k];
        }
    }
}

// ---------------- K3b: assign loop, parallel last-writer-wins ----------------
__global__ void k_assign(const float* __restrict__ targets,
                         const float* __restrict__ tk_s, const int* __restrict__ tk_i,
                         const float* __restrict__ bt_score, const int* __restrict__ btcb_idx,
                         int* __restrict__ cb_idx2, float* __restrict__ c_score,
                         int P, int N) {
    int b = blockIdx.x;
    int tid = threadIdx.x;
    int T = N * KTOP_;  // 160
    __shared__ int sh_p[512];
    __shared__ float sh_s[512];
    __shared__ int sh_c[512];
    if (tid < T) {
        int i = tid / KTOP_, j = tid % KTOP_;
        int p = tk_i[(size_t)(b * N + i) * KTOP_ + j];
        float s = tk_s[(size_t)(b * N + i) * KTOP_ + j];
        size_t bp = (size_t)b * P + p;
        float bs = bt_score[bp];
        int bj = btcb_idx[bp] & 0xFFFF;
        float conf1 = (bs < T1_) ? 0.f : targets[(size_t)(b * N + bj) * 5 + 4];
        sh_p[tid] = p; sh_s[tid] = s;
        sh_c[tid] = (conf1 < 1.f && s > 0.f) ? 1 : 0;
    }
    __syncthreads();
    if (tid < T && sh_c[tid]) {
        int p = sh_p[tid];
        bool last = true;
        for (int t2 = tid + 1; t2 < T; t2++) {
            if (sh_c[t2] && sh_p[t2] == p) { last = false; break; }
        }
        if (last) {
            size_t bp = (size_t)b * P + p;
            cb_idx2[bp] = tid / KTOP_;
            c_score[bp] = sh_s[tid];
        }
    }
}

// ---------------- K4: per-element losses + block partial sums ----------------
__global__ void k_loss(const float4* __restrict__ loc4, const float* __restrict__ conf,
                       const float4* __restrict__ priors4, const float* __restrict__ targets,
                       const float* __restrict__ bt_score, const int* __restrict__ btcb_idx,
                       const float* __restrict__ cb_score, const int* __restrict__ cb_idx2,
                       const float* __restrict__ c_score,
                       double* __restrict__ partials,
                       int P, int N, int C) {
    int b = blockIdx.y;
    int i = blockIdx.x * blockDim.x + threadIdx.x;
    double l1 = 0.0, l2 = 0.0, f1 = 0.0, f2 = 0.0;
    int n1 = 0, n2 = 0;
    if (i < P) {
        size_t bp = (size_t)b * P + i;
        float bs = bt_score[bp];
        int widx = btcb_idx[bp];
        int bj = widx & 0xFFFF;
        float cbs = cb_score[bp]; float cs = c_score[bp];
        int cj = (cs > 0.f) ? cb_idx2[bp] : ((widx >> 16) & 0xFFFF);
        float lab1 = targets[(size_t)(b * N + bj) * 5 + 4];
        float conf1 = (bs < T1_) ? 0.f : lab1;
        if ((bs < T1_) && (cbs >= T2_) && (cs < T2_)) conf1 = -1.f;
        float lab2 = targets[(size_t)(b * N + cj) * 5 + 4];
        float conf2 = (cs < T2_) ? -1.f : lab2;
        bool m1 = conf1 > 0.f, m2 = conf2 > 0.f;
        n1 = m1 ? 1 : 0; n2 = m2 ? 1 : 0;

        float4 pr = priors4[i];
        float pcx = pr.x, pcy = pr.y, pw = pr.z, ph = pr.w;
        float4 lc = loc4[bp];
        float p0 = lc.x, p1 = lc.y, p2 = lc.z, p3 = lc.w;

        if (m1) {
            const float* tb = &targets[(size_t)(b * N + bj) * 5];
            float gx = ((tb[0] + tb[2]) * 0.5f - pcx) / (VAR0_ * pw);
            float gy = ((tb[1] + tb[3]) * 0.5f - pcy) / (VAR0_ * ph);
            float gw = logf((tb[2] - tb[0]) / pw) / VAR1_;
            float gh = logf((tb[3] - tb[1]) / ph) / VAR1_;
            l1 = (double)(sl1(p0 - gx) + sl1(p1 - gy) + sl1(p2 - gw) + sl1(p3 - gh));
        }
        if (m2) {
            const float* tb = &targets[(size_t)(b * N + cj) * 5];
            float gx = ((tb[0] + tb[2]) * 0.5f - pcx) / (VAR0_ * pw);
            float gy = ((tb[1] + tb[3]) * 0.5f - pcy) / (VAR0_ * ph);
            float gw = logf((tb[2] - tb[0]) / pw) / VAR1_;
            float gh = logf((tb[3] - tb[1]) / ph) / VAR1_;
            l2 = (double)(sl1(p0 - gx) + sl1(p1 - gy) + sl1(p2 - gw) + sl1(p3 - gh));
        }
        float x0, x1v;
        if (C == 2) {
            float2 cv2 = ((const float2*)conf)[bp];
            x0 = cv2.x; x1v = cv2.y;
        } else {
            x0 = conf[bp * C + 0]; x1v = conf[bp * C + 1];
        }
        {   // focal 1
            float t = fmaxf(conf1, 0.f);
            float keep = (conf1 >= 0.f) ? 1.f : 0.f;
            float x = (t >= 1.f) ? x1v : x0;
            float ce = fmaxf(x, 0.f) - x * t + log1pf(expf(-fabsf(x)));
            float a = t * ALPHA_ + (1.f - t) * (1.f - ALPHA_);
            float pr_ = 1.f / (1.f + expf(-x));
            float pt = (t == 1.f) ? pr_ : (1.f - pr_);
            float om = 1.f - pt;
            f1 = (double)(a * om * om * ce * keep);
        }
        {   // focal 2 (iou-weighted)
            float t = fmaxf(conf2, 0.f);
            float keep = (conf2 >= 0.f) ? 1.f : 0.f;
            float x = (t >= 1.f) ? x1v : x0;
            float ce = fmaxf(x, 0.f) - x * t + log1pf(expf(-fabsf(x)));
            float a = cs * (t * ALPHA_ + (1.f - t) * (1.f - ALPHA_));
            float pr_ = 1.f / (1.f + expf(-x));
            float pt = (t == 1.f) ? pr_ : (1.f - pr_);
            float om = 1.f - pt;
            f2 = (double)(a * om * om * ce * keep);
        }
    }
    // wave-level shuffle reduce, then one LDS merge across 4 waves
    int tid = threadIdx.x;
    int lane = tid & 63, wid = tid >> 6;
#pragma unroll
    for (int off = 32; off > 0; off >>= 1) {
        l1 += __shfl_xor(l1, off);
        l2 += __shfl_xor(l2, off);
        f1 += __shfl_xor(f1, off);
        f2 += __shfl_xor(f2, off);
        n1 += __shfl_xor(n1, off);
        n2 += __shfl_xor(n2, off);
    }
    __shared__ double swd[BS / 64][4];
    __shared__ int swn[BS / 64][2];
    if (lane == 0) {
        swd[wid][0] = l1; swd[wid][1] = l2; swd[wid][2] = f1; swd[wid][3] = f2;
        swn[wid][0] = n1; swn[wid][1] = n2;
    }
    __syncthreads();
    if (tid == 0) {
        double a0 = 0, a1 = 0, a2 = 0, a3 = 0; int b0 = 0, b1 = 0;
        for (int wv = 0; wv < BS / 64; wv++) {
            a0 += swd[wv][0]; a1 += swd[wv][1]; a2 += swd[wv][2]; a3 += swd[wv][3];
            b0 += swn[wv][0]; b1 += swn[wv][1];
        }
        int blk = blockIdx.y * gridDim.x + blockIdx.x;
        partials[(size_t)blk * 6 + 0] = a0;
        partials[(size_t)blk * 6 + 1] = a1;
        partials[(size_t)blk * 6 + 2] = a2;
        partials[(size_t)blk * 6 + 3] = a3;
        partials[(size_t)blk * 6 + 4] = (double)b0;
        partials[(size_t)blk * 6 + 5] = (double)b1;
    }
}

// ---------------- K5: final reduction + loss assembly ----------------
__global__ void k_final(const double* __restrict__ partials, int nPart, float* __restrict__ out) {
    int tid = threadIdx.x;
    double a[6] = {0, 0, 0, 0, 0, 0};
    for (int k = tid; k < nPart; k += BS) {
#pragma unroll
        for (int j = 0; j < 6; j++) a[j] += partials[(size_t)k * 6 + j];
    }
    __shared__ double sd[BS * 6];
#pragma unroll
    for (int j = 0; j < 6; j++) sd[tid * 6 + j] = a[j];
    __syncthreads();
    for (int s = BS / 2; s > 0; s >>= 1) {
        if (tid < s) {
#pragma unroll
            for (int j = 0; j < 6; j++) sd[tid * 6 + j] += sd[(tid + s) * 6 + j];
        }
        __syncthreads();
    }
    if (tid == 0) {
        double L1 = sd[0], L2 = sd[1], F1 = sd[2], F2 = sd[3], N1 = sd[4], N2 = sd[5];
        double l1v = L1 / fmax(N1, 1.0), l2v = L2 / fmax(N2, 1.0);
        double f1v = F1 / fmax(N1, 1.0), f2v = F2 / fmax(N2, 1.0);
        double locl = (N1 > 0 ? l1v : 0.0) + (N2 > 0 ? l2v : 0.0);
        double clsl = (N1 > 0 ? f1v : 0.0) + (N2 > 0 ? f2v : 0.0);
        if (N1 == 0 && N2 == 0) { locl = 1e-4; clsl = 1e-4; }
        out[0] = (float)locl;
        out[1] = (float)clsl;
    }
}

extern "C" void kernel_launch(void* const* d_in, const int* in_sizes, int n_in,
                              void* d_out, int out_size, void* d_ws, size_t ws_size,
                              hipStream_t stream) {
    const float* targets = (const float*)d_in[3];
    const float* conf = (const float*)d_in[1];
    const float4* loc4 = (const float4*)d_in[0];
    const float4* priors4 = (const float4*)d_in[2];

    int P = in_sizes[2] / 4;
    int B = in_sizes[0] / (P * 4);
    int N = in_sizes[3] / (B * 5);
    int C = in_sizes[1] / (B * P);
    const int CAP = 2048;
    size_t BP = (size_t)B * P;

    unsigned char* ws = (unsigned char*)d_ws;
    size_t off = 0;
    auto alloc = [&](size_t bytes) { size_t cur = off; off += (bytes + 255) & ~(size_t)255; return cur; };
    float* bt_score = (float*)(ws + alloc(BP * 4));
    float* cb_score = (float*)(ws + alloc(BP * 4));
    int* btcb_idx = (int*)(ws + alloc(BP * 4));
    int* cb_idx2 = (int*)(ws + alloc(BP * 4));
    float* c_score = (float*)(ws + alloc(BP * 4));
    float* row_max = (float*)(ws + alloc((size_t)B * N * 4));
    int* row_arg = (int*)(ws + alloc((size_t)B * N * 4));
    float* tk_s = (float*)(ws + alloc((size_t)B * N * KTOP_ * 4));
    int* tk_i = (int*)(ws + alloc((size_t)B * N * KTOP_ * 4));
    float* cand_v = (float*)(ws + alloc((size_t)B * N * CAP * 4));
    int* cand_i = (int*)(ws + alloc((size_t)B * N * CAP * 4));
    int* cand_cnt = (int*)(ws + alloc((size_t)B * N * 4));
    int bx = (P + BS - 1) / BS;
    double* partials = (double*)(ws + alloc((size_t)bx * B * 6 * 8));
    float* out = (float*)d_out;

    k_init<<<dim3((B * N + BS - 1) / BS), dim3(BS), 0, stream>>>(cand_cnt, B * N);
    dim3 g1(bx, B);
    if (N == 32) {
        k_per_prior<32><<<g1, BS, 0, stream>>>(loc4, priors4, targets, bt_score, cb_score,
                                               btcb_idx, c_score, cand_v, cand_i, cand_cnt,
                                               P, N, CAP);
    } else {
        k_per_prior<0><<<g1, BS, 0, stream>>>(loc4, priors4, targets, bt_score, cb_score,
                                              btcb_idx, c_score, cand_v, cand_i, cand_cnt,
                                              P, N, CAP);
    }
    k_row_max<<<dim3(N, B), BS, 0, stream>>>(priors4, targets, row_max, row_arg, P, N);
    int maskWords = (P + 31) / 32;
    size_t shmem = (size_t)maskWords * 4;
    k_greedy<<<dim3(B), 64, shmem, stream>>>(priors4, targets, row_max, row_arg,
                                             bt_score, btcb_idx, P, N);
    k_topk<<<dim3(N, B), BS, 0, stream>>>(loc4, priors4, targets, cand_v, cand_i, cand_cnt,
                                          tk_s, tk_i, P, N, CAP);
    k_assign<<<dim3(B), BS, 0, stream>>>(targets, tk_s, tk_i, bt_score, btcb_idx,
                                         cb_idx2, c_score, P, N);
    k_loss<<<g1, BS, 0, stream>>>(loc4, conf, priors4, targets, bt_score, btcb_idx,
                                  cb_score, cb_idx2, c_score, partials, P, N, C);
    k_final<<<1, BS, 0, stream>>>(partials, bx * B, out);
}

// Round 5
// 342.979 us; speedup vs baseline: 1.6212x; 1.6212x over previous
//
#include <hip/hip_runtime.h>
#include <cstdint>
#include <cstddef>

#define VAR0_ 0.1f
#define VAR1_ 0.2f
#define KTOP_ 5
#define T1_ 0.35f
#define T2_ 0.5f
#define ALPHA_ 0.25f
#define BETA_ 0.11f
#define BS 256

__device__ __forceinline__ float sl1(float d) {
    float x = fabsf(d);
    return (x >= BETA_) ? (x - 0.5f * BETA_) : (0.5f * x * x / BETA_);
}

// ---------------- K0: zero candidate counters (tiny) ----------------
__global__ void k_init(int* __restrict__ cand_cnt, int nCnt) {
    int i = blockIdx.x * blockDim.x + threadIdx.x;
    if (i < nCnt) cand_cnt[i] = 0;
}

// ---------------- K1: per-prior column maxes + decode + candidate harvest ----------------
// Divide-free max tracking: a/b > c/d  <=>  a*d > c*b  (b,d > 0).
// Merged stage-1/stage-2 n-loop (shared truth reads, 2 indep IoU chains).
// NOTE: partial unroll only — full unroll at N=32 spilled to scratch
// (VGPR 24->64, 1.1 GB spill traffic, 134->345 us; round-4 regression).
__global__ void k_per_prior(const float4* __restrict__ loc4, const float4* __restrict__ priors4,
                            const float* __restrict__ targets,
                            float* __restrict__ bt_score, float* __restrict__ cb_score,
                            int* __restrict__ btcb_idx, float* __restrict__ c_score,
                            float* __restrict__ cand_v, int* __restrict__ cand_i,
                            int* __restrict__ cand_cnt,
                            int P, int N, int CAP) {
    int b = blockIdx.y;
    int i = blockIdx.x * blockDim.x + threadIdx.x;
    __shared__ float4 tr4[64];
    __shared__ float trA[64];
    for (int t = threadIdx.x; t < N; t += blockDim.x) {
        float x1 = targets[(size_t)(b * N + t) * 5 + 0];
        float y1 = targets[(size_t)(b * N + t) * 5 + 1];
        float x2 = targets[(size_t)(b * N + t) * 5 + 2];
        float y2 = targets[(size_t)(b * N + t) * 5 + 3];
        tr4[t] = make_float4(x1, y1, x2, y2);
        trA[t] = (x2 - x1) * (y2 - y1);
    }
    __syncthreads();
    if (i >= P) return;

    float4 pr = priors4[i];
    size_t bp = (size_t)b * P + i;
    float4 lc = loc4[bp];

    float pcx = pr.x, pcy = pr.y, pw = pr.z, ph = pr.w;
    float px1 = pcx - pw * 0.5f, py1 = pcy - ph * 0.5f;
    float px2 = pcx + pw * 0.5f, py2 = pcy + ph * 0.5f;
    float pa = (px2 - px1) * (py2 - py1);

    // decode(loc, prior)
    float dcx = pcx + lc.x * VAR0_ * pw;
    float dcy = pcy + lc.y * VAR0_ * ph;
    float dw = pw * expf(lc.z * VAR1_);
    float dh = ph * expf(lc.w * VAR1_);
    float dx1 = dcx - dw * 0.5f, dy1 = dcy - dh * 0.5f;
    float dx2 = dcx + dw * 0.5f, dy2 = dcy + dh * 0.5f;
    float da = (dx2 - dx1) * (dy2 - dy1);

    float b_i = -1.f, b_u = 1.f; int bn = 0;
    float c_i = -1.f, c_u = 1.f; int cn = 0;
#pragma unroll 2
    for (int n = 0; n < N; n++) {
        float4 t4 = tr4[n];
        float ta = trA[n];
        // stage-1: IoU(truth, prior_pt)
        float lx1 = fmaxf(t4.x, px1), ly1 = fmaxf(t4.y, py1);
        float rx1 = fminf(t4.z, px2), ry1 = fminf(t4.w, py2);
        float w1 = fmaxf(rx1 - lx1, 0.f), h1 = fmaxf(ry1 - ly1, 0.f);
        float inter1 = w1 * h1;
        float uni1 = ta + pa - inter1;
        bool bet1 = inter1 * b_u > b_i * uni1;
        b_i = bet1 ? inter1 : b_i; b_u = bet1 ? uni1 : b_u; bn = bet1 ? n : bn;
        // stage-2: IoU(truth, decoded)
        float lx2 = fmaxf(t4.x, dx1), ly2 = fmaxf(t4.y, dy1);
        float rx2 = fminf(t4.z, dx2), ry2 = fminf(t4.w, dy2);
        float w2 = fmaxf(rx2 - lx2, 0.f), h2 = fmaxf(ry2 - ly2, 0.f);
        float inter2 = w2 * h2;
        float uni2 = ta + da - inter2;
        bool bet2 = inter2 * c_u > c_i * uni2;
        c_i = bet2 ? inter2 : c_i; c_u = bet2 ? uni2 : c_u; cn = bet2 ? n : cn;
        if (inter2 >= uni2 * 0.4999990f) {  // conservative pre-test; exact test below
            float v = inter2 / uni2;
            if (v >= T2_) {
                int pos = atomicAdd(&cand_cnt[b * N + n], 1);
                if (pos < CAP) {
                    size_t o = (size_t)(b * N + n) * CAP + pos;
                    cand_v[o] = v; cand_i[o] = i;
                }
            }
        }
    }
    bt_score[bp] = b_i / b_u;
    cb_score[bp] = c_i / c_u;
    btcb_idx[bp] = bn | (cn << 16);
    c_score[bp] = 0.f;
}

// ---------------- K1b: per-(b,n) row max/argmax over all priors ----------------
__global__ void k_row_max(const float4* __restrict__ priors4, const float* __restrict__ targets,
                          float* __restrict__ row_max, int* __restrict__ row_arg,
                          int P, int N) {
    int n = blockIdx.x, b = blockIdx.y;
    float tx1 = targets[(size_t)(b * N + n) * 5 + 0];
    float ty1 = targets[(size_t)(b * N + n) * 5 + 1];
    float tx2 = targets[(size_t)(b * N + n) * 5 + 2];
    float ty2 = targets[(size_t)(b * N + n) * 5 + 3];
    float ta = (tx2 - tx1) * (ty2 - ty1);
    float b_i = -1.f, b_u = 1.f; int bi = 0x7fffffff;
    for (int i = threadIdx.x; i < P; i += blockDim.x) {
        float4 pr = priors4[i];
        float px1 = pr.x - pr.z * 0.5f, py1 = pr.y - pr.w * 0.5f;
        float px2 = pr.x + pr.z * 0.5f, py2 = pr.y + pr.w * 0.5f;
        float lx = fmaxf(tx1, px1), ly = fmaxf(ty1, py1);
        float rx = fminf(tx2, px2), ry = fminf(ty2, py2);
        float w = fmaxf(rx - lx, 0.f), h = fmaxf(ry - ly, 0.f);
        float inter = w * h;
        float uni = ta + (px2 - px1) * (py2 - py1) - inter;
        bool better = inter * b_u > b_i * uni;  // strict >, increasing i -> smallest idx kept
        b_i = better ? inter : b_i; b_u = better ? uni : b_u; bi = better ? i : bi;
    }
    float bv = b_i / b_u;  // one divide; reduce on rounded values (ref semantics)
    int tid = threadIdx.x;
    int lane = tid & 63, wid = tid >> 6;
#pragma unroll
    for (int off = 32; off > 0; off >>= 1) {
        float ov = __shfl_xor(bv, off);
        int oi = __shfl_xor(bi, off);
        if (ov > bv || (ov == bv && oi < bi)) { bv = ov; bi = oi; }
    }
    __shared__ float swv[BS / 64];
    __shared__ int swi[BS / 64];
    if (lane == 0) { swv[wid] = bv; swi[wid] = bi; }
    __syncthreads();
    if (tid == 0) {
        float fv = swv[0]; int fi = swi[0];
        for (int wv = 1; wv < BS / 64; wv++) {
            if (swv[wv] > fv || (swv[wv] == fv && swi[wv] < fi)) { fv = swv[wv]; fi = swi[wv]; }
        }
        row_max[b * N + n] = fv; row_arg[b * N + n] = fi;
    }
}

// ---------------- K2: greedy bipartite matching — ONE WAVE per image, register rows ----------------
__global__ void k_greedy(const float4* __restrict__ priors4, const float* __restrict__ targets,
                         const float* __restrict__ row_max_in, const int* __restrict__ row_arg_in,
                         float* __restrict__ bt_score, int* __restrict__ btcb_idx,
                         int P, int N) {
    int b = blockIdx.x;
    int lane = threadIdx.x;  // block == 1 wave of 64
    extern __shared__ unsigned int mask[];
    int maskWords = (P + 31) >> 5;
    for (int w = lane; w < maskWords; w += 64) mask[w] = 0u;

    float rmax = -2.f; int rarg = 0x7fffffff; int alive = 0;
    float tx1 = 0.f, ty1 = 0.f, tx2 = 0.f, ty2 = 0.f, ta = 0.f;
    if (lane < N) {
        rmax = row_max_in[b * N + lane];
        rarg = row_arg_in[b * N + lane];
        alive = 1;
        tx1 = targets[(size_t)(b * N + lane) * 5 + 0];
        ty1 = targets[(size_t)(b * N + lane) * 5 + 1];
        tx2 = targets[(size_t)(b * N + lane) * 5 + 2];
        ty2 = targets[(size_t)(b * N + lane) * 5 + 3];
        ta = (tx2 - tx1) * (ty2 - ty1);
    }
    __syncthreads();

    for (int it = 0; it < N; it++) {
        float v = (lane < N && alive) ? rmax : -3.f;
        int idx = lane;
#pragma unroll
        for (int off = 32; off > 0; off >>= 1) {
            float ov = __shfl_xor(v, off);
            int oi = __shfl_xor(idx, off);
            if (ov > v || (ov == v && oi < idx)) { v = ov; idx = oi; }
        }
        int bj = idx;
        float bv = v;
        int sel = __shfl(rarg, bj);
        if (lane == bj) alive = 0;
        if (lane == 0) {
            size_t bpsel = (size_t)b * P + sel;
            bt_score[bpsel] = bv;
            int wrd = btcb_idx[bpsel];
            btcb_idx[bpsel] = (wrd & ~0xFFFF) | bj;
            mask[sel >> 5] |= (1u << (sel & 31));
        }
        __syncthreads();

        unsigned long long coll = __ballot(lane < N && alive && rarg == sel);
        while (coll) {
            int r = __ffsll((long long)coll) - 1;
            coll &= coll - 1;
            float rx1 = __shfl(tx1, r), ry1 = __shfl(ty1, r);
            float rx2 = __shfl(tx2, r), ry2 = __shfl(ty2, r);
            float ra = __shfl(ta, r);
            float n_i = -2.f, n_u = 1.f; int ni = 0x7fffffff;
            for (int i = lane; i < P; i += 64) {
                if (mask[i >> 5] & (1u << (i & 31))) continue;
                float4 pr = priors4[i];
                float px1 = pr.x - pr.z * 0.5f, py1 = pr.y - pr.w * 0.5f;
                float px2 = pr.x + pr.z * 0.5f, py2 = pr.y + pr.w * 0.5f;
                float lx = fmaxf(rx1, px1), ly = fmaxf(ry1, py1);
                float rx = fminf(rx2, px2), ry = fminf(ry2, py2);
                float w = fmaxf(rx - lx, 0.f), h = fmaxf(ry - ly, 0.f);
                float inter = w * h;
                float uni = ra + (px2 - px1) * (py2 - py1) - inter;
                bool better = inter * n_u > n_i * uni;
                n_i = better ? inter : n_i; n_u = better ? uni : n_u; ni = better ? i : ni;
            }
            float nv = n_i / n_u;
#pragma unroll
            for (int off = 32; off > 0; off >>= 1) {
                float ov = __shfl_xor(nv, off);
                int oi = __shfl_xor(ni, off);
                if (ov > nv || (ov == nv && oi < ni)) { nv = ov; ni = oi; }
            }
            if (lane == r) { rmax = nv; rarg = ni; }
        }
        __syncthreads();
    }
}

// ---------------- K3: per-(b,n) top-5 of thresholded c_iou (lax.top_k semantics) ----------------
__global__ void k_topk(const float4* __restrict__ loc4, const float4* __restrict__ priors4,
                       const float* __restrict__ targets,
                       const float* __restrict__ cand_v, const int* __restrict__ cand_i,
                       const int* __restrict__ cand_cnt,
                       float* __restrict__ tk_s, int* __restrict__ tk_i,
                       int P, int N, int CAP) {
    int n = blockIdx.x, b = blockIdx.y;
    int row = b * N + n;
    int tid = threadIdx.x;

    float vals[KTOP_]; int ids[KTOP_];
#pragma unroll
    for (int k = 0; k < KTOP_; k++) { vals[k] = -1.f; ids[k] = 0x7fffffff; }

    int cnt = cand_cnt[row];
    if (cnt <= CAP) {
        for (int k = tid; k < cnt; k += blockDim.x) {
            float cv = cand_v[(size_t)row * CAP + k];
            int ci = cand_i[(size_t)row * CAP + k];
#pragma unroll
            for (int q = 0; q < KTOP_; q++) {
                bool better = (cv > vals[q]) || ((cv == vals[q]) && (ci < ids[q]));
                float tv = better ? cv : vals[q]; int ti = better ? ci : ids[q];
                cv = better ? vals[q] : cv; ci = better ? ids[q] : ci;
                vals[q] = tv; ids[q] = ti;
            }
        }
    } else {
        // deterministic fallback: full rescan of this row (overflowed candidate buffer)
        float tx1 = targets[(size_t)row * 5 + 0], ty1 = targets[(size_t)row * 5 + 1];
        float tx2 = targets[(size_t)row * 5 + 2], ty2 = targets[(size_t)row * 5 + 3];
        float ta = (tx2 - tx1) * (ty2 - ty1);
        for (int i = tid; i < P; i += blockDim.x) {
            float4 pr = priors4[i];
            size_t bp = (size_t)b * P + i;
            float4 lc = loc4[bp];
            float dcx = pr.x + lc.x * VAR0_ * pr.z;
            float dcy = pr.y + lc.y * VAR0_ * pr.w;
            float dw = pr.z * expf(lc.z * VAR1_);
            float dh = pr.w * expf(lc.w * VAR1_);
            float dx1 = dcx - dw * 0.5f, dy1 = dcy - dh * 0.5f;
            float dx2 = dcx + dw * 0.5f, dy2 = dcy + dh * 0.5f;
            float lx = fmaxf(tx1, dx1), ly = fmaxf(ty1, dy1);
            float rx = fminf(tx2, dx2), ry = fminf(ty2, dy2);
            float w = fmaxf(rx - lx, 0.f), h = fmaxf(ry - ly, 0.f);
            float inter = w * h;
            float uni = ta + (dx2 - dx1) * (dy2 - dy1) - inter;
            if (inter >= uni * 0.4999990f) {
                float v = inter / uni;
                if (v >= T2_) {
                    float cv = v; int ci = i;
#pragma unroll
                    for (int q = 0; q < KTOP_; q++) {
                        bool better = (cv > vals[q]) || ((cv == vals[q]) && (ci < ids[q]));
                        float tv = better ? cv : vals[q]; int ti = better ? ci : ids[q];
                        cv = better ? vals[q] : cv; ci = better ? ids[q] : ci;
                        vals[q] = tv; ids[q] = ti;
                    }
                }
            }
        }
    }

    __shared__ float mv[BS * KTOP_];
    __shared__ int mi[BS * KTOP_];
#pragma unroll
    for (int k = 0; k < KTOP_; k++) { mv[tid * KTOP_ + k] = vals[k]; mi[tid * KTOP_ + k] = ids[k]; }
    __syncthreads();
    for (int s = BS / 2; s > 0; s >>= 1) {
        if (tid < s) {
#pragma unroll
            for (int j = 0; j < KTOP_; j++) {
                float cv = mv[(tid + s) * KTOP_ + j];
                int ci = mi[(tid + s) * KTOP_ + j];
#pragma unroll
                for (int q = 0; q < KTOP_; q++) {
                    bool better = (cv > vals[q]) || ((cv == vals[q]) && (ci < ids[q]));
                    float tv = better ? cv : vals[q]; int ti = better ? ci : ids[q];
                    cv = better ? vals[q] : cv; ci = better ? ids[q] : ci;
                    vals[q] = tv; ids[q] = ti;
                }
            }
#pragma unroll
            for (int k = 0; k < KTOP_; k++) { mv[tid * KTOP_ + k] = vals[k]; mi[tid * KTOP_ + k] = ids[k]; }
        }
        __syncthreads();
    }
    if (tid == 0) {
#pragma unroll
        for (int k = 0; k < KTOP_; k++) {
            tk_s[(size_t)row * KTOP_ + k] = (vals[k] > 0.f) ? vals[k] : 0.f;
            tk_i[(size_t)row * KTOP_ + k] = (ids[k] == 0x7fffffff) ? 0 : ids[k];
        }
    }
}

// ---------------- K3b: assign loop, parallel last-writer-wins ----------------
__global__ void k_assign(const float* __restrict__ targets,
                         const float* __restrict__ tk_s, const int* __restrict__ tk_i,
                         const float* __restrict__ bt_score, const int* __restrict__ btcb_idx,
                         int* __restrict__ cb_idx2, float* __restrict__ c_score,
                         int P, int N) {
    int b = blockIdx.x;
    int tid = threadIdx.x;
    int T = N * KTOP_;  // 160
    __shared__ int sh_p[512];
    __shared__ float sh_s[512];
    __shared__ int sh_c[512];
    if (tid < T) {
        int i = tid / KTOP_, j = tid % KTOP_;
        int p = tk_i[(size_t)(b * N + i) * KTOP_ + j];
        float s = tk_s[(size_t)(b * N + i) * KTOP_ + j];
        size_t bp = (size_t)b * P + p;
        float bs = bt_score[bp];
        int bj = btcb_idx[bp] & 0xFFFF;
        float conf1 = (bs < T1_) ? 0.f : targets[(size_t)(b * N + bj) * 5 + 4];
        sh_p[tid] = p; sh_s[tid] = s;
        sh_c[tid] = (conf1 < 1.f && s > 0.f) ? 1 : 0;
    }
    __syncthreads();
    if (tid < T && sh_c[tid]) {
        int p = sh_p[tid];
        bool last = true;
        for (int t2 = tid + 1; t2 < T; t2++) {
            if (sh_c[t2] && sh_p[t2] == p) { last = false; break; }
        }
        if (last) {
            size_t bp = (size_t)b * P + p;
            cb_idx2[bp] = tid / KTOP_;
            c_score[bp] = sh_s[tid];
        }
    }
}

// ---------------- K4: per-element losses + block partial sums ----------------
__global__ void k_loss(const float4* __restrict__ loc4, const float* __restrict__ conf,
                       const float4* __restrict__ priors4, const float* __restrict__ targets,
                       const float* __restrict__ bt_score, const int* __restrict__ btcb_idx,
                       const float* __restrict__ cb_score, const int* __restrict__ cb_idx2,
                       const float* __restrict__ c_score,
                       double* __restrict__ partials,
                       int P, int N, int C) {
    int b = blockIdx.y;
    int i = blockIdx.x * blockDim.x + threadIdx.x;
    double l1 = 0.0, l2 = 0.0, f1 = 0.0, f2 = 0.0;
    int n1 = 0, n2 = 0;
    if (i < P) {
        size_t bp = (size_t)b * P + i;
        float bs = bt_score[bp];
        int widx = btcb_idx[bp];
        int bj = widx & 0xFFFF;
        float cbs = cb_score[bp]; float cs = c_score[bp];
        int cj = (cs > 0.f) ? cb_idx2[bp] : ((widx >> 16) & 0xFFFF);
        float lab1 = targets[(size_t)(b * N + bj) * 5 + 4];
        float conf1 = (bs < T1_) ? 0.f : lab1;
        if ((bs < T1_) && (cbs >= T2_) && (cs < T2_)) conf1 = -1.f;
        float lab2 = targets[(size_t)(b * N + cj) * 5 + 4];
        float conf2 = (cs < T2_) ? -1.f : lab2;
        bool m1 = conf1 > 0.f, m2 = conf2 > 0.f;
        n1 = m1 ? 1 : 0; n2 = m2 ? 1 : 0;

        float4 pr = priors4[i];
        float pcx = pr.x, pcy = pr.y, pw = pr.z, ph = pr.w;
        float4 lc = loc4[bp];
        float p0 = lc.x, p1 = lc.y, p2 = lc.z, p3 = lc.w;

        if (m1) {
            const float* tb = &targets[(size_t)(b * N + bj) * 5];
            float gx = ((tb[0] + tb[2]) * 0.5f - pcx) / (VAR0_ * pw);
            float gy = ((tb[1] + tb[3]) * 0.5f - pcy) / (VAR0_ * ph);
            float gw = logf((tb[2] - tb[0]) / pw) / VAR1_;
            float gh = logf((tb[3] - tb[1]) / ph) / VAR1_;
            l1 = (double)(sl1(p0 - gx) + sl1(p1 - gy) + sl1(p2 - gw) + sl1(p3 - gh));
        }
        if (m2) {
            const float* tb = &targets[(size_t)(b * N + cj) * 5];
            float gx = ((tb[0] + tb[2]) * 0.5f - pcx) / (VAR0_ * pw);
            float gy = ((tb[1] + tb[3]) * 0.5f - pcy) / (VAR0_ * ph);
            float gw = logf((tb[2] - tb[0]) / pw) / VAR1_;
            float gh = logf((tb[3] - tb[1]) / ph) / VAR1_;
            l2 = (double)(sl1(p0 - gx) + sl1(p1 - gy) + sl1(p2 - gw) + sl1(p3 - gh));
        }
        float x0, x1v;
        if (C == 2) {
            float2 cv2 = ((const float2*)conf)[bp];
            x0 = cv2.x; x1v = cv2.y;
        } else {
            x0 = conf[bp * C + 0]; x1v = conf[bp * C + 1];
        }
        {   // focal 1
            float t = fmaxf(conf1, 0.f);
            float keep = (conf1 >= 0.f) ? 1.f : 0.f;
            float x = (t >= 1.f) ? x1v : x0;
            float ce = fmaxf(x, 0.f) - x * t + log1pf(expf(-fabsf(x)));
            float a = t * ALPHA_ + (1.f - t) * (1.f - ALPHA_);
            float pr_ = 1.f / (1.f + expf(-x));
            float pt = (t == 1.f) ? pr_ : (1.f - pr_);
            float om = 1.f - pt;
            f1 = (double)(a * om * om * ce * keep);
        }
        {   // focal 2 (iou-weighted)
            float t = fmaxf(conf2, 0.f);
            float keep = (conf2 >= 0.f) ? 1.f : 0.f;
            float x = (t >= 1.f) ? x1v : x0;
            float ce = fmaxf(x, 0.f) - x * t + log1pf(expf(-fabsf(x)));
            float a = cs * (t * ALPHA_ + (1.f - t) * (1.f - ALPHA_));
            float pr_ = 1.f / (1.f + expf(-x));
            float pt = (t == 1.f) ? pr_ : (1.f - pr_);
            float om = 1.f - pt;
            f2 = (double)(a * om * om * ce * keep);
        }
    }
    int tid = threadIdx.x;
    int lane = tid & 63, wid = tid >> 6;
#pragma unroll
    for (int off = 32; off > 0; off >>= 1) {
        l1 += __shfl_xor(l1, off);
        l2 += __shfl_xor(l2, off);
        f1 += __shfl_xor(f1, off);
        f2 += __shfl_xor(f2, off);
        n1 += __shfl_xor(n1, off);
        n2 += __shfl_xor(n2, off);
    }
    __shared__ double swd[BS / 64][4];
    __shared__ int swn[BS / 64][2];
    if (lane == 0) {
        swd[wid][0] = l1; swd[wid][1] = l2; swd[wid][2] = f1; swd[wid][3] = f2;
        swn[wid][0] = n1; swn[wid][1] = n2;
    }
    __syncthreads();
    if (tid == 0) {
        double a0 = 0, a1 = 0, a2 = 0, a3 = 0; int b0 = 0, b1 = 0;
        for (int wv = 0; wv < BS / 64; wv++) {
            a0 += swd[wv][0]; a1 += swd[wv][1]; a2 += swd[wv][2]; a3 += swd[wv][3];
            b0 += swn[wv][0]; b1 += swn[wv][1];
        }
        int blk = blockIdx.y * gridDim.x + blockIdx.x;
        partials[(size_t)blk * 6 + 0] = a0;
        partials[(size_t)blk * 6 + 1] = a1;
        partials[(size_t)blk * 6 + 2] = a2;
        partials[(size_t)blk * 6 + 3] = a3;
        partials[(size_t)blk * 6 + 4] = (double)b0;
        partials[(size_t)blk * 6 + 5] = (double)b1;
    }
}

// ---------------- K5: final reduction + loss assembly ----------------
__global__ void k_final(const double* __restrict__ partials, int nPart, float* __restrict__ out) {
    int tid = threadIdx.x;
    double a[6] = {0, 0, 0, 0, 0, 0};
    for (int k = tid; k < nPart; k += BS) {
#pragma unroll
        for (int j = 0; j < 6; j++) a[j] += partials[(size_t)k * 6 + j];
    }
    __shared__ double sd[BS * 6];
#pragma unroll
    for (int j = 0; j < 6; j++) sd[tid * 6 + j] = a[j];
    __syncthreads();
    for (int s = BS / 2; s > 0; s >>= 1) {
        if (tid < s) {
#pragma unroll
            for (int j = 0; j < 6; j++) sd[tid * 6 + j] += sd[(tid + s) * 6 + j];
        }
        __syncthreads();
    }
    if (tid == 0) {
        double L1 = sd[0], L2 = sd[1], F1 = sd[2], F2 = sd[3], N1 = sd[4], N2 = sd[5];
        double l1v = L1 / fmax(N1, 1.0), l2v = L2 / fmax(N2, 1.0);
        double f1v = F1 / fmax(N1, 1.0), f2v = F2 / fmax(N2, 1.0);
        double locl = (N1 > 0 ? l1v : 0.0) + (N2 > 0 ? l2v : 0.0);
        double clsl = (N1 > 0 ? f1v : 0.0) + (N2 > 0 ? f2v : 0.0);
        if (N1 == 0 && N2 == 0) { locl = 1e-4; clsl = 1e-4; }
        out[0] = (float)locl;
        out[1] = (float)clsl;
    }
}

extern "C" void kernel_launch(void* const* d_in, const int* in_sizes, int n_in,
                              void* d_out, int out_size, void* d_ws, size_t ws_size,
                              hipStream_t stream) {
    const float* targets = (const float*)d_in[3];
    const float* conf = (const float*)d_in[1];
    const float4* loc4 = (const float4*)d_in[0];
    const float4* priors4 = (const float4*)d_in[2];

    int P = in_sizes[2] / 4;
    int B = in_sizes[0] / (P * 4);
    int N = in_sizes[3] / (B * 5);
    int C = in_sizes[1] / (B * P);
    const int CAP = 2048;
    size_t BP = (size_t)B * P;

    unsigned char* ws = (unsigned char*)d_ws;
    size_t off = 0;
    auto alloc = [&](size_t bytes) { size_t cur = off; off += (bytes + 255) & ~(size_t)255; return cur; };
    float* bt_score = (float*)(ws + alloc(BP * 4));
    float* cb_score = (float*)(ws + alloc(BP * 4));
    int* btcb_idx = (int*)(ws + alloc(BP * 4));
    int* cb_idx2 = (int*)(ws + alloc(BP * 4));
    float* c_score = (float*)(ws + alloc(BP * 4));
    float* row_max = (float*)(ws + alloc((size_t)B * N * 4));
    int* row_arg = (int*)(ws + alloc((size_t)B * N * 4));
    float* tk_s = (float*)(ws + alloc((size_t)B * N * KTOP_ * 4));
    int* tk_i = (int*)(ws + alloc((size_t)B * N * KTOP_ * 4));
    float* cand_v = (float*)(ws + alloc((size_t)B * N * CAP * 4));
    int* cand_i = (int*)(ws + alloc((size_t)B * N * CAP * 4));
    int* cand_cnt = (int*)(ws + alloc((size_t)B * N * 4));
    int bx = (P + BS - 1) / BS;
    double* partials = (double*)(ws + alloc((size_t)bx * B * 6 * 8));
    float* out = (float*)d_out;

    k_init<<<dim3((B * N + BS - 1) / BS), dim3(BS), 0, stream>>>(cand_cnt, B * N);
    dim3 g1(bx, B);
    k_per_prior<<<g1, BS, 0, stream>>>(loc4, priors4, targets, bt_score, cb_score,
                                       btcb_idx, c_score, cand_v, cand_i, cand_cnt,
                                       P, N, CAP);
    k_row_max<<<dim3(N, B), BS, 0, stream>>>(priors4, targets, row_max, row_arg, P, N);
    int maskWords = (P + 31) / 32;
    size_t shmem = (size_t)maskWords * 4;
    k_greedy<<<dim3(B), 64, shmem, stream>>>(priors4, targets, row_max, row_arg,
                                             bt_score, btcb_idx, P, N);
    k_topk<<<dim3(N, B), BS, 0, stream>>>(loc4, priors4, targets, cand_v, cand_i, cand_cnt,
                                          tk_s, tk_i, P, N, CAP);
    k_assign<<<dim3(B), BS, 0, stream>>>(targets, tk_s, tk_i, bt_score, btcb_idx,
                                         cb_idx2, c_score, P, N);
    k_loss<<<g1, BS, 0, stream>>>(loc4, conf, priors4, targets, bt_score, btcb_idx,
                                  cb_score, cb_idx2, c_score, partials, P, N, C);
    k_final<<<1, BS, 0, stream>>>(partials, bx * B, out);
}

// Round 6
// 266.319 us; speedup vs baseline: 2.0878x; 1.2879x over previous
//
#include <hip/hip_runtime.h>
#include <cstdint>
#include <cstddef>

#define VAR0_ 0.1f
#define VAR1_ 0.2f
#define KTOP_ 5
#define T1_ 0.35f
#define T2_ 0.5f
#define ALPHA_ 0.25f
#define BETA_ 0.11f
#define BS 256
#define RSPLIT 8

__device__ __forceinline__ float sl1(float d) {
    float x = fabsf(d);
    return (x >= BETA_) ? (x - 0.5f * BETA_) : (0.5f * x * x / BETA_);
}

// ---------------- K0: zero candidate counters (tiny) ----------------
__global__ void k_init(int* __restrict__ cand_cnt, int nCnt) {
    int i = blockIdx.x * blockDim.x + threadIdx.x;
    if (i < nCnt) cand_cnt[i] = 0;
}

// ---------------- K1: per-prior column maxes + decode + candidate harvest ----------------
// Divide-free max tracking: a/b > c/d  <=>  a*d > c*b  (b,d > 0).
// NOTE: partial unroll only — full unroll at N=32 spilled to scratch
// (VGPR 24->64, 1.1 GB spill traffic; round-4 regression).
__global__ void k_per_prior(const float4* __restrict__ loc4, const float4* __restrict__ priors4,
                            const float* __restrict__ targets,
                            float* __restrict__ bt_score, float* __restrict__ cb_score,
                            int* __restrict__ btcb_idx, float* __restrict__ c_score,
                            float* __restrict__ cand_v, int* __restrict__ cand_i,
                            int* __restrict__ cand_cnt,
                            int P, int N, int CAP) {
    int b = blockIdx.y;
    int i = blockIdx.x * blockDim.x + threadIdx.x;
    __shared__ float4 tr4[64];
    __shared__ float trA[64];
    for (int t = threadIdx.x; t < N; t += blockDim.x) {
        float x1 = targets[(size_t)(b * N + t) * 5 + 0];
        float y1 = targets[(size_t)(b * N + t) * 5 + 1];
        float x2 = targets[(size_t)(b * N + t) * 5 + 2];
        float y2 = targets[(size_t)(b * N + t) * 5 + 3];
        tr4[t] = make_float4(x1, y1, x2, y2);
        trA[t] = (x2 - x1) * (y2 - y1);
    }
    __syncthreads();
    if (i >= P) return;

    float4 pr = priors4[i];
    size_t bp = (size_t)b * P + i;
    float4 lc = loc4[bp];

    float pcx = pr.x, pcy = pr.y, pw = pr.z, ph = pr.w;
    float px1 = pcx - pw * 0.5f, py1 = pcy - ph * 0.5f;
    float px2 = pcx + pw * 0.5f, py2 = pcy + ph * 0.5f;
    float pa = (px2 - px1) * (py2 - py1);

    // decode(loc, prior)
    float dcx = pcx + lc.x * VAR0_ * pw;
    float dcy = pcy + lc.y * VAR0_ * ph;
    float dw = pw * expf(lc.z * VAR1_);
    float dh = ph * expf(lc.w * VAR1_);
    float dx1 = dcx - dw * 0.5f, dy1 = dcy - dh * 0.5f;
    float dx2 = dcx + dw * 0.5f, dy2 = dcy + dh * 0.5f;
    float da = (dx2 - dx1) * (dy2 - dy1);

    float b_i = -1.f, b_u = 1.f; int bn = 0;
    float c_i = -1.f, c_u = 1.f; int cn = 0;
#pragma unroll 2
    for (int n = 0; n < N; n++) {
        float4 t4 = tr4[n];
        float ta = trA[n];
        // stage-1: IoU(truth, prior_pt)
        float lx1 = fmaxf(t4.x, px1), ly1 = fmaxf(t4.y, py1);
        float rx1 = fminf(t4.z, px2), ry1 = fminf(t4.w, py2);
        float w1 = fmaxf(rx1 - lx1, 0.f), h1 = fmaxf(ry1 - ly1, 0.f);
        float inter1 = w1 * h1;
        float uni1 = ta + pa - inter1;
        bool bet1 = inter1 * b_u > b_i * uni1;
        b_i = bet1 ? inter1 : b_i; b_u = bet1 ? uni1 : b_u; bn = bet1 ? n : bn;
        // stage-2: IoU(truth, decoded)
        float lx2 = fmaxf(t4.x, dx1), ly2 = fmaxf(t4.y, dy1);
        float rx2 = fminf(t4.z, dx2), ry2 = fminf(t4.w, dy2);
        float w2 = fmaxf(rx2 - lx2, 0.f), h2 = fmaxf(ry2 - ly2, 0.f);
        float inter2 = w2 * h2;
        float uni2 = ta + da - inter2;
        bool bet2 = inter2 * c_u > c_i * uni2;
        c_i = bet2 ? inter2 : c_i; c_u = bet2 ? uni2 : c_u; cn = bet2 ? n : cn;
        if (inter2 >= uni2 * 0.4999990f) {  // conservative pre-test; exact test below
            float v = inter2 / uni2;
            if (v >= T2_) {
                int pos = atomicAdd(&cand_cnt[b * N + n], 1);
                if (pos < CAP) {
                    size_t o = (size_t)(b * N + n) * CAP + pos;
                    cand_v[o] = v; cand_i[o] = i;
                }
            }
        }
    }
    bt_score[bp] = b_i / b_u;
    cb_score[bp] = c_i / c_u;
    btcb_idx[bp] = bn | (cn << 16);
    c_score[bp] = 0.f;
}

// ---------------- K1b: per-(b,n) row max/argmax — P split 8-ways for occupancy ----------------
// Round-5 fix: 512 blocks -> 22% occupancy, latency-bound (129 us).
// Split P across blockIdx.z: 4096 blocks -> full occupancy.
__global__ void k_row_max_part(const float4* __restrict__ priors4, const float* __restrict__ targets,
                               float* __restrict__ part_max, int* __restrict__ part_arg,
                               int P, int N) {
    int n = blockIdx.x, b = blockIdx.y, s = blockIdx.z;
    int chunk = (P + RSPLIT - 1) / RSPLIT;
    int i0 = s * chunk;
    int i1 = min(P, i0 + chunk);
    float tx1 = targets[(size_t)(b * N + n) * 5 + 0];
    float ty1 = targets[(size_t)(b * N + n) * 5 + 1];
    float tx2 = targets[(size_t)(b * N + n) * 5 + 2];
    float ty2 = targets[(size_t)(b * N + n) * 5 + 3];
    float ta = (tx2 - tx1) * (ty2 - ty1);
    float b_i = -1.f, b_u = 1.f; int bi = 0x7fffffff;
    for (int i = i0 + threadIdx.x; i < i1; i += blockDim.x) {
        float4 pr = priors4[i];
        float px1 = pr.x - pr.z * 0.5f, py1 = pr.y - pr.w * 0.5f;
        float px2 = pr.x + pr.z * 0.5f, py2 = pr.y + pr.w * 0.5f;
        float lx = fmaxf(tx1, px1), ly = fmaxf(ty1, py1);
        float rx = fminf(tx2, px2), ry = fminf(ty2, py2);
        float w = fmaxf(rx - lx, 0.f), h = fmaxf(ry - ly, 0.f);
        float inter = w * h;
        float uni = ta + (px2 - px1) * (py2 - py1) - inter;
        bool better = inter * b_u > b_i * uni;  // strict >, increasing i -> smallest idx kept
        b_i = better ? inter : b_i; b_u = better ? uni : b_u; bi = better ? i : bi;
    }
    float bv = b_i / b_u;  // one divide; merge on rounded values (ref semantics)
    int tid = threadIdx.x;
    int lane = tid & 63, wid = tid >> 6;
#pragma unroll
    for (int off = 32; off > 0; off >>= 1) {
        float ov = __shfl_xor(bv, off);
        int oi = __shfl_xor(bi, off);
        if (ov > bv || (ov == bv && oi < bi)) { bv = ov; bi = oi; }
    }
    __shared__ float swv[BS / 64];
    __shared__ int swi[BS / 64];
    if (lane == 0) { swv[wid] = bv; swi[wid] = bi; }
    __syncthreads();
    if (tid == 0) {
        float fv = swv[0]; int fi = swi[0];
        for (int wv = 1; wv < BS / 64; wv++) {
            if (swv[wv] > fv || (swv[wv] == fv && swi[wv] < fi)) { fv = swv[wv]; fi = swi[wv]; }
        }
        int o = (b * N + n) * RSPLIT + s;
        part_max[o] = fv; part_arg[o] = fi;
    }
}

__global__ void k_row_max_fin(const float* __restrict__ part_max, const int* __restrict__ part_arg,
                              float* __restrict__ row_max, int* __restrict__ row_arg, int N) {
    int n = blockIdx.x, b = blockIdx.y;
    int lane = threadIdx.x;  // 64
    float v = -2.f; int idx = 0x7fffffff;
    if (lane < RSPLIT) {
        int o = (b * N + n) * RSPLIT + lane;
        v = part_max[o]; idx = part_arg[o];
    }
#pragma unroll
    for (int off = 32; off > 0; off >>= 1) {
        float ov = __shfl_xor(v, off);
        int oi = __shfl_xor(idx, off);
        if (ov > v || (ov == v && oi < idx)) { v = ov; idx = oi; }
    }
    if (lane == 0) { row_max[b * N + n] = v; row_arg[b * N + n] = idx; }
}

// ---------------- K2: greedy bipartite matching — ONE WAVE per image, register rows ----------------
__global__ void k_greedy(const float4* __restrict__ priors4, const float* __restrict__ targets,
                         const float* __restrict__ row_max_in, const int* __restrict__ row_arg_in,
                         float* __restrict__ bt_score, int* __restrict__ btcb_idx,
                         int P, int N) {
    int b = blockIdx.x;
    int lane = threadIdx.x;  // block == 1 wave of 64
    extern __shared__ unsigned int mask[];
    int maskWords = (P + 31) >> 5;
    for (int w = lane; w < maskWords; w += 64) mask[w] = 0u;

    float rmax = -2.f; int rarg = 0x7fffffff; int alive = 0;
    float tx1 = 0.f, ty1 = 0.f, tx2 = 0.f, ty2 = 0.f, ta = 0.f;
    if (lane < N) {
        rmax = row_max_in[b * N + lane];
        rarg = row_arg_in[b * N + lane];
        alive = 1;
        tx1 = targets[(size_t)(b * N + lane) * 5 + 0];
        ty1 = targets[(size_t)(b * N + lane) * 5 + 1];
        tx2 = targets[(size_t)(b * N + lane) * 5 + 2];
        ty2 = targets[(size_t)(b * N + lane) * 5 + 3];
        ta = (tx2 - tx1) * (ty2 - ty1);
    }
    __syncthreads();

    for (int it = 0; it < N; it++) {
        float v = (lane < N && alive) ? rmax : -3.f;
        int idx = lane;
#pragma unroll
        for (int off = 32; off > 0; off >>= 1) {
            float ov = __shfl_xor(v, off);
            int oi = __shfl_xor(idx, off);
            if (ov > v || (ov == v && oi < idx)) { v = ov; idx = oi; }
        }
        int bj = idx;
        float bv = v;
        int sel = __shfl(rarg, bj);
        if (lane == bj) alive = 0;
        if (lane == 0) {
            size_t bpsel = (size_t)b * P + sel;
            bt_score[bpsel] = bv;
            int wrd = btcb_idx[bpsel];
            btcb_idx[bpsel] = (wrd & ~0xFFFF) | bj;
            mask[sel >> 5] |= (1u << (sel & 31));
        }
        __syncthreads();

        unsigned long long coll = __ballot(lane < N && alive && rarg == sel);
        while (coll) {
            int r = __ffsll((long long)coll) - 1;
            coll &= coll - 1;
            float rx1 = __shfl(tx1, r), ry1 = __shfl(ty1, r);
            float rx2 = __shfl(tx2, r), ry2 = __shfl(ty2, r);
            float ra = __shfl(ta, r);
            float n_i = -2.f, n_u = 1.f; int ni = 0x7fffffff;
            for (int i = lane; i < P; i += 64) {
                if (mask[i >> 5] & (1u << (i & 31))) continue;
                float4 pr = priors4[i];
                float px1 = pr.x - pr.z * 0.5f, py1 = pr.y - pr.w * 0.5f;
                float px2 = pr.x + pr.z * 0.5f, py2 = pr.y + pr.w * 0.5f;
                float lx = fmaxf(rx1, px1), ly = fmaxf(ry1, py1);
                float rx = fminf(rx2, px2), ry = fminf(ry2, py2);
                float w = fmaxf(rx - lx, 0.f), h = fmaxf(ry - ly, 0.f);
                float inter = w * h;
                float uni = ra + (px2 - px1) * (py2 - py1) - inter;
                bool better = inter * n_u > n_i * uni;
                n_i = better ? inter : n_i; n_u = better ? uni : n_u; ni = better ? i : ni;
            }
            float nv = n_i / n_u;
#pragma unroll
            for (int off = 32; off > 0; off >>= 1) {
                float ov = __shfl_xor(nv, off);
                int oi = __shfl_xor(ni, off);
                if (ov > nv || (ov == nv && oi < ni)) { nv = ov; ni = oi; }
            }
            if (lane == r) { rmax = nv; rarg = ni; }
        }
        __syncthreads();
    }
}

// ---------------- K3: per-(b,n) top-5 of thresholded c_iou (lax.top_k semantics) ----------------
__global__ void k_topk(const float4* __restrict__ loc4, const float4* __restrict__ priors4,
                       const float* __restrict__ targets,
                       const float* __restrict__ cand_v, const int* __restrict__ cand_i,
                       const int* __restrict__ cand_cnt,
                       float* __restrict__ tk_s, int* __restrict__ tk_i,
                       int P, int N, int CAP) {
    int n = blockIdx.x, b = blockIdx.y;
    int row = b * N + n;
    int tid = threadIdx.x;

    float vals[KTOP_]; int ids[KTOP_];
#pragma unroll
    for (int k = 0; k < KTOP_; k++) { vals[k] = -1.f; ids[k] = 0x7fffffff; }

    int cnt = cand_cnt[row];
    if (cnt <= CAP) {
        for (int k = tid; k < cnt; k += blockDim.x) {
            float cv = cand_v[(size_t)row * CAP + k];
            int ci = cand_i[(size_t)row * CAP + k];
#pragma unroll
            for (int q = 0; q < KTOP_; q++) {
                bool better = (cv > vals[q]) || ((cv == vals[q]) && (ci < ids[q]));
                float tv = better ? cv : vals[q]; int ti = better ? ci : ids[q];
                cv = better ? vals[q] : cv; ci = better ? ids[q] : ci;
                vals[q] = tv; ids[q] = ti;
            }
        }
    } else {
        // deterministic fallback: full rescan of this row (overflowed candidate buffer)
        float tx1 = targets[(size_t)row * 5 + 0], ty1 = targets[(size_t)row * 5 + 1];
        float tx2 = targets[(size_t)row * 5 + 2], ty2 = targets[(size_t)row * 5 + 3];
        float ta = (tx2 - tx1) * (ty2 - ty1);
        for (int i = tid; i < P; i += blockDim.x) {
            float4 pr = priors4[i];
            size_t bp = (size_t)b * P + i;
            float4 lc = loc4[bp];
            float dcx = pr.x + lc.x * VAR0_ * pr.z;
            float dcy = pr.y + lc.y * VAR0_ * pr.w;
            float dw = pr.z * expf(lc.z * VAR1_);
            float dh = pr.w * expf(lc.w * VAR1_);
            float dx1 = dcx - dw * 0.5f, dy1 = dcy - dh * 0.5f;
            float dx2 = dcx + dw * 0.5f, dy2 = dcy + dh * 0.5f;
            float lx = fmaxf(tx1, dx1), ly = fmaxf(ty1, dy1);
            float rx = fminf(tx2, dx2), ry = fminf(ty2, dy2);
            float w = fmaxf(rx - lx, 0.f), h = fmaxf(ry - ly, 0.f);
            float inter = w * h;
            float uni = ta + (dx2 - dx1) * (dy2 - dy1) - inter;
            if (inter >= uni * 0.4999990f) {
                float v = inter / uni;
                if (v >= T2_) {
                    float cv = v; int ci = i;
#pragma unroll
                    for (int q = 0; q < KTOP_; q++) {
                        bool better = (cv > vals[q]) || ((cv == vals[q]) && (ci < ids[q]));
                        float tv = better ? cv : vals[q]; int ti = better ? ci : ids[q];
                        cv = better ? vals[q] : cv; ci = better ? ids[q] : ci;
                        vals[q] = tv; ids[q] = ti;
                    }
                }
            }
        }
    }

    __shared__ float mv[BS * KTOP_];
    __shared__ int mi[BS * KTOP_];
#pragma unroll
    for (int k = 0; k < KTOP_; k++) { mv[tid * KTOP_ + k] = vals[k]; mi[tid * KTOP_ + k] = ids[k]; }
    __syncthreads();
    for (int s = BS / 2; s > 0; s >>= 1) {
        if (tid < s) {
#pragma unroll
            for (int j = 0; j < KTOP_; j++) {
                float cv = mv[(tid + s) * KTOP_ + j];
                int ci = mi[(tid + s) * KTOP_ + j];
#pragma unroll
                for (int q = 0; q < KTOP_; q++) {
                    bool better = (cv > vals[q]) || ((cv == vals[q]) && (ci < ids[q]));
                    float tv = better ? cv : vals[q]; int ti = better ? ci : ids[q];
                    cv = better ? vals[q] : cv; ci = better ? ids[q] : ci;
                    vals[q] = tv; ids[q] = ti;
                }
            }
#pragma unroll
            for (int k = 0; k < KTOP_; k++) { mv[tid * KTOP_ + k] = vals[k]; mi[tid * KTOP_ + k] = ids[k]; }
        }
        __syncthreads();
    }
    if (tid == 0) {
#pragma unroll
        for (int k = 0; k < KTOP_; k++) {
            tk_s[(size_t)row * KTOP_ + k] = (vals[k] > 0.f) ? vals[k] : 0.f;
            tk_i[(size_t)row * KTOP_ + k] = (ids[k] == 0x7fffffff) ? 0 : ids[k];
        }
    }
}

// ---------------- K3b: assign loop, parallel last-writer-wins ----------------
__global__ void k_assign(const float* __restrict__ targets,
                         const float* __restrict__ tk_s, const int* __restrict__ tk_i,
                         const float* __restrict__ bt_score, const int* __restrict__ btcb_idx,
                         int* __restrict__ cb_idx2, float* __restrict__ c_score,
                         int P, int N) {
    int b = blockIdx.x;
    int tid = threadIdx.x;
    int T = N * KTOP_;  // 160
    __shared__ int sh_p[512];
    __shared__ float sh_s[512];
    __shared__ int sh_c[512];
    if (tid < T) {
        int i = tid / KTOP_, j = tid % KTOP_;
        int p = tk_i[(size_t)(b * N + i) * KTOP_ + j];
        float s = tk_s[(size_t)(b * N + i) * KTOP_ + j];
        size_t bp = (size_t)b * P + p;
        float bs = bt_score[bp];
        int bj = btcb_idx[bp] & 0xFFFF;
        float conf1 = (bs < T1_) ? 0.f : targets[(size_t)(b * N + bj) * 5 + 4];
        sh_p[tid] = p; sh_s[tid] = s;
        sh_c[tid] = (conf1 < 1.f && s > 0.f) ? 1 : 0;
    }
    __syncthreads();
    if (tid < T && sh_c[tid]) {
        int p = sh_p[tid];
        bool last = true;
        for (int t2 = tid + 1; t2 < T; t2++) {
            if (sh_c[t2] && sh_p[t2] == p) { last = false; break; }
        }
        if (last) {
            size_t bp = (size_t)b * P + p;
            cb_idx2[bp] = tid / KTOP_;
            c_score[bp] = sh_s[tid];
        }
    }
}

// ---------------- K4: per-element losses + block partial sums ----------------
__global__ void k_loss(const float4* __restrict__ loc4, const float* __restrict__ conf,
                       const float4* __restrict__ priors4, const float* __restrict__ targets,
                       const float* __restrict__ bt_score, const int* __restrict__ btcb_idx,
                       const float* __restrict__ cb_score, const int* __restrict__ cb_idx2,
                       const float* __restrict__ c_score,
                       double* __restrict__ partials,
                       int P, int N, int C) {
    int b = blockIdx.y;
    int i = blockIdx.x * blockDim.x + threadIdx.x;
    double l1 = 0.0, l2 = 0.0, f1 = 0.0, f2 = 0.0;
    int n1 = 0, n2 = 0;
    if (i < P) {
        size_t bp = (size_t)b * P + i;
        float bs = bt_score[bp];
        int widx = btcb_idx[bp];
        int bj = widx & 0xFFFF;
        float cbs = cb_score[bp]; float cs = c_score[bp];
        int cj = (cs > 0.f) ? cb_idx2[bp] : ((widx >> 16) & 0xFFFF);
        float lab1 = targets[(size_t)(b * N + bj) * 5 + 4];
        float conf1 = (bs < T1_) ? 0.f : lab1;
        if ((bs < T1_) && (cbs >= T2_) && (cs < T2_)) conf1 = -1.f;
        float lab2 = targets[(size_t)(b * N + cj) * 5 + 4];
        float conf2 = (cs < T2_) ? -1.f : lab2;
        bool m1 = conf1 > 0.f, m2 = conf2 > 0.f;
        n1 = m1 ? 1 : 0; n2 = m2 ? 1 : 0;

        float4 pr = priors4[i];
        float pcx = pr.x, pcy = pr.y, pw = pr.z, ph = pr.w;
        float4 lc = loc4[bp];
        float p0 = lc.x, p1 = lc.y, p2 = lc.z, p3 = lc.w;

        if (m1) {
            const float* tb = &targets[(size_t)(b * N + bj) * 5];
            float gx = ((tb[0] + tb[2]) * 0.5f - pcx) / (VAR0_ * pw);
            float gy = ((tb[1] + tb[3]) * 0.5f - pcy) / (VAR0_ * ph);
            float gw = logf((tb[2] - tb[0]) / pw) / VAR1_;
            float gh = logf((tb[3] - tb[1]) / ph) / VAR1_;
            l1 = (double)(sl1(p0 - gx) + sl1(p1 - gy) + sl1(p2 - gw) + sl1(p3 - gh));
        }
        if (m2) {
            const float* tb = &targets[(size_t)(b * N + cj) * 5];
            float gx = ((tb[0] + tb[2]) * 0.5f - pcx) / (VAR0_ * pw);
            float gy = ((tb[1] + tb[3]) * 0.5f - pcy) / (VAR0_ * ph);
            float gw = logf((tb[2] - tb[0]) / pw) / VAR1_;
            float gh = logf((tb[3] - tb[1]) / ph) / VAR1_;
            l2 = (double)(sl1(p0 - gx) + sl1(p1 - gy) + sl1(p2 - gw) + sl1(p3 - gh));
        }
        float x0, x1v;
        if (C == 2) {
            float2 cv2 = ((const float2*)conf)[bp];
            x0 = cv2.x; x1v = cv2.y;
        } else {
            x0 = conf[bp * C + 0]; x1v = conf[bp * C + 1];
        }
        {   // focal 1
            float t = fmaxf(conf1, 0.f);
            float keep = (conf1 >= 0.f) ? 1.f : 0.f;
            float x = (t >= 1.f) ? x1v : x0;
            float ce = fmaxf(x, 0.f) - x * t + log1pf(expf(-fabsf(x)));
            float a = t * ALPHA_ + (1.f - t) * (1.f - ALPHA_);
            float pr_ = 1.f / (1.f + expf(-x));
            float pt = (t == 1.f) ? pr_ : (1.f - pr_);
            float om = 1.f - pt;
            f1 = (double)(a * om * om * ce * keep);
        }
        {   // focal 2 (iou-weighted)
            float t = fmaxf(conf2, 0.f);
            float keep = (conf2 >= 0.f) ? 1.f : 0.f;
            float x = (t >= 1.f) ? x1v : x0;
            float ce = fmaxf(x, 0.f) - x * t + log1pf(expf(-fabsf(x)));
            float a = cs * (t * ALPHA_ + (1.f - t) * (1.f - ALPHA_));
            float pr_ = 1.f / (1.f + expf(-x));
            float pt = (t == 1.f) ? pr_ : (1.f - pr_);
            float om = 1.f - pt;
            f2 = (double)(a * om * om * ce * keep);
        }
    }
    int tid = threadIdx.x;
    int lane = tid & 63, wid = tid >> 6;
#pragma unroll
    for (int off = 32; off > 0; off >>= 1) {
        l1 += __shfl_xor(l1, off);
        l2 += __shfl_xor(l2, off);
        f1 += __shfl_xor(f1, off);
        f2 += __shfl_xor(f2, off);
        n1 += __shfl_xor(n1, off);
        n2 += __shfl_xor(n2, off);
    }
    __shared__ double swd[BS / 64][4];
    __shared__ int swn[BS / 64][2];
    if (lane == 0) {
        swd[wid][0] = l1; swd[wid][1] = l2; swd[wid][2] = f1; swd[wid][3] = f2;
        swn[wid][0] = n1; swn[wid][1] = n2;
    }
    __syncthreads();
    if (tid == 0) {
        double a0 = 0, a1 = 0, a2 = 0, a3 = 0; int b0 = 0, b1 = 0;
        for (int wv = 0; wv < BS / 64; wv++) {
            a0 += swd[wv][0]; a1 += swd[wv][1]; a2 += swd[wv][2]; a3 += swd[wv][3];
            b0 += swn[wv][0]; b1 += swn[wv][1];
        }
        int blk = blockIdx.y * gridDim.x + blockIdx.x;
        partials[(size_t)blk * 6 + 0] = a0;
        partials[(size_t)blk * 6 + 1] = a1;
        partials[(size_t)blk * 6 + 2] = a2;
        partials[(size_t)blk * 6 + 3] = a3;
        partials[(size_t)blk * 6 + 4] = (double)b0;
        partials[(size_t)blk * 6 + 5] = (double)b1;
    }
}

// ---------------- K5: final reduction + loss assembly ----------------
__global__ void k_final(const double* __restrict__ partials, int nPart, float* __restrict__ out) {
    int tid = threadIdx.x;
    double a[6] = {0, 0, 0, 0, 0, 0};
    for (int k = tid; k < nPart; k += BS) {
#pragma unroll
        for (int j = 0; j < 6; j++) a[j] += partials[(size_t)k * 6 + j];
    }
    __shared__ double sd[BS * 6];
#pragma unroll
    for (int j = 0; j < 6; j++) sd[tid * 6 + j] = a[j];
    __syncthreads();
    for (int s = BS / 2; s > 0; s >>= 1) {
        if (tid < s) {
#pragma unroll
            for (int j = 0; j < 6; j++) sd[tid * 6 + j] += sd[(tid + s) * 6 + j];
        }
        __syncthreads();
    }
    if (tid == 0) {
        double L1 = sd[0], L2 = sd[1], F1 = sd[2], F2 = sd[3], N1 = sd[4], N2 = sd[5];
        double l1v = L1 / fmax(N1, 1.0), l2v = L2 / fmax(N2, 1.0);
        double f1v = F1 / fmax(N1, 1.0), f2v = F2 / fmax(N2, 1.0);
        double locl = (N1 > 0 ? l1v : 0.0) + (N2 > 0 ? l2v : 0.0);
        double clsl = (N1 > 0 ? f1v : 0.0) + (N2 > 0 ? f2v : 0.0);
        if (N1 == 0 && N2 == 0) { locl = 1e-4; clsl = 1e-4; }
        out[0] = (float)locl;
        out[1] = (float)clsl;
    }
}

extern "C" void kernel_launch(void* const* d_in, const int* in_sizes, int n_in,
                              void* d_out, int out_size, void* d_ws, size_t ws_size,
                              hipStream_t stream) {
    const float* targets = (const float*)d_in[3];
    const float* conf = (const float*)d_in[1];
    const float4* loc4 = (const float4*)d_in[0];
    const float4* priors4 = (const float4*)d_in[2];

    int P = in_sizes[2] / 4;
    int B = in_sizes[0] / (P * 4);
    int N = in_sizes[3] / (B * 5);
    int C = in_sizes[1] / (B * P);
    const int CAP = 2048;
    size_t BP = (size_t)B * P;

    unsigned char* ws = (unsigned char*)d_ws;
    size_t off = 0;
    auto alloc = [&](size_t bytes) { size_t cur = off; off += (bytes + 255) & ~(size_t)255; return cur; };
    float* bt_score = (float*)(ws + alloc(BP * 4));
    float* cb_score = (float*)(ws + alloc(BP * 4));
    int* btcb_idx = (int*)(ws + alloc(BP * 4));
    int* cb_idx2 = (int*)(ws + alloc(BP * 4));
    float* c_score = (float*)(ws + alloc(BP * 4));
    float* row_max = (float*)(ws + alloc((size_t)B * N * 4));
    int* row_arg = (int*)(ws + alloc((size_t)B * N * 4));
    float* part_max = (float*)(ws + alloc((size_t)B * N * RSPLIT * 4));
    int* part_arg = (int*)(ws + alloc((size_t)B * N * RSPLIT * 4));
    float* tk_s = (float*)(ws + alloc((size_t)B * N * KTOP_ * 4));
    int* tk_i = (int*)(ws + alloc((size_t)B * N * KTOP_ * 4));
    float* cand_v = (float*)(ws + alloc((size_t)B * N * CAP * 4));
    int* cand_i = (int*)(ws + alloc((size_t)B * N * CAP * 4));
    int* cand_cnt = (int*)(ws + alloc((size_t)B * N * 4));
    int bx = (P + BS - 1) / BS;
    double* partials = (double*)(ws + alloc((size_t)bx * B * 6 * 8));
    float* out = (float*)d_out;

    k_init<<<dim3((B * N + BS - 1) / BS), dim3(BS), 0, stream>>>(cand_cnt, B * N);
    dim3 g1(bx, B);
    k_per_prior<<<g1, BS, 0, stream>>>(loc4, priors4, targets, bt_score, cb_score,
                                       btcb_idx, c_score, cand_v, cand_i, cand_cnt,
                                       P, N, CAP);
    k_row_max_part<<<dim3(N, B, RSPLIT), BS, 0, stream>>>(priors4, targets,
                                                          part_max, part_arg, P, N);
    k_row_max_fin<<<dim3(N, B), 64, 0, stream>>>(part_max, part_arg, row_max, row_arg, N);
    int maskWords = (P + 31) / 32;
    size_t shmem = (size_t)maskWords * 4;
    k_greedy<<<dim3(B), 64, shmem, stream>>>(priors4, targets, row_max, row_arg,
                                             bt_score, btcb_idx, P, N);
    k_topk<<<dim3(N, B), BS, 0, stream>>>(loc4, priors4, targets, cand_v, cand_i, cand_cnt,
                                          tk_s, tk_i, P, N, CAP);
    k_assign<<<dim3(B), BS, 0, stream>>>(targets, tk_s, tk_i, bt_score, btcb_idx,
                                         cb_idx2, c_score, P, N);
    k_loss<<<g1, BS, 0, stream>>>(loc4, conf, priors4, targets, bt_score, btcb_idx,
                                  cb_score, cb_idx2, c_score, partials, P, N, C);
    k_final<<<1, BS, 0, stream>>>(partials, bx * B, out);
}

// Round 7
// 248.031 us; speedup vs baseline: 2.2418x; 1.0737x over previous
//
#include <hip/hip_runtime.h>
#include <cstdint>
#include <cstddef>

#define VAR0_ 0.1f
#define VAR1_ 0.2f
#define KTOP_ 5
#define T1_ 0.35f
#define T2_ 0.5f
#define ALPHA_ 0.25f
#define BETA_ 0.11f
#define BS 256
#define RSPLIT 8

__device__ __forceinline__ float sl1(float d) {
    float x = fabsf(d);
    return (x >= BETA_) ? (x - 0.5f * BETA_) : (0.5f * x * x / BETA_);
}

// ---------------- K0: zero candidate counters (tiny) ----------------
__global__ void k_init(int* __restrict__ cand_cnt, int nCnt) {
    int i = blockIdx.x * blockDim.x + threadIdx.x;
    if (i < nCnt) cand_cnt[i] = 0;
}

// ---------------- K1: per-prior stage-1 argmax + deferred candidate harvest ----------------
// Divide-free max tracking: a/b > c/d  <=>  a*d > c*b  (b,d > 0).
// Round-6 fixes:
//  * harvest atomic moved OUT of the n-loop (bitmask defer) — the in-loop
//    atomicAdd->pos dependency forced a vmcnt(0) stall per iteration.
//  * stage-2 max/argmax chain dropped: c_bp_idx's initial value is never
//    observable (conf_s2=-1 wherever c_score<T2), and c_bp_score's only use
//    is the boolean >=T2  ==  "harvested any candidate" (bit 16 of btcb_idx).
// NOTE: partial unroll only — full unroll at N=32 spilled (round-4).
__global__ void k_per_prior(const float4* __restrict__ loc4, const float4* __restrict__ priors4,
                            const float* __restrict__ targets,
                            float* __restrict__ bt_score,
                            int* __restrict__ btcb_idx, float* __restrict__ c_score,
                            float* __restrict__ cand_v, int* __restrict__ cand_i,
                            int* __restrict__ cand_cnt,
                            int P, int N, int CAP) {
    int b = blockIdx.y;
    int i = blockIdx.x * blockDim.x + threadIdx.x;
    __shared__ float4 tr4[64];
    __shared__ float trA[64];
    for (int t = threadIdx.x; t < N; t += blockDim.x) {
        float x1 = targets[(size_t)(b * N + t) * 5 + 0];
        float y1 = targets[(size_t)(b * N + t) * 5 + 1];
        float x2 = targets[(size_t)(b * N + t) * 5 + 2];
        float y2 = targets[(size_t)(b * N + t) * 5 + 3];
        tr4[t] = make_float4(x1, y1, x2, y2);
        trA[t] = (x2 - x1) * (y2 - y1);
    }
    __syncthreads();
    if (i >= P) return;

    float4 pr = priors4[i];
    size_t bp = (size_t)b * P + i;
    float4 lc = loc4[bp];

    float pcx = pr.x, pcy = pr.y, pw = pr.z, ph = pr.w;
    float px1 = pcx - pw * 0.5f, py1 = pcy - ph * 0.5f;
    float px2 = pcx + pw * 0.5f, py2 = pcy + ph * 0.5f;
    float pa = (px2 - px1) * (py2 - py1);

    // decode(loc, prior)
    float dcx = pcx + lc.x * VAR0_ * pw;
    float dcy = pcy + lc.y * VAR0_ * ph;
    float dw = pw * expf(lc.z * VAR1_);
    float dh = ph * expf(lc.w * VAR1_);
    float dx1 = dcx - dw * 0.5f, dy1 = dcy - dh * 0.5f;
    float dx2 = dcx + dw * 0.5f, dy2 = dcy + dh * 0.5f;
    float da = (dx2 - dx1) * (dy2 - dy1);

    float b_i = -1.f, b_u = 1.f; int bn = 0;
    unsigned long long hmask = 0ull;
#pragma unroll 2
    for (int n = 0; n < N; n++) {
        float4 t4 = tr4[n];
        float ta = trA[n];
        // stage-1: IoU(truth, prior_pt) — divide-free argmax, first-max tiebreak
        float lx1 = fmaxf(t4.x, px1), ly1 = fmaxf(t4.y, py1);
        float rx1 = fminf(t4.z, px2), ry1 = fminf(t4.w, py2);
        float w1 = fmaxf(rx1 - lx1, 0.f), h1 = fmaxf(ry1 - ly1, 0.f);
        float inter1 = w1 * h1;
        float uni1 = ta + pa - inter1;
        bool bet1 = inter1 * b_u > b_i * uni1;
        b_i = bet1 ? inter1 : b_i; b_u = bet1 ? uni1 : b_u; bn = bet1 ? n : bn;
        // stage-2: conservative pretest only; exact test deferred
        float lx2 = fmaxf(t4.x, dx1), ly2 = fmaxf(t4.y, dy1);
        float rx2 = fminf(t4.z, dx2), ry2 = fminf(t4.w, dy2);
        float w2 = fmaxf(rx2 - lx2, 0.f), h2 = fmaxf(ry2 - ly2, 0.f);
        float inter2 = w2 * h2;
        float uni2 = ta + da - inter2;
        if (inter2 >= uni2 * 0.4999990f) hmask |= (1ull << n);
    }

    // deferred harvest: exact divide + atomic, outside the hot loop
    int hadCand = 0;
    while (hmask) {
        int n = __ffsll((long long)hmask) - 1;
        hmask &= hmask - 1;
        float4 t4 = tr4[n];
        float lx2 = fmaxf(t4.x, dx1), ly2 = fmaxf(t4.y, dy1);
        float rx2 = fminf(t4.z, dx2), ry2 = fminf(t4.w, dy2);
        float w2 = fmaxf(rx2 - lx2, 0.f), h2 = fmaxf(ry2 - ly2, 0.f);
        float inter2 = w2 * h2;
        float uni2 = trA[n] + da - inter2;
        float v = inter2 / uni2;
        if (v >= T2_) {
            hadCand = 1;
            int pos = atomicAdd(&cand_cnt[b * N + n], 1);
            if (pos < CAP) {
                size_t o = (size_t)(b * N + n) * CAP + pos;
                cand_v[o] = v; cand_i[o] = i;
            }
        }
    }

    bt_score[bp] = b_i / b_u;
    btcb_idx[bp] = bn | (hadCand << 16);
    c_score[bp] = 0.f;
}

// ---------------- K1b: per-(b,n) row max/argmax — P split 8-ways for occupancy ----------------
__global__ void k_row_max_part(const float4* __restrict__ priors4, const float* __restrict__ targets,
                               float* __restrict__ part_max, int* __restrict__ part_arg,
                               int P, int N) {
    int n = blockIdx.x, b = blockIdx.y, s = blockIdx.z;
    int chunk = (P + RSPLIT - 1) / RSPLIT;
    int i0 = s * chunk;
    int i1 = min(P, i0 + chunk);
    float tx1 = targets[(size_t)(b * N + n) * 5 + 0];
    float ty1 = targets[(size_t)(b * N + n) * 5 + 1];
    float tx2 = targets[(size_t)(b * N + n) * 5 + 2];
    float ty2 = targets[(size_t)(b * N + n) * 5 + 3];
    float ta = (tx2 - tx1) * (ty2 - ty1);
    float b_i = -1.f, b_u = 1.f; int bi = 0x7fffffff;
    for (int i = i0 + threadIdx.x; i < i1; i += blockDim.x) {
        float4 pr = priors4[i];
        float px1 = pr.x - pr.z * 0.5f, py1 = pr.y - pr.w * 0.5f;
        float px2 = pr.x + pr.z * 0.5f, py2 = pr.y + pr.w * 0.5f;
        float lx = fmaxf(tx1, px1), ly = fmaxf(ty1, py1);
        float rx = fminf(tx2, px2), ry = fminf(ty2, py2);
        float w = fmaxf(rx - lx, 0.f), h = fmaxf(ry - ly, 0.f);
        float inter = w * h;
        float uni = ta + (px2 - px1) * (py2 - py1) - inter;
        bool better = inter * b_u > b_i * uni;  // strict >, increasing i -> smallest idx kept
        b_i = better ? inter : b_i; b_u = better ? uni : b_u; bi = better ? i : bi;
    }
    float bv = b_i / b_u;  // one divide; merge on rounded values (ref semantics)
    int tid = threadIdx.x;
    int lane = tid & 63, wid = tid >> 6;
#pragma unroll
    for (int off = 32; off > 0; off >>= 1) {
        float ov = __shfl_xor(bv, off);
        int oi = __shfl_xor(bi, off);
        if (ov > bv || (ov == bv && oi < bi)) { bv = ov; bi = oi; }
    }
    __shared__ float swv[BS / 64];
    __shared__ int swi[BS / 64];
    if (lane == 0) { swv[wid] = bv; swi[wid] = bi; }
    __syncthreads();
    if (tid == 0) {
        float fv = swv[0]; int fi = swi[0];
        for (int wv = 1; wv < BS / 64; wv++) {
            if (swv[wv] > fv || (swv[wv] == fv && swi[wv] < fi)) { fv = swv[wv]; fi = swi[wv]; }
        }
        int o = (b * N + n) * RSPLIT + s;
        part_max[o] = fv; part_arg[o] = fi;
    }
}

__global__ void k_row_max_fin(const float* __restrict__ part_max, const int* __restrict__ part_arg,
                              float* __restrict__ row_max, int* __restrict__ row_arg, int N) {
    int n = blockIdx.x, b = blockIdx.y;
    int lane = threadIdx.x;  // 64
    float v = -2.f; int idx = 0x7fffffff;
    if (lane < RSPLIT) {
        int o = (b * N + n) * RSPLIT + lane;
        v = part_max[o]; idx = part_arg[o];
    }
#pragma unroll
    for (int off = 32; off > 0; off >>= 1) {
        float ov = __shfl_xor(v, off);
        int oi = __shfl_xor(idx, off);
        if (ov > v || (ov == v && oi < idx)) { v = ov; idx = oi; }
    }
    if (lane == 0) { row_max[b * N + n] = v; row_arg[b * N + n] = idx; }
}

// ---------------- K2: greedy bipartite matching — ONE WAVE per image, register rows ----------------
__global__ void k_greedy(const float4* __restrict__ priors4, const float* __restrict__ targets,
                         const float* __restrict__ row_max_in, const int* __restrict__ row_arg_in,
                         float* __restrict__ bt_score, int* __restrict__ btcb_idx,
                         int P, int N) {
    int b = blockIdx.x;
    int lane = threadIdx.x;  // block == 1 wave of 64
    extern __shared__ unsigned int mask[];
    int maskWords = (P + 31) >> 5;
    for (int w = lane; w < maskWords; w += 64) mask[w] = 0u;

    float rmax = -2.f; int rarg = 0x7fffffff; int alive = 0;
    float tx1 = 0.f, ty1 = 0.f, tx2 = 0.f, ty2 = 0.f, ta = 0.f;
    if (lane < N) {
        rmax = row_max_in[b * N + lane];
        rarg = row_arg_in[b * N + lane];
        alive = 1;
        tx1 = targets[(size_t)(b * N + lane) * 5 + 0];
        ty1 = targets[(size_t)(b * N + lane) * 5 + 1];
        tx2 = targets[(size_t)(b * N + lane) * 5 + 2];
        ty2 = targets[(size_t)(b * N + lane) * 5 + 3];
        ta = (tx2 - tx1) * (ty2 - ty1);
    }
    __syncthreads();

    for (int it = 0; it < N; it++) {
        float v = (lane < N && alive) ? rmax : -3.f;
        int idx = lane;
#pragma unroll
        for (int off = 32; off > 0; off >>= 1) {
            float ov = __shfl_xor(v, off);
            int oi = __shfl_xor(idx, off);
            if (ov > v || (ov == v && oi < idx)) { v = ov; idx = oi; }
        }
        int bj = idx;
        float bv = v;
        int sel = __shfl(rarg, bj);
        if (lane == bj) alive = 0;
        if (lane == 0) {
            size_t bpsel = (size_t)b * P + sel;
            bt_score[bpsel] = bv;
            int wrd = btcb_idx[bpsel];
            btcb_idx[bpsel] = (wrd & ~0xFFFF) | bj;   // preserve hadCand flag (bit 16)
            mask[sel >> 5] |= (1u << (sel & 31));
        }
        __syncthreads();

        unsigned long long coll = __ballot(lane < N && alive && rarg == sel);
        while (coll) {
            int r = __ffsll((long long)coll) - 1;
            coll &= coll - 1;
            float rx1 = __shfl(tx1, r), ry1 = __shfl(ty1, r);
            float rx2 = __shfl(tx2, r), ry2 = __shfl(ty2, r);
            float ra = __shfl(ta, r);
            float n_i = -2.f, n_u = 1.f; int ni = 0x7fffffff;
            for (int i = lane; i < P; i += 64) {
                if (mask[i >> 5] & (1u << (i & 31))) continue;
                float4 pr = priors4[i];
                float px1 = pr.x - pr.z * 0.5f, py1 = pr.y - pr.w * 0.5f;
                float px2 = pr.x + pr.z * 0.5f, py2 = pr.y + pr.w * 0.5f;
                float lx = fmaxf(rx1, px1), ly = fmaxf(ry1, py1);
                float rx = fminf(rx2, px2), ry = fminf(ry2, py2);
                float w = fmaxf(rx - lx, 0.f), h = fmaxf(ry - ly, 0.f);
                float inter = w * h;
                float uni = ra + (px2 - px1) * (py2 - py1) - inter;
                bool better = inter * n_u > n_i * uni;
                n_i = better ? inter : n_i; n_u = better ? uni : n_u; ni = better ? i : ni;
            }
            float nv = n_i / n_u;
#pragma unroll
            for (int off = 32; off > 0; off >>= 1) {
                float ov = __shfl_xor(nv, off);
                int oi = __shfl_xor(ni, off);
                if (ov > nv || (ov == nv && oi < ni)) { nv = ov; ni = oi; }
            }
            if (lane == r) { rmax = nv; rarg = ni; }
        }
        __syncthreads();
    }
}

// ---------------- K3: per-(b,n) top-5 of thresholded c_iou (lax.top_k semantics) ----------------
__global__ void k_topk(const float4* __restrict__ loc4, const float4* __restrict__ priors4,
                       const float* __restrict__ targets,
                       const float* __restrict__ cand_v, const int* __restrict__ cand_i,
                       const int* __restrict__ cand_cnt,
                       float* __restrict__ tk_s, int* __restrict__ tk_i,
                       int P, int N, int CAP) {
    int n = blockIdx.x, b = blockIdx.y;
    int row = b * N + n;
    int tid = threadIdx.x;

    float vals[KTOP_]; int ids[KTOP_];
#pragma unroll
    for (int k = 0; k < KTOP_; k++) { vals[k] = -1.f; ids[k] = 0x7fffffff; }

    int cnt = cand_cnt[row];
    if (cnt <= CAP) {
        for (int k = tid; k < cnt; k += blockDim.x) {
            float cv = cand_v[(size_t)row * CAP + k];
            int ci = cand_i[(size_t)row * CAP + k];
#pragma unroll
            for (int q = 0; q < KTOP_; q++) {
                bool better = (cv > vals[q]) || ((cv == vals[q]) && (ci < ids[q]));
                float tv = better ? cv : vals[q]; int ti = better ? ci : ids[q];
                cv = better ? vals[q] : cv; ci = better ? ids[q] : ci;
                vals[q] = tv; ids[q] = ti;
            }
        }
    } else {
        // deterministic fallback: full rescan of this row (overflowed candidate buffer)
        float tx1 = targets[(size_t)row * 5 + 0], ty1 = targets[(size_t)row * 5 + 1];
        float tx2 = targets[(size_t)row * 5 + 2], ty2 = targets[(size_t)row * 5 + 3];
        float ta = (tx2 - tx1) * (ty2 - ty1);
        for (int i = tid; i < P; i += blockDim.x) {
            float4 pr = priors4[i];
            size_t bp = (size_t)b * P + i;
            float4 lc = loc4[bp];
            float dcx = pr.x + lc.x * VAR0_ * pr.z;
            float dcy = pr.y + lc.y * VAR0_ * pr.w;
            float dw = pr.z * expf(lc.z * VAR1_);
            float dh = pr.w * expf(lc.w * VAR1_);
            float dx1 = dcx - dw * 0.5f, dy1 = dcy - dh * 0.5f;
            float dx2 = dcx + dw * 0.5f, dy2 = dcy + dh * 0.5f;
            float lx = fmaxf(tx1, dx1), ly = fmaxf(ty1, dy1);
            float rx = fminf(tx2, dx2), ry = fminf(ty2, dy2);
            float w = fmaxf(rx - lx, 0.f), h = fmaxf(ry - ly, 0.f);
            float inter = w * h;
            float uni = ta + (dx2 - dx1) * (dy2 - dy1) - inter;
            if (inter >= uni * 0.4999990f) {
                float v = inter / uni;
                if (v >= T2_) {
                    float cv = v; int ci = i;
#pragma unroll
                    for (int q = 0; q < KTOP_; q++) {
                        bool better = (cv > vals[q]) || ((cv == vals[q]) && (ci < ids[q]));
                        float tv = better ? cv : vals[q]; int ti = better ? ci : ids[q];
                        cv = better ? vals[q] : cv; ci = better ? ids[q] : ci;
                        vals[q] = tv; ids[q] = ti;
                    }
                }
            }
        }
    }

    __shared__ float mv[BS * KTOP_];
    __shared__ int mi[BS * KTOP_];
#pragma unroll
    for (int k = 0; k < KTOP_; k++) { mv[tid * KTOP_ + k] = vals[k]; mi[tid * KTOP_ + k] = ids[k]; }
    __syncthreads();
    for (int s = BS / 2; s > 0; s >>= 1) {
        if (tid < s) {
#pragma unroll
            for (int j = 0; j < KTOP_; j++) {
                float cv = mv[(tid + s) * KTOP_ + j];
                int ci = mi[(tid + s) * KTOP_ + j];
#pragma unroll
                for (int q = 0; q < KTOP_; q++) {
                    bool better = (cv > vals[q]) || ((cv == vals[q]) && (ci < ids[q]));
                    float tv = better ? cv : vals[q]; int ti = better ? ci : ids[q];
                    cv = better ? vals[q] : cv; ci = better ? ids[q] : ci;
                    vals[q] = tv; ids[q] = ti;
                }
            }
#pragma unroll
            for (int k = 0; k < KTOP_; k++) { mv[tid * KTOP_ + k] = vals[k]; mi[tid * KTOP_ + k] = ids[k]; }
        }
        __syncthreads();
    }
    if (tid == 0) {
#pragma unroll
        for (int k = 0; k < KTOP_; k++) {
            tk_s[(size_t)row * KTOP_ + k] = (vals[k] > 0.f) ? vals[k] : 0.f;
            tk_i[(size_t)row * KTOP_ + k] = (ids[k] == 0x7fffffff) ? 0 : ids[k];
        }
    }
}

// ---------------- K3b: assign loop, parallel last-writer-wins ----------------
__global__ void k_assign(const float* __restrict__ targets,
                         const float* __restrict__ tk_s, const int* __restrict__ tk_i,
                         const float* __restrict__ bt_score, const int* __restrict__ btcb_idx,
                         int* __restrict__ cb_idx2, float* __restrict__ c_score,
                         int P, int N) {
    int b = blockIdx.x;
    int tid = threadIdx.x;
    int T = N * KTOP_;  // 160
    __shared__ int sh_p[512];
    __shared__ float sh_s[512];
    __shared__ int sh_c[512];
    if (tid < T) {
        int i = tid / KTOP_, j = tid % KTOP_;
        int p = tk_i[(size_t)(b * N + i) * KTOP_ + j];
        float s = tk_s[(size_t)(b * N + i) * KTOP_ + j];
        size_t bp = (size_t)b * P + p;
        float bs = bt_score[bp];
        int bj = btcb_idx[bp] & 0xFFFF;
        float conf1 = (bs < T1_) ? 0.f : targets[(size_t)(b * N + bj) * 5 + 4];
        sh_p[tid] = p; sh_s[tid] = s;
        sh_c[tid] = (conf1 < 1.f && s > 0.f) ? 1 : 0;
    }
    __syncthreads();
    if (tid < T && sh_c[tid]) {
        int p = sh_p[tid];
        bool last = true;
        for (int t2 = tid + 1; t2 < T; t2++) {
            if (sh_c[t2] && sh_p[t2] == p) { last = false; break; }
        }
        if (last) {
            size_t bp = (size_t)b * P + p;
            cb_idx2[bp] = tid / KTOP_;
            c_score[bp] = sh_s[tid];
        }
    }
}

// ---------------- K4: per-element losses + block partial sums ----------------
__global__ void k_loss(const float4* __restrict__ loc4, const float* __restrict__ conf,
                       const float4* __restrict__ priors4, const float* __restrict__ targets,
                       const float* __restrict__ bt_score, const int* __restrict__ btcb_idx,
                       const int* __restrict__ cb_idx2,
                       const float* __restrict__ c_score,
                       double* __restrict__ partials,
                       int P, int N, int C) {
    int b = blockIdx.y;
    int i = blockIdx.x * blockDim.x + threadIdx.x;
    double l1 = 0.0, l2 = 0.0, f1 = 0.0, f2 = 0.0;
    int n1 = 0, n2 = 0;
    if (i < P) {
        size_t bp = (size_t)b * P + i;
        float bs = bt_score[bp];
        int widx = btcb_idx[bp];
        int bj = widx & 0xFFFF;
        int hadCand = (widx >> 16) & 1;          // == (c_bp_score >= T2)
        float cs = c_score[bp];
        int cj = (cs > 0.f) ? cb_idx2[bp] : 0;   // only observable when cs >= T2
        float lab1 = targets[(size_t)(b * N + bj) * 5 + 4];
        float conf1 = (bs < T1_) ? 0.f : lab1;
        if ((bs < T1_) && hadCand && (cs < T2_)) conf1 = -1.f;
        float lab2 = targets[(size_t)(b * N + cj) * 5 + 4];
        float conf2 = (cs < T2_) ? -1.f : lab2;
        bool m1 = conf1 > 0.f, m2 = conf2 > 0.f;
        n1 = m1 ? 1 : 0; n2 = m2 ? 1 : 0;

        float4 pr = priors4[i];
        float pcx = pr.x, pcy = pr.y, pw = pr.z, ph = pr.w;
        float4 lc = loc4[bp];
        float p0 = lc.x, p1 = lc.y, p2 = lc.z, p3 = lc.w;

        if (m1) {
            const float* tb = &targets[(size_t)(b * N + bj) * 5];
            float gx = ((tb[0] + tb[2]) * 0.5f - pcx) / (VAR0_ * pw);
            float gy = ((tb[1] + tb[3]) * 0.5f - pcy) / (VAR0_ * ph);
            float gw = logf((tb[2] - tb[0]) / pw) / VAR1_;
            float gh = logf((tb[3] - tb[1]) / ph) / VAR1_;
            l1 = (double)(sl1(p0 - gx) + sl1(p1 - gy) + sl1(p2 - gw) + sl1(p3 - gh));
        }
        if (m2) {
            const float* tb = &targets[(size_t)(b * N + cj) * 5];
            float gx = ((tb[0] + tb[2]) * 0.5f - pcx) / (VAR0_ * pw);
            float gy = ((tb[1] + tb[3]) * 0.5f - pcy) / (VAR0_ * ph);
            float gw = logf((tb[2] - tb[0]) / pw) / VAR1_;
            float gh = logf((tb[3] - tb[1]) / ph) / VAR1_;
            l2 = (double)(sl1(p0 - gx) + sl1(p1 - gy) + sl1(p2 - gw) + sl1(p3 - gh));
        }
        float x0, x1v;
        if (C == 2) {
            float2 cv2 = ((const float2*)conf)[bp];
            x0 = cv2.x; x1v = cv2.y;
        } else {
            x0 = conf[bp * C + 0]; x1v = conf[bp * C + 1];
        }
        {   // focal 1
            float t = fmaxf(conf1, 0.f);
            float keep = (conf1 >= 0.f) ? 1.f : 0.f;
            float x = (t >= 1.f) ? x1v : x0;
            float ce = fmaxf(x, 0.f) - x * t + log1pf(expf(-fabsf(x)));
            float a = t * ALPHA_ + (1.f - t) * (1.f - ALPHA_);
            float pr_ = 1.f / (1.f + expf(-x));
            float pt = (t == 1.f) ? pr_ : (1.f - pr_);
            float om = 1.f - pt;
            f1 = (double)(a * om * om * ce * keep);
        }
        {   // focal 2 (iou-weighted)
            float t = fmaxf(conf2, 0.f);
            float keep = (conf2 >= 0.f) ? 1.f : 0.f;
            float x = (t >= 1.f) ? x1v : x0;
            float ce = fmaxf(x, 0.f) - x * t + log1pf(expf(-fabsf(x)));
            float a = cs * (t * ALPHA_ + (1.f - t) * (1.f - ALPHA_));
            float pr_ = 1.f / (1.f + expf(-x));
            float pt = (t == 1.f) ? pr_ : (1.f - pr_);
            float om = 1.f - pt;
            f2 = (double)(a * om * om * ce * keep);
        }
    }
    int tid = threadIdx.x;
    int lane = tid & 63, wid = tid >> 6;
#pragma unroll
    for (int off = 32; off > 0; off >>= 1) {
        l1 += __shfl_xor(l1, off);
        l2 += __shfl_xor(l2, off);
        f1 += __shfl_xor(f1, off);
        f2 += __shfl_xor(f2, off);
        n1 += __shfl_xor(n1, off);
        n2 += __shfl_xor(n2, off);
    }
    __shared__ double swd[BS / 64][4];
    __shared__ int swn[BS / 64][2];
    if (lane == 0) {
        swd[wid][0] = l1; swd[wid][1] = l2; swd[wid][2] = f1; swd[wid][3] = f2;
        swn[wid][0] = n1; swn[wid][1] = n2;
    }
    __syncthreads();
    if (tid == 0) {
        double a0 = 0, a1 = 0, a2 = 0, a3 = 0; int b0 = 0, b1 = 0;
        for (int wv = 0; wv < BS / 64; wv++) {
            a0 += swd[wv][0]; a1 += swd[wv][1]; a2 += swd[wv][2]; a3 += swd[wv][3];
            b0 += swn[wv][0]; b1 += swn[wv][1];
        }
        int blk = blockIdx.y * gridDim.x + blockIdx.x;
        partials[(size_t)blk * 6 + 0] = a0;
        partials[(size_t)blk * 6 + 1] = a1;
        partials[(size_t)blk * 6 + 2] = a2;
        partials[(size_t)blk * 6 + 3] = a3;
        partials[(size_t)blk * 6 + 4] = (double)b0;
        partials[(size_t)blk * 6 + 5] = (double)b1;
    }
}

// ---------------- K5: final reduction + loss assembly ----------------
__global__ void k_final(const double* __restrict__ partials, int nPart, float* __restrict__ out) {
    int tid = threadIdx.x;
    double a[6] = {0, 0, 0, 0, 0, 0};
    for (int k = tid; k < nPart; k += BS) {
#pragma unroll
        for (int j = 0; j < 6; j++) a[j] += partials[(size_t)k * 6 + j];
    }
    __shared__ double sd[BS * 6];
#pragma unroll
    for (int j = 0; j < 6; j++) sd[tid * 6 + j] = a[j];
    __syncthreads();
    for (int s = BS / 2; s > 0; s >>= 1) {
        if (tid < s) {
#pragma unroll
            for (int j = 0; j < 6; j++) sd[tid * 6 + j] += sd[(tid + s) * 6 + j];
        }
        __syncthreads();
    }
    if (tid == 0) {
        double L1 = sd[0], L2 = sd[1], F1 = sd[2], F2 = sd[3], N1 = sd[4], N2 = sd[5];
        double l1v = L1 / fmax(N1, 1.0), l2v = L2 / fmax(N2, 1.0);
        double f1v = F1 / fmax(N1, 1.0), f2v = F2 / fmax(N2, 1.0);
        double locl = (N1 > 0 ? l1v : 0.0) + (N2 > 0 ? l2v : 0.0);
        double clsl = (N1 > 0 ? f1v : 0.0) + (N2 > 0 ? f2v : 0.0);
        if (N1 == 0 && N2 == 0) { locl = 1e-4; clsl = 1e-4; }
        out[0] = (float)locl;
        out[1] = (float)clsl;
    }
}

extern "C" void kernel_launch(void* const* d_in, const int* in_sizes, int n_in,
                              void* d_out, int out_size, void* d_ws, size_t ws_size,
                              hipStream_t stream) {
    const float* targets = (const float*)d_in[3];
    const float* conf = (const float*)d_in[1];
    const float4* loc4 = (const float4*)d_in[0];
    const float4* priors4 = (const float4*)d_in[2];

    int P = in_sizes[2] / 4;
    int B = in_sizes[0] / (P * 4);
    int N = in_sizes[3] / (B * 5);
    int C = in_sizes[1] / (B * P);
    const int CAP = 2048;
    size_t BP = (size_t)B * P;

    unsigned char* ws = (unsigned char*)d_ws;
    size_t off = 0;
    auto alloc = [&](size_t bytes) { size_t cur = off; off += (bytes + 255) & ~(size_t)255; return cur; };
    float* bt_score = (float*)(ws + alloc(BP * 4));
    int* btcb_idx = (int*)(ws + alloc(BP * 4));
    int* cb_idx2 = (int*)(ws + alloc(BP * 4));
    float* c_score = (float*)(ws + alloc(BP * 4));
    float* row_max = (float*)(ws + alloc((size_t)B * N * 4));
    int* row_arg = (int*)(ws + alloc((size_t)B * N * 4));
    float* part_max = (float*)(ws + alloc((size_t)B * N * RSPLIT * 4));
    int* part_arg = (int*)(ws + alloc((size_t)B * N * RSPLIT * 4));
    float* tk_s = (float*)(ws + alloc((size_t)B * N * KTOP_ * 4));
    int* tk_i = (int*)(ws + alloc((size_t)B * N * KTOP_ * 4));
    float* cand_v = (float*)(ws + alloc((size_t)B * N * CAP * 4));
    int* cand_i = (int*)(ws + alloc((size_t)B * N * CAP * 4));
    int* cand_cnt = (int*)(ws + alloc((size_t)B * N * 4));
    int bx = (P + BS - 1) / BS;
    double* partials = (double*)(ws + alloc((size_t)bx * B * 6 * 8));
    float* out = (float*)d_out;

    k_init<<<dim3((B * N + BS - 1) / BS), dim3(BS), 0, stream>>>(cand_cnt, B * N);
    dim3 g1(bx, B);
    k_per_prior<<<g1, BS, 0, stream>>>(loc4, priors4, targets, bt_score,
                                       btcb_idx, c_score, cand_v, cand_i, cand_cnt,
                                       P, N, CAP);
    k_row_max_part<<<dim3(N, B, RSPLIT), BS, 0, stream>>>(priors4, targets,
                                                          part_max, part_arg, P, N);
    k_row_max_fin<<<dim3(N, B), 64, 0, stream>>>(part_max, part_arg, row_max, row_arg, N);
    int maskWords = (P + 31) / 32;
    size_t shmem = (size_t)maskWords * 4;
    k_greedy<<<dim3(B), 64, shmem, stream>>>(priors4, targets, row_max, row_arg,
                                             bt_score, btcb_idx, P, N);
    k_topk<<<dim3(N, B), BS, 0, stream>>>(loc4, priors4, targets, cand_v, cand_i, cand_cnt,
                                          tk_s, tk_i, P, N, CAP);
    k_assign<<<dim3(B), BS, 0, stream>>>(targets, tk_s, tk_i, bt_score, btcb_idx,
                                         cb_idx2, c_score, P, N);
    k_loss<<<g1, BS, 0, stream>>>(loc4, conf, priors4, targets, bt_score, btcb_idx,
                                  cb_idx2, c_score, partials, P, N, C);
    k_final<<<1, BS, 0, stream>>>(partials, bx * B, out);
}

// Round 8
// 229.350 us; speedup vs baseline: 2.4244x; 1.0815x over previous
//
#include <hip/hip_runtime.h>
#include <cstdint>
#include <cstddef>

#define VAR0_ 0.1f
#define VAR1_ 0.2f
#define KTOP_ 5
#define T1_ 0.35f
#define T2_ 0.5f
#define ALPHA_ 0.25f
#define BETA_ 0.11f
#define BS 256
#define RSPLIT 8

__device__ __forceinline__ float sl1(float d) {
    float x = fabsf(d);
    return (x >= BETA_) ? (x - 0.5f * BETA_) : (0.5f * x * x / BETA_);
}

// ---------------- K0: zero candidate counters (tiny) ----------------
__global__ void k_init(int* __restrict__ cand_cnt, int nCnt) {
    int i = blockIdx.x * blockDim.x + threadIdx.x;
    if (i < nCnt) cand_cnt[i] = 0;
}

// ---------------- K1: per-prior stage-1 argmax + deferred harvest, ILP=2 ----------------
// Each thread handles priors i0 and i0+256: one LDS truth read feeds 4 indep
// IoU chains (round-7 was single-chain latency-bound at VALUBusy 53%).
// Outputs packed 16B/prior: {bt_score, bn|had<<16, cb_idx2(0), c_score(0)}.
// NOTE: partial unroll only — full unroll at N=32 spilled (round-4).
__global__ void k_per_prior(const float4* __restrict__ loc4, const float4* __restrict__ priors4,
                            const float* __restrict__ targets,
                            float4* __restrict__ recs4,
                            float* __restrict__ cand_v, int* __restrict__ cand_i,
                            int* __restrict__ cand_cnt,
                            int P, int N, int CAP) {
    int b = blockIdx.y;
    int iA = blockIdx.x * (BS * 2) + threadIdx.x;
    int iB = iA + BS;
    __shared__ float4 tr4[64];
    __shared__ float trA[64];
    for (int t = threadIdx.x; t < N; t += blockDim.x) {
        float x1 = targets[(size_t)(b * N + t) * 5 + 0];
        float y1 = targets[(size_t)(b * N + t) * 5 + 1];
        float x2 = targets[(size_t)(b * N + t) * 5 + 2];
        float y2 = targets[(size_t)(b * N + t) * 5 + 3];
        tr4[t] = make_float4(x1, y1, x2, y2);
        trA[t] = (x2 - x1) * (y2 - y1);
    }
    __syncthreads();
    bool vA = iA < P, vB = iB < P;
    if (!vA) return;

    float4 prA = priors4[iA];
    float4 prB = vB ? priors4[iB] : make_float4(0.f, 0.f, 1.f, 1.f);
    size_t bpA = (size_t)b * P + iA;
    size_t bpB = (size_t)b * P + iB;
    float4 lcA = loc4[bpA];
    float4 lcB = vB ? loc4[bpB] : make_float4(0.f, 0.f, 0.f, 0.f);

    // prior point-form A
    float pxA1 = prA.x - prA.z * 0.5f, pyA1 = prA.y - prA.w * 0.5f;
    float pxA2 = prA.x + prA.z * 0.5f, pyA2 = prA.y + prA.w * 0.5f;
    float paA = (pxA2 - pxA1) * (pyA2 - pyA1);
    // decode A
    float dcxA = prA.x + lcA.x * VAR0_ * prA.z;
    float dcyA = prA.y + lcA.y * VAR0_ * prA.w;
    float dwA = prA.z * expf(lcA.z * VAR1_);
    float dhA = prA.w * expf(lcA.w * VAR1_);
    float dxA1 = dcxA - dwA * 0.5f, dyA1 = dcyA - dhA * 0.5f;
    float dxA2 = dcxA + dwA * 0.5f, dyA2 = dcyA + dhA * 0.5f;
    float daA = (dxA2 - dxA1) * (dyA2 - dyA1);
    // prior point-form B
    float pxB1 = prB.x - prB.z * 0.5f, pyB1 = prB.y - prB.w * 0.5f;
    float pxB2 = prB.x + prB.z * 0.5f, pyB2 = prB.y + prB.w * 0.5f;
    float paB = (pxB2 - pxB1) * (pyB2 - pyB1);
    // decode B
    float dcxB = prB.x + lcB.x * VAR0_ * prB.z;
    float dcyB = prB.y + lcB.y * VAR0_ * prB.w;
    float dwB = prB.z * expf(lcB.z * VAR1_);
    float dhB = prB.w * expf(lcB.w * VAR1_);
    float dxB1 = dcxB - dwB * 0.5f, dyB1 = dcyB - dhB * 0.5f;
    float dxB2 = dcxB + dwB * 0.5f, dyB2 = dcyB + dhB * 0.5f;
    float daB = (dxB2 - dxB1) * (dyB2 - dyB1);

    float biA = -1.f, buA = 1.f; int bnA = 0;
    float biB = -1.f, buB = 1.f; int bnB = 0;
    unsigned long long hmA = 0ull, hmB = 0ull;
#pragma unroll 2
    for (int n = 0; n < N; n++) {
        float4 t4 = tr4[n];
        float ta = trA[n];
        // A stage-1
        {
            float lx = fmaxf(t4.x, pxA1), ly = fmaxf(t4.y, pyA1);
            float rx = fminf(t4.z, pxA2), ry = fminf(t4.w, pyA2);
            float w = fmaxf(rx - lx, 0.f), h = fmaxf(ry - ly, 0.f);
            float inter = w * h, uni = ta + paA - inter;
            bool bet = inter * buA > biA * uni;
            biA = bet ? inter : biA; buA = bet ? uni : buA; bnA = bet ? n : bnA;
        }
        // B stage-1
        {
            float lx = fmaxf(t4.x, pxB1), ly = fmaxf(t4.y, pyB1);
            float rx = fminf(t4.z, pxB2), ry = fminf(t4.w, pyB2);
            float w = fmaxf(rx - lx, 0.f), h = fmaxf(ry - ly, 0.f);
            float inter = w * h, uni = ta + paB - inter;
            bool bet = inter * buB > biB * uni;
            biB = bet ? inter : biB; buB = bet ? uni : buB; bnB = bet ? n : bnB;
        }
        // A stage-2 pretest
        {
            float lx = fmaxf(t4.x, dxA1), ly = fmaxf(t4.y, dyA1);
            float rx = fminf(t4.z, dxA2), ry = fminf(t4.w, dyA2);
            float w = fmaxf(rx - lx, 0.f), h = fmaxf(ry - ly, 0.f);
            float inter = w * h, uni = ta + daA - inter;
            if (inter >= uni * 0.4999990f) hmA |= (1ull << n);
        }
        // B stage-2 pretest
        {
            float lx = fmaxf(t4.x, dxB1), ly = fmaxf(t4.y, dyB1);
            float rx = fminf(t4.z, dxB2), ry = fminf(t4.w, dyB2);
            float w = fmaxf(rx - lx, 0.f), h = fmaxf(ry - ly, 0.f);
            float inter = w * h, uni = ta + daB - inter;
            if (inter >= uni * 0.4999990f) hmB |= (1ull << n);
        }
    }

    // deferred harvest A
    int hadA = 0;
    while (hmA) {
        int n = __ffsll((long long)hmA) - 1;
        hmA &= hmA - 1;
        float4 t4 = tr4[n];
        float lx = fmaxf(t4.x, dxA1), ly = fmaxf(t4.y, dyA1);
        float rx = fminf(t4.z, dxA2), ry = fminf(t4.w, dyA2);
        float w = fmaxf(rx - lx, 0.f), h = fmaxf(ry - ly, 0.f);
        float inter = w * h;
        float v = inter / (trA[n] + daA - inter);
        if (v >= T2_) {
            hadA = 1;
            int pos = atomicAdd(&cand_cnt[b * N + n], 1);
            if (pos < CAP) {
                size_t o = (size_t)(b * N + n) * CAP + pos;
                cand_v[o] = v; cand_i[o] = iA;
            }
        }
    }
    // deferred harvest B
    int hadB = 0;
    while (hmB) {
        int n = __ffsll((long long)hmB) - 1;
        hmB &= hmB - 1;
        float4 t4 = tr4[n];
        float lx = fmaxf(t4.x, dxB1), ly = fmaxf(t4.y, dyB1);
        float rx = fminf(t4.z, dxB2), ry = fminf(t4.w, dyB2);
        float w = fmaxf(rx - lx, 0.f), h = fmaxf(ry - ly, 0.f);
        float inter = w * h;
        float v = inter / (trA[n] + daB - inter);
        if (v >= T2_) {
            hadB = 1;
            int pos = atomicAdd(&cand_cnt[b * N + n], 1);
            if (pos < CAP) {
                size_t o = (size_t)(b * N + n) * CAP + pos;
                cand_v[o] = v; cand_i[o] = iB;
            }
        }
    }

    recs4[bpA] = make_float4(biA / buA, __int_as_float(bnA | (hadA << 16)),
                             __int_as_float(0), 0.f);
    if (vB)
        recs4[bpB] = make_float4(biB / buB, __int_as_float(bnB | (hadB << 16)),
                                 __int_as_float(0), 0.f);
}

// ---------------- K1b: per-(b,n) row max/argmax — split 8-ways, ILP=2 ----------------
__global__ void k_row_max_part(const float4* __restrict__ priors4, const float* __restrict__ targets,
                               float* __restrict__ part_max, int* __restrict__ part_arg,
                               int P, int N) {
    int n = blockIdx.x, b = blockIdx.y, s = blockIdx.z;
    int chunk = (P + RSPLIT - 1) / RSPLIT;
    int i0 = s * chunk;
    int i1 = min(P, i0 + chunk);
    float tx1 = targets[(size_t)(b * N + n) * 5 + 0];
    float ty1 = targets[(size_t)(b * N + n) * 5 + 1];
    float tx2 = targets[(size_t)(b * N + n) * 5 + 2];
    float ty2 = targets[(size_t)(b * N + n) * 5 + 3];
    float ta = (tx2 - tx1) * (ty2 - ty1);
    // dual independent chains for ILP
    float aI = -1.f, aU = 1.f; int aX = 0x7fffffff;
    float bI = -1.f, bU = 1.f; int bX = 0x7fffffff;
    int i = i0 + threadIdx.x;
    for (; i + BS < i1; i += 2 * BS) {
        {
            float4 pr = priors4[i];
            float px1 = pr.x - pr.z * 0.5f, py1 = pr.y - pr.w * 0.5f;
            float px2 = pr.x + pr.z * 0.5f, py2 = pr.y + pr.w * 0.5f;
            float lx = fmaxf(tx1, px1), ly = fmaxf(ty1, py1);
            float rx = fminf(tx2, px2), ry = fminf(ty2, py2);
            float w = fmaxf(rx - lx, 0.f), h = fmaxf(ry - ly, 0.f);
            float inter = w * h;
            float uni = ta + (px2 - px1) * (py2 - py1) - inter;
            bool bet = inter * aU > aI * uni;
            aI = bet ? inter : aI; aU = bet ? uni : aU; aX = bet ? i : aX;
        }
        {
            int j = i + BS;
            float4 pr = priors4[j];
            float px1 = pr.x - pr.z * 0.5f, py1 = pr.y - pr.w * 0.5f;
            float px2 = pr.x + pr.z * 0.5f, py2 = pr.y + pr.w * 0.5f;
            float lx = fmaxf(tx1, px1), ly = fmaxf(ty1, py1);
            float rx = fminf(tx2, px2), ry = fminf(ty2, py2);
            float w = fmaxf(rx - lx, 0.f), h = fmaxf(ry - ly, 0.f);
            float inter = w * h;
            float uni = ta + (px2 - px1) * (py2 - py1) - inter;
            bool bet = inter * bU > bI * uni;
            bI = bet ? inter : bI; bU = bet ? uni : bU; bX = bet ? j : bX;
        }
    }
    for (; i < i1; i += BS) {
        float4 pr = priors4[i];
        float px1 = pr.x - pr.z * 0.5f, py1 = pr.y - pr.w * 0.5f;
        float px2 = pr.x + pr.z * 0.5f, py2 = pr.y + pr.w * 0.5f;
        float lx = fmaxf(tx1, px1), ly = fmaxf(ty1, py1);
        float rx = fminf(tx2, px2), ry = fminf(ty2, py2);
        float w = fmaxf(rx - lx, 0.f), h = fmaxf(ry - ly, 0.f);
        float inter = w * h;
        float uni = ta + (px2 - px1) * (py2 - py1) - inter;
        bool bet = inter * aU > aI * uni;
        aI = bet ? inter : aI; aU = bet ? uni : aU; aX = bet ? i : aX;
    }
    // merge chains: value desc, idx asc (aX < bX always except init; compare fully)
    {
        bool bet = (bI * aU > aI * bU) || ((bI * aU == aI * bU) && (bX < aX));
        aI = bet ? bI : aI; aU = bet ? bU : aU; aX = bet ? bX : aX;
    }
    float bv = aI / aU;  // one divide; merge on rounded values (ref semantics)
    int tid = threadIdx.x;
    int lane = tid & 63, wid = tid >> 6;
#pragma unroll
    for (int off = 32; off > 0; off >>= 1) {
        float ov = __shfl_xor(bv, off);
        int oi = __shfl_xor(aX, off);
        if (ov > bv || (ov == bv && oi < aX)) { bv = ov; aX = oi; }
    }
    __shared__ float swv[BS / 64];
    __shared__ int swi[BS / 64];
    if (lane == 0) { swv[wid] = bv; swi[wid] = aX; }
    __syncthreads();
    if (tid == 0) {
        float fv = swv[0]; int fi = swi[0];
        for (int wv = 1; wv < BS / 64; wv++) {
            if (swv[wv] > fv || (swv[wv] == fv && swi[wv] < fi)) { fv = swv[wv]; fi = swi[wv]; }
        }
        int o = (b * N + n) * RSPLIT + s;
        part_max[o] = fv; part_arg[o] = fi;
    }
}

// ---------------- K2: greedy matching — ONE WAVE per image; merges partials inline ----------------
__global__ void k_greedy(const float4* __restrict__ priors4, const float* __restrict__ targets,
                         const float* __restrict__ part_max, const int* __restrict__ part_arg,
                         float* __restrict__ recs, int P, int N) {
    int b = blockIdx.x;
    int lane = threadIdx.x;  // block == 1 wave of 64
    extern __shared__ unsigned int mask[];
    int maskWords = (P + 31) >> 5;
    for (int w = lane; w < maskWords; w += 64) mask[w] = 0u;

    float rmax = -2.f; int rarg = 0x7fffffff; int alive = 0;
    float tx1 = 0.f, ty1 = 0.f, tx2 = 0.f, ty2 = 0.f, ta = 0.f;
    if (lane < N) {
        // merge the 8 row partials (was k_row_max_fin)
        float bv = -2.f; int bi = 0x7fffffff;
        for (int s = 0; s < RSPLIT; s++) {
            int o = (b * N + lane) * RSPLIT + s;
            float v = part_max[o]; int ix = part_arg[o];
            if (v > bv || (v == bv && ix < bi)) { bv = v; bi = ix; }
        }
        rmax = bv; rarg = bi;
        alive = 1;
        tx1 = targets[(size_t)(b * N + lane) * 5 + 0];
        ty1 = targets[(size_t)(b * N + lane) * 5 + 1];
        tx2 = targets[(size_t)(b * N + lane) * 5 + 2];
        ty2 = targets[(size_t)(b * N + lane) * 5 + 3];
        ta = (tx2 - tx1) * (ty2 - ty1);
    }
    __syncthreads();

    for (int it = 0; it < N; it++) {
        float v = (lane < N && alive) ? rmax : -3.f;
        int idx = lane;
#pragma unroll
        for (int off = 32; off > 0; off >>= 1) {
            float ov = __shfl_xor(v, off);
            int oi = __shfl_xor(idx, off);
            if (ov > v || (ov == v && oi < idx)) { v = ov; idx = oi; }
        }
        int bj = idx;
        float bv = v;
        int sel = __shfl(rarg, bj);
        if (lane == bj) alive = 0;
        if (lane == 0) {
            float* base = recs + 4 * ((size_t)b * P + sel);
            int wrd = __float_as_int(base[1]);
            base[0] = bv;
            base[1] = __int_as_float((wrd & ~0xFFFF) | bj);  // preserve hadCand bit 16
            mask[sel >> 5] |= (1u << (sel & 31));
        }
        __syncthreads();

        unsigned long long coll = __ballot(lane < N && alive && rarg == sel);
        while (coll) {
            int r = __ffsll((long long)coll) - 1;
            coll &= coll - 1;
            float rx1 = __shfl(tx1, r), ry1 = __shfl(ty1, r);
            float rx2 = __shfl(tx2, r), ry2 = __shfl(ty2, r);
            float ra = __shfl(ta, r);
            float n_i = -2.f, n_u = 1.f; int ni = 0x7fffffff;
            for (int i = lane; i < P; i += 64) {
                if (mask[i >> 5] & (1u << (i & 31))) continue;
                float4 pr = priors4[i];
                float px1 = pr.x - pr.z * 0.5f, py1 = pr.y - pr.w * 0.5f;
                float px2 = pr.x + pr.z * 0.5f, py2 = pr.y + pr.w * 0.5f;
                float lx = fmaxf(rx1, px1), ly = fmaxf(ry1, py1);
                float rx = fminf(rx2, px2), ry = fminf(ry2, py2);
                float w = fmaxf(rx - lx, 0.f), h = fmaxf(ry - ly, 0.f);
                float inter = w * h;
                float uni = ra + (px2 - px1) * (py2 - py1) - inter;
                bool better = inter * n_u > n_i * uni;
                n_i = better ? inter : n_i; n_u = better ? uni : n_u; ni = better ? i : ni;
            }
            float nv = n_i / n_u;
#pragma unroll
            for (int off = 32; off > 0; off >>= 1) {
                float ov = __shfl_xor(nv, off);
                int oi = __shfl_xor(ni, off);
                if (ov > nv || (ov == nv && oi < ni)) { nv = ov; ni = oi; }
            }
            if (lane == r) { rmax = nv; rarg = ni; }
        }
        __syncthreads();
    }
}

// ---------------- K3: per-(b,n) top-5 of thresholded c_iou (lax.top_k semantics) ----------------
__global__ void k_topk(const float4* __restrict__ loc4, const float4* __restrict__ priors4,
                       const float* __restrict__ targets,
                       const float* __restrict__ cand_v, const int* __restrict__ cand_i,
                       const int* __restrict__ cand_cnt,
                       float* __restrict__ tk_s, int* __restrict__ tk_i,
                       int P, int N, int CAP) {
    int n = blockIdx.x, b = blockIdx.y;
    int row = b * N + n;
    int tid = threadIdx.x;

    float vals[KTOP_]; int ids[KTOP_];
#pragma unroll
    for (int k = 0; k < KTOP_; k++) { vals[k] = -1.f; ids[k] = 0x7fffffff; }

    int cnt = cand_cnt[row];
    if (cnt <= CAP) {
        for (int k = tid; k < cnt; k += blockDim.x) {
            float cv = cand_v[(size_t)row * CAP + k];
            int ci = cand_i[(size_t)row * CAP + k];
#pragma unroll
            for (int q = 0; q < KTOP_; q++) {
                bool better = (cv > vals[q]) || ((cv == vals[q]) && (ci < ids[q]));
                float tv = better ? cv : vals[q]; int ti = better ? ci : ids[q];
                cv = better ? vals[q] : cv; ci = better ? ids[q] : ci;
                vals[q] = tv; ids[q] = ti;
            }
        }
    } else {
        // deterministic fallback: full rescan of this row (overflowed candidate buffer)
        float tx1 = targets[(size_t)row * 5 + 0], ty1 = targets[(size_t)row * 5 + 1];
        float tx2 = targets[(size_t)row * 5 + 2], ty2 = targets[(size_t)row * 5 + 3];
        float ta = (tx2 - tx1) * (ty2 - ty1);
        for (int i = tid; i < P; i += blockDim.x) {
            float4 pr = priors4[i];
            size_t bp = (size_t)b * P + i;
            float4 lc = loc4[bp];
            float dcx = pr.x + lc.x * VAR0_ * pr.z;
            float dcy = pr.y + lc.y * VAR0_ * pr.w;
            float dw = pr.z * expf(lc.z * VAR1_);
            float dh = pr.w * expf(lc.w * VAR1_);
            float dx1 = dcx - dw * 0.5f, dy1 = dcy - dh * 0.5f;
            float dx2 = dcx + dw * 0.5f, dy2 = dcy + dh * 0.5f;
            float lx = fmaxf(tx1, dx1), ly = fmaxf(ty1, dy1);
            float rx = fminf(tx2, dx2), ry = fminf(ty2, dy2);
            float w = fmaxf(rx - lx, 0.f), h = fmaxf(ry - ly, 0.f);
            float inter = w * h;
            float uni = ta + (dx2 - dx1) * (dy2 - dy1) - inter;
            if (inter >= uni * 0.4999990f) {
                float v = inter / uni;
                if (v >= T2_) {
                    float cv = v; int ci = i;
#pragma unroll
                    for (int q = 0; q < KTOP_; q++) {
                        bool better = (cv > vals[q]) || ((cv == vals[q]) && (ci < ids[q]));
                        float tv = better ? cv : vals[q]; int ti = better ? ci : ids[q];
                        cv = better ? vals[q] : cv; ci = better ? ids[q] : ci;
                        vals[q] = tv; ids[q] = ti;
                    }
                }
            }
        }
    }

    __shared__ float mv[BS * KTOP_];
    __shared__ int mi[BS * KTOP_];
#pragma unroll
    for (int k = 0; k < KTOP_; k++) { mv[tid * KTOP_ + k] = vals[k]; mi[tid * KTOP_ + k] = ids[k]; }
    __syncthreads();
    for (int s = BS / 2; s > 0; s >>= 1) {
        if (tid < s) {
#pragma unroll
            for (int j = 0; j < KTOP_; j++) {
                float cv = mv[(tid + s) * KTOP_ + j];
                int ci = mi[(tid + s) * KTOP_ + j];
#pragma unroll
                for (int q = 0; q < KTOP_; q++) {
                    bool better = (cv > vals[q]) || ((cv == vals[q]) && (ci < ids[q]));
                    float tv = better ? cv : vals[q]; int ti = better ? ci : ids[q];
                    cv = better ? vals[q] : cv; ci = better ? ids[q] : ci;
                    vals[q] = tv; ids[q] = ti;
                }
            }
#pragma unroll
            for (int k = 0; k < KTOP_; k++) { mv[tid * KTOP_ + k] = vals[k]; mi[tid * KTOP_ + k] = ids[k]; }
        }
        __syncthreads();
    }
    if (tid == 0) {
#pragma unroll
        for (int k = 0; k < KTOP_; k++) {
            tk_s[(size_t)row * KTOP_ + k] = (vals[k] > 0.f) ? vals[k] : 0.f;
            tk_i[(size_t)row * KTOP_ + k] = (ids[k] == 0x7fffffff) ? 0 : ids[k];
        }
    }
}

// ---------------- K3b: assign loop, parallel last-writer-wins ----------------
__global__ void k_assign(const float* __restrict__ targets,
                         const float* __restrict__ tk_s, const int* __restrict__ tk_i,
                         float* __restrict__ recs, int P, int N) {
    int b = blockIdx.x;
    int tid = threadIdx.x;
    int T = N * KTOP_;  // 160
    __shared__ int sh_p[512];
    __shared__ float sh_s[512];
    __shared__ int sh_c[512];
    if (tid < T) {
        int i = tid / KTOP_, j = tid % KTOP_;
        int p = tk_i[(size_t)(b * N + i) * KTOP_ + j];
        float s = tk_s[(size_t)(b * N + i) * KTOP_ + j];
        const float* base = recs + 4 * ((size_t)b * P + p);
        float bs = base[0];
        int bj = __float_as_int(base[1]) & 0xFFFF;
        float conf1 = (bs < T1_) ? 0.f : targets[(size_t)(b * N + bj) * 5 + 4];
        sh_p[tid] = p; sh_s[tid] = s;
        sh_c[tid] = (conf1 < 1.f && s > 0.f) ? 1 : 0;
    }
    __syncthreads();
    if (tid < T && sh_c[tid]) {
        int p = sh_p[tid];
        bool last = true;
        for (int t2 = tid + 1; t2 < T; t2++) {
            if (sh_c[t2] && sh_p[t2] == p) { last = false; break; }
        }
        if (last) {
            float* base = recs + 4 * ((size_t)b * P + p);
            base[2] = __int_as_float(tid / KTOP_);
            base[3] = sh_s[tid];
        }
    }
}

// ---------------- K4: per-element losses + block partial sums ----------------
__global__ void k_loss(const float4* __restrict__ loc4, const float* __restrict__ conf,
                       const float4* __restrict__ priors4, const float* __restrict__ targets,
                       const float4* __restrict__ recs4,
                       double* __restrict__ partials,
                       int P, int N, int C) {
    int b = blockIdx.y;
    int i = blockIdx.x * blockDim.x + threadIdx.x;
    double l1 = 0.0, l2 = 0.0, f1 = 0.0, f2 = 0.0;
    int n1 = 0, n2 = 0;
    if (i < P) {
        size_t bp = (size_t)b * P + i;
        float4 r = recs4[bp];             // one 16B load: {bt_score, btcb, cb_idx2, c_score}
        float bs = r.x;
        int widx = __float_as_int(r.y);
        int bj = widx & 0xFFFF;
        int hadCand = (widx >> 16) & 1;   // == (c_bp_score >= T2)
        float cs = r.w;
        int cj = (cs > 0.f) ? __float_as_int(r.z) : 0;
        float lab1 = targets[(size_t)(b * N + bj) * 5 + 4];
        float conf1 = (bs < T1_) ? 0.f : lab1;
        if ((bs < T1_) && hadCand && (cs < T2_)) conf1 = -1.f;
        float lab2 = targets[(size_t)(b * N + cj) * 5 + 4];
        float conf2 = (cs < T2_) ? -1.f : lab2;
        bool m1 = conf1 > 0.f, m2 = conf2 > 0.f;
        n1 = m1 ? 1 : 0; n2 = m2 ? 1 : 0;

        float4 pr = priors4[i];
        float pcx = pr.x, pcy = pr.y, pw = pr.z, ph = pr.w;
        float4 lc = loc4[bp];
        float p0 = lc.x, p1 = lc.y, p2 = lc.z, p3 = lc.w;

        if (m1) {
            const float* tb = &targets[(size_t)(b * N + bj) * 5];
            float gx = ((tb[0] + tb[2]) * 0.5f - pcx) / (VAR0_ * pw);
            float gy = ((tb[1] + tb[3]) * 0.5f - pcy) / (VAR0_ * ph);
            float gw = logf((tb[2] - tb[0]) / pw) / VAR1_;
            float gh = logf((tb[3] - tb[1]) / ph) / VAR1_;
            l1 = (double)(sl1(p0 - gx) + sl1(p1 - gy) + sl1(p2 - gw) + sl1(p3 - gh));
        }
        if (m2) {
            const float* tb = &targets[(size_t)(b * N + cj) * 5];
            float gx = ((tb[0] + tb[2]) * 0.5f - pcx) / (VAR0_ * pw);
            float gy = ((tb[1] + tb[3]) * 0.5f - pcy) / (VAR0_ * ph);
            float gw = logf((tb[2] - tb[0]) / pw) / VAR1_;
            float gh = logf((tb[3] - tb[1]) / ph) / VAR1_;
            l2 = (double)(sl1(p0 - gx) + sl1(p1 - gy) + sl1(p2 - gw) + sl1(p3 - gh));
        }
        float x0, x1v;
        if (C == 2) {
            float2 cv2 = ((const float2*)conf)[bp];
            x0 = cv2.x; x1v = cv2.y;
        } else {
            x0 = conf[bp * C + 0]; x1v = conf[bp * C + 1];
        }
        {   // focal 1
            float t = fmaxf(conf1, 0.f);
            float keep = (conf1 >= 0.f) ? 1.f : 0.f;
            float x = (t >= 1.f) ? x1v : x0;
            float ce = fmaxf(x, 0.f) - x * t + log1pf(expf(-fabsf(x)));
            float a = t * ALPHA_ + (1.f - t) * (1.f - ALPHA_);
            float pr_ = 1.f / (1.f + expf(-x));
            float pt = (t == 1.f) ? pr_ : (1.f - pr_);
            float om = 1.f - pt;
            f1 = (double)(a * om * om * ce * keep);
        }
        {   // focal 2 (iou-weighted)
            float t = fmaxf(conf2, 0.f);
            float keep = (conf2 >= 0.f) ? 1.f : 0.f;
            float x = (t >= 1.f) ? x1v : x0;
            float ce = fmaxf(x, 0.f) - x * t + log1pf(expf(-fabsf(x)));
            float a = cs * (t * ALPHA_ + (1.f - t) * (1.f - ALPHA_));
            float pr_ = 1.f / (1.f + expf(-x));
            float pt = (t == 1.f) ? pr_ : (1.f - pr_);
            float om = 1.f - pt;
            f2 = (double)(a * om * om * ce * keep);
        }
    }
    int tid = threadIdx.x;
    int lane = tid & 63, wid = tid >> 6;
#pragma unroll
    for (int off = 32; off > 0; off >>= 1) {
        l1 += __shfl_xor(l1, off);
        l2 += __shfl_xor(l2, off);
        f1 += __shfl_xor(f1, off);
        f2 += __shfl_xor(f2, off);
        n1 += __shfl_xor(n1, off);
        n2 += __shfl_xor(n2, off);
    }
    __shared__ double swd[BS / 64][4];
    __shared__ int swn[BS / 64][2];
    if (lane == 0) {
        swd[wid][0] = l1; swd[wid][1] = l2; swd[wid][2] = f1; swd[wid][3] = f2;
        swn[wid][0] = n1; swn[wid][1] = n2;
    }
    __syncthreads();
    if (tid == 0) {
        double a0 = 0, a1 = 0, a2 = 0, a3 = 0; int b0 = 0, b1 = 0;
        for (int wv = 0; wv < BS / 64; wv++) {
            a0 += swd[wv][0]; a1 += swd[wv][1]; a2 += swd[wv][2]; a3 += swd[wv][3];
            b0 += swn[wv][0]; b1 += swn[wv][1];
        }
        int blk = blockIdx.y * gridDim.x + blockIdx.x;
        partials[(size_t)blk * 6 + 0] = a0;
        partials[(size_t)blk * 6 + 1] = a1;
        partials[(size_t)blk * 6 + 2] = a2;
        partials[(size_t)blk * 6 + 3] = a3;
        partials[(size_t)blk * 6 + 4] = (double)b0;
        partials[(size_t)blk * 6 + 5] = (double)b1;
    }
}

// ---------------- K5: final reduction + loss assembly ----------------
__global__ void k_final(const double* __restrict__ partials, int nPart, float* __restrict__ out) {
    int tid = threadIdx.x;
    double a[6] = {0, 0, 0, 0, 0, 0};
    for (int k = tid; k < nPart; k += BS) {
#pragma unroll
        for (int j = 0; j < 6; j++) a[j] += partials[(size_t)k * 6 + j];
    }
    __shared__ double sd[BS * 6];
#pragma unroll
    for (int j = 0; j < 6; j++) sd[tid * 6 + j] = a[j];
    __syncthreads();
    for (int s = BS / 2; s > 0; s >>= 1) {
        if (tid < s) {
#pragma unroll
            for (int j = 0; j < 6; j++) sd[tid * 6 + j] += sd[(tid + s) * 6 + j];
        }
        __syncthreads();
    }
    if (tid == 0) {
        double L1 = sd[0], L2 = sd[1], F1 = sd[2], F2 = sd[3], N1 = sd[4], N2 = sd[5];
        double l1v = L1 / fmax(N1, 1.0), l2v = L2 / fmax(N2, 1.0);
        double f1v = F1 / fmax(N1, 1.0), f2v = F2 / fmax(N2, 1.0);
        double locl = (N1 > 0 ? l1v : 0.0) + (N2 > 0 ? l2v : 0.0);
        double clsl = (N1 > 0 ? f1v : 0.0) + (N2 > 0 ? f2v : 0.0);
        if (N1 == 0 && N2 == 0) { locl = 1e-4; clsl = 1e-4; }
        out[0] = (float)locl;
        out[1] = (float)clsl;
    }
}

extern "C" void kernel_launch(void* const* d_in, const int* in_sizes, int n_in,
                              void* d_out, int out_size, void* d_ws, size_t ws_size,
                              hipStream_t stream) {
    const float* targets = (const float*)d_in[3];
    const float* conf = (const float*)d_in[1];
    const float4* loc4 = (const float4*)d_in[0];
    const float4* priors4 = (const float4*)d_in[2];

    int P = in_sizes[2] / 4;
    int B = in_sizes[0] / (P * 4);
    int N = in_sizes[3] / (B * 5);
    int C = in_sizes[1] / (B * P);
    const int CAP = 2048;
    size_t BP = (size_t)B * P;

    unsigned char* ws = (unsigned char*)d_ws;
    size_t off = 0;
    auto alloc = [&](size_t bytes) { size_t cur = off; off += (bytes + 255) & ~(size_t)255; return cur; };
    float* recs = (float*)(ws + alloc(BP * 16));      // packed {bt_score, btcb, cb_idx2, c_score}
    float* part_max = (float*)(ws + alloc((size_t)B * N * RSPLIT * 4));
    int* part_arg = (int*)(ws + alloc((size_t)B * N * RSPLIT * 4));
    float* tk_s = (float*)(ws + alloc((size_t)B * N * KTOP_ * 4));
    int* tk_i = (int*)(ws + alloc((size_t)B * N * KTOP_ * 4));
    float* cand_v = (float*)(ws + alloc((size_t)B * N * CAP * 4));
    int* cand_i = (int*)(ws + alloc((size_t)B * N * CAP * 4));
    int* cand_cnt = (int*)(ws + alloc((size_t)B * N * 4));
    int bx = (P + BS - 1) / BS;
    double* partials = (double*)(ws + alloc((size_t)bx * B * 6 * 8));
    float* out = (float*)d_out;

    k_init<<<dim3((B * N + BS - 1) / BS), dim3(BS), 0, stream>>>(cand_cnt, B * N);
    int bx2 = (P + BS * 2 - 1) / (BS * 2);
    k_per_prior<<<dim3(bx2, B), BS, 0, stream>>>(loc4, priors4, targets, (float4*)recs,
                                                 cand_v, cand_i, cand_cnt, P, N, CAP);
    k_row_max_part<<<dim3(N, B, RSPLIT), BS, 0, stream>>>(priors4, targets,
                                                          part_max, part_arg, P, N);
    int maskWords = (P + 31) / 32;
    size_t shmem = (size_t)maskWords * 4;
    k_greedy<<<dim3(B), 64, shmem, stream>>>(priors4, targets, part_max, part_arg,
                                             recs, P, N);
    k_topk<<<dim3(N, B), BS, 0, stream>>>(loc4, priors4, targets, cand_v, cand_i, cand_cnt,
                                          tk_s, tk_i, P, N, CAP);
    k_assign<<<dim3(B), BS, 0, stream>>>(targets, tk_s, tk_i, recs, P, N);
    k_loss<<<dim3(bx, B), BS, 0, stream>>>(loc4, conf, priors4, targets, (const float4*)recs,
                                           partials, P, N, C);
    k_final<<<1, BS, 0, stream>>>(partials, bx * B, out);
}

// Round 9
// 221.686 us; speedup vs baseline: 2.5082x; 1.0346x over previous
//
#include <hip/hip_runtime.h>
#include <cstdint>
#include <cstddef>

#define VAR0_ 0.1f
#define VAR1_ 0.2f
#define KTOP_ 5
#define T1_ 0.35f
#define T2_ 0.5f
#define ALPHA_ 0.25f
#define BETA_ 0.11f
#define BS 256
#define RSPLIT 8
#define ILP 4

__device__ __forceinline__ float sl1(float d) {
    float x = fabsf(d);
    return (x >= BETA_) ? (x - 0.5f * BETA_) : (0.5f * x * x / BETA_);
}

// ---------------- K0: zero candidate counters (tiny) ----------------
__global__ void k_init(int* __restrict__ cand_cnt, int nCnt) {
    int i = blockIdx.x * blockDim.x + threadIdx.x;
    if (i < nCnt) cand_cnt[i] = 0;
}

// ---------------- K1: per-prior stage-1 argmax + deferred harvest, ILP=4, two-phase ----------------
// Round-8 insight: 12800 waves over 8192 slots -> 1.56 residency rounds (tail).
// ILP=4 -> 6400 waves -> single round. Two-phase split keeps VGPR < 64 cliff.
// Pretest: inter >= (ta+da)*0.33330f (conservative form of v>=0.5 after /);
// exact divide re-test in deferred harvest keeps candidate set bit-identical.
__global__ void k_per_prior(const float4* __restrict__ loc4, const float4* __restrict__ priors4,
                            const float* __restrict__ targets,
                            float4* __restrict__ recs4,
                            float* __restrict__ cand_v, int* __restrict__ cand_i,
                            int* __restrict__ cand_cnt,
                            int P, int N, int CAP) {
    int b = blockIdx.y;
    int tid = threadIdx.x;
    int base = blockIdx.x * (BS * ILP) + tid;
    __shared__ float4 tr4[64];
    __shared__ float trA[64];
    __shared__ float trT[64];   // trA * 0.33330f
    for (int t = tid; t < N; t += BS) {
        float x1 = targets[(size_t)(b * N + t) * 5 + 0];
        float y1 = targets[(size_t)(b * N + t) * 5 + 1];
        float x2 = targets[(size_t)(b * N + t) * 5 + 2];
        float y2 = targets[(size_t)(b * N + t) * 5 + 3];
        tr4[t] = make_float4(x1, y1, x2, y2);
        float a = (x2 - x1) * (y2 - y1);
        trA[t] = a;
        trT[t] = a * 0.33330f;
    }
    __syncthreads();
    if (base >= P) return;

    int iv[ILP]; int val[ILP];
    float px1[ILP], py1[ILP], px2[ILP], py2[ILP], pa[ILP];
#pragma unroll
    for (int k = 0; k < ILP; k++) {
        int i = base + k * BS; iv[k] = i; val[k] = (i < P);
        float4 pr = val[k] ? priors4[i] : make_float4(0.f, 0.f, 1.f, 1.f);
        px1[k] = pr.x - pr.z * 0.5f; py1[k] = pr.y - pr.w * 0.5f;
        px2[k] = pr.x + pr.z * 0.5f; py2[k] = pr.y + pr.w * 0.5f;
        pa[k] = (px2[k] - px1[k]) * (py2[k] - py1[k]);
    }

    // phase A: stage-1 argmax (divide-free, first-max tiebreak)
    float bi[ILP], bu[ILP]; int bn[ILP];
#pragma unroll
    for (int k = 0; k < ILP; k++) { bi[k] = -1.f; bu[k] = 1.f; bn[k] = 0; }
#pragma unroll 2
    for (int n = 0; n < N; n++) {
        float4 t4 = tr4[n];
        float ta = trA[n];
#pragma unroll
        for (int k = 0; k < ILP; k++) {
            float lx = fmaxf(t4.x, px1[k]), ly = fmaxf(t4.y, py1[k]);
            float rx = fminf(t4.z, px2[k]), ry = fminf(t4.w, py2[k]);
            float w = fmaxf(rx - lx, 0.f), h = fmaxf(ry - ly, 0.f);
            float inter = w * h, uni = ta + pa[k] - inter;
            bool bet = inter * bu[k] > bi[k] * uni;
            bi[k] = bet ? inter : bi[k]; bu[k] = bet ? uni : bu[k]; bn[k] = bet ? n : bn[k];
        }
    }
    float bv[ILP];
#pragma unroll
    for (int k = 0; k < ILP; k++) bv[k] = bi[k] / bu[k];

    // phase B: decode (reload priors/locs; corners regs reused)
    float dx1[ILP], dy1[ILP], dx2[ILP], dy2[ILP], da[ILP], daC[ILP];
#pragma unroll
    for (int k = 0; k < ILP; k++) {
        float4 pr = val[k] ? priors4[iv[k]] : make_float4(0.f, 0.f, 1.f, 1.f);
        float4 lc = val[k] ? loc4[(size_t)b * P + iv[k]] : make_float4(0.f, 0.f, 0.f, 0.f);
        float dcx = pr.x + lc.x * VAR0_ * pr.z;
        float dcy = pr.y + lc.y * VAR0_ * pr.w;
        float dw = pr.z * expf(lc.z * VAR1_);
        float dh = pr.w * expf(lc.w * VAR1_);
        dx1[k] = dcx - dw * 0.5f; dy1[k] = dcy - dh * 0.5f;
        dx2[k] = dcx + dw * 0.5f; dy2[k] = dcy + dh * 0.5f;
        da[k] = (dx2[k] - dx1[k]) * (dy2[k] - dy1[k]);
        daC[k] = da[k] * 0.33330f;
    }
    unsigned long long hm[ILP];
#pragma unroll
    for (int k = 0; k < ILP; k++) hm[k] = 0ull;
#pragma unroll 2
    for (int n = 0; n < N; n++) {
        float4 t4 = tr4[n];
        float tt = trT[n];
#pragma unroll
        for (int k = 0; k < ILP; k++) {
            float lx = fmaxf(t4.x, dx1[k]), ly = fmaxf(t4.y, dy1[k]);
            float rx = fminf(t4.z, dx2[k]), ry = fminf(t4.w, dy2[k]);
            float w = fmaxf(rx - lx, 0.f), h = fmaxf(ry - ly, 0.f);
            float inter = w * h;
            if (inter >= tt + daC[k]) hm[k] |= (1ull << n);
        }
    }

    // deferred harvest (exact divide + atomic) + packed store
#pragma unroll
    for (int k = 0; k < ILP; k++) {
        if (!val[k]) continue;
        int had = 0;
        unsigned long long m = hm[k];
        while (m) {
            int n = __ffsll((long long)m) - 1;
            m &= m - 1;
            float4 t4 = tr4[n];
            float lx = fmaxf(t4.x, dx1[k]), ly = fmaxf(t4.y, dy1[k]);
            float rx = fminf(t4.z, dx2[k]), ry = fminf(t4.w, dy2[k]);
            float w = fmaxf(rx - lx, 0.f), h = fmaxf(ry - ly, 0.f);
            float inter = w * h;
            float v = inter / (trA[n] + da[k] - inter);
            if (v >= T2_) {
                had = 1;
                int pos = atomicAdd(&cand_cnt[b * N + n], 1);
                if (pos < CAP) {
                    size_t o = (size_t)(b * N + n) * CAP + pos;
                    cand_v[o] = v; cand_i[o] = iv[k];
                }
            }
        }
        recs4[(size_t)b * P + iv[k]] =
            make_float4(bv[k], __int_as_float(bn[k] | (had << 16)), __int_as_float(0), 0.f);
    }
}

// ---------------- K1b: per-(b,n) row max/argmax — split 8-ways, 4 chains ----------------
__global__ void k_row_max_part(const float4* __restrict__ priors4, const float* __restrict__ targets,
                               float* __restrict__ part_max, int* __restrict__ part_arg,
                               int P, int N) {
    int n = blockIdx.x, b = blockIdx.y, s = blockIdx.z;
    int chunk = (P + RSPLIT - 1) / RSPLIT;
    int i0 = s * chunk;
    int i1 = min(P, i0 + chunk);
    float tx1 = targets[(size_t)(b * N + n) * 5 + 0];
    float ty1 = targets[(size_t)(b * N + n) * 5 + 1];
    float tx2 = targets[(size_t)(b * N + n) * 5 + 2];
    float ty2 = targets[(size_t)(b * N + n) * 5 + 3];
    float ta = (tx2 - tx1) * (ty2 - ty1);
    float cI[4], cU[4]; int cX[4];
#pragma unroll
    for (int k = 0; k < 4; k++) { cI[k] = -1.f; cU[k] = 1.f; cX[k] = 0x7fffffff; }
    int i = i0 + threadIdx.x;
    for (; i + 3 * BS < i1; i += 4 * BS) {
#pragma unroll
        for (int k = 0; k < 4; k++) {
            int j = i + k * BS;
            float4 pr = priors4[j];
            float px1 = pr.x - pr.z * 0.5f, py1 = pr.y - pr.w * 0.5f;
            float px2 = pr.x + pr.z * 0.5f, py2 = pr.y + pr.w * 0.5f;
            float lx = fmaxf(tx1, px1), ly = fmaxf(ty1, py1);
            float rx = fminf(tx2, px2), ry = fminf(ty2, py2);
            float w = fmaxf(rx - lx, 0.f), h = fmaxf(ry - ly, 0.f);
            float inter = w * h;
            float uni = ta + (px2 - px1) * (py2 - py1) - inter;
            bool bet = inter * cU[k] > cI[k] * uni;
            cI[k] = bet ? inter : cI[k]; cU[k] = bet ? uni : cU[k]; cX[k] = bet ? j : cX[k];
        }
    }
    for (; i < i1; i += BS) {
        float4 pr = priors4[i];
        float px1 = pr.x - pr.z * 0.5f, py1 = pr.y - pr.w * 0.5f;
        float px2 = pr.x + pr.z * 0.5f, py2 = pr.y + pr.w * 0.5f;
        float lx = fmaxf(tx1, px1), ly = fmaxf(ty1, py1);
        float rx = fminf(tx2, px2), ry = fminf(ty2, py2);
        float w = fmaxf(rx - lx, 0.f), h = fmaxf(ry - ly, 0.f);
        float inter = w * h;
        float uni = ta + (px2 - px1) * (py2 - py1) - inter;
        bool bet = inter * cU[0] > cI[0] * uni;
        cI[0] = bet ? inter : cI[0]; cU[0] = bet ? uni : cU[0]; cX[0] = bet ? i : cX[0];
    }
    // merge chains (value desc via exact cross-products, idx asc)
#pragma unroll
    for (int k = 1; k < 4; k++) {
        float l = cI[k] * cU[0], r = cI[0] * cU[k];
        bool bet = (l > r) || ((l == r) && (cX[k] < cX[0]));
        cI[0] = bet ? cI[k] : cI[0]; cU[0] = bet ? cU[k] : cU[0]; cX[0] = bet ? cX[k] : cX[0];
    }
    float bv = cI[0] / cU[0];  // one divide; merge on rounded values (ref semantics)
    int bx = cX[0];
    int tid = threadIdx.x;
    int lane = tid & 63, wid = tid >> 6;
#pragma unroll
    for (int off = 32; off > 0; off >>= 1) {
        float ov = __shfl_xor(bv, off);
        int oi = __shfl_xor(bx, off);
        if (ov > bv || (ov == bv && oi < bx)) { bv = ov; bx = oi; }
    }
    __shared__ float swv[BS / 64];
    __shared__ int swi[BS / 64];
    if (lane == 0) { swv[wid] = bv; swi[wid] = bx; }
    __syncthreads();
    if (tid == 0) {
        float fv = swv[0]; int fi = swi[0];
        for (int wv = 1; wv < BS / 64; wv++) {
            if (swv[wv] > fv || (swv[wv] == fv && swi[wv] < fi)) { fv = swv[wv]; fi = swi[wv]; }
        }
        int o = (b * N + n) * RSPLIT + s;
        part_max[o] = fv; part_arg[o] = fi;
    }
}

// ---------------- K2: greedy matching — ONE WAVE per image; merges partials inline ----------------
__global__ void k_greedy(const float4* __restrict__ priors4, const float* __restrict__ targets,
                         const float* __restrict__ part_max, const int* __restrict__ part_arg,
                         float* __restrict__ recs, int P, int N) {
    int b = blockIdx.x;
    int lane = threadIdx.x;  // block == 1 wave of 64
    extern __shared__ unsigned int mask[];
    int maskWords = (P + 31) >> 5;
    for (int w = lane; w < maskWords; w += 64) mask[w] = 0u;

    float rmax = -2.f; int rarg = 0x7fffffff; int alive = 0;
    float tx1 = 0.f, ty1 = 0.f, tx2 = 0.f, ty2 = 0.f, ta = 0.f;
    if (lane < N) {
        float bv = -2.f; int bi = 0x7fffffff;
        for (int s = 0; s < RSPLIT; s++) {
            int o = (b * N + lane) * RSPLIT + s;
            float v = part_max[o]; int ix = part_arg[o];
            if (v > bv || (v == bv && ix < bi)) { bv = v; bi = ix; }
        }
        rmax = bv; rarg = bi;
        alive = 1;
        tx1 = targets[(size_t)(b * N + lane) * 5 + 0];
        ty1 = targets[(size_t)(b * N + lane) * 5 + 1];
        tx2 = targets[(size_t)(b * N + lane) * 5 + 2];
        ty2 = targets[(size_t)(b * N + lane) * 5 + 3];
        ta = (tx2 - tx1) * (ty2 - ty1);
    }
    __syncthreads();

    for (int it = 0; it < N; it++) {
        float v = (lane < N && alive) ? rmax : -3.f;
        int idx = lane;
#pragma unroll
        for (int off = 32; off > 0; off >>= 1) {
            float ov = __shfl_xor(v, off);
            int oi = __shfl_xor(idx, off);
            if (ov > v || (ov == v && oi < idx)) { v = ov; idx = oi; }
        }
        int bj = idx;
        float bv = v;
        int sel = __shfl(rarg, bj);
        if (lane == bj) alive = 0;
        if (lane == 0) {
            float* base = recs + 4 * ((size_t)b * P + sel);
            int wrd = __float_as_int(base[1]);
            base[0] = bv;
            base[1] = __int_as_float((wrd & ~0xFFFF) | bj);  // preserve hadCand bit 16
            mask[sel >> 5] |= (1u << (sel & 31));
        }
        __syncthreads();

        unsigned long long coll = __ballot(lane < N && alive && rarg == sel);
        while (coll) {
            int r = __ffsll((long long)coll) - 1;
            coll &= coll - 1;
            float rx1 = __shfl(tx1, r), ry1 = __shfl(ty1, r);
            float rx2 = __shfl(tx2, r), ry2 = __shfl(ty2, r);
            float ra = __shfl(ta, r);
            float n_i = -2.f, n_u = 1.f; int ni = 0x7fffffff;
            for (int i = lane; i < P; i += 64) {
                if (mask[i >> 5] & (1u << (i & 31))) continue;
                float4 pr = priors4[i];
                float px1 = pr.x - pr.z * 0.5f, py1 = pr.y - pr.w * 0.5f;
                float px2 = pr.x + pr.z * 0.5f, py2 = pr.y + pr.w * 0.5f;
                float lx = fmaxf(rx1, px1), ly = fmaxf(ry1, py1);
                float rx = fminf(rx2, px2), ry = fminf(ry2, py2);
                float w = fmaxf(rx - lx, 0.f), h = fmaxf(ry - ly, 0.f);
                float inter = w * h;
                float uni = ra + (px2 - px1) * (py2 - py1) - inter;
                bool better = inter * n_u > n_i * uni;
                n_i = better ? inter : n_i; n_u = better ? uni : n_u; ni = better ? i : ni;
            }
            float nv = n_i / n_u;
#pragma unroll
            for (int off = 32; off > 0; off >>= 1) {
                float ov = __shfl_xor(nv, off);
                int oi = __shfl_xor(ni, off);
                if (ov > nv || (ov == nv && oi < ni)) { nv = ov; ni = oi; }
            }
            if (lane == r) { rmax = nv; rarg = ni; }
        }
        __syncthreads();
    }
}

// ---------------- K3: per-(b,n) top-5 of thresholded c_iou (lax.top_k semantics) ----------------
__global__ void k_topk(const float4* __restrict__ loc4, const float4* __restrict__ priors4,
                       const float* __restrict__ targets,
                       const float* __restrict__ cand_v, const int* __restrict__ cand_i,
                       const int* __restrict__ cand_cnt,
                       float* __restrict__ tk_s, int* __restrict__ tk_i,
                       int P, int N, int CAP) {
    int n = blockIdx.x, b = blockIdx.y;
    int row = b * N + n;
    int tid = threadIdx.x;

    float vals[KTOP_]; int ids[KTOP_];
#pragma unroll
    for (int k = 0; k < KTOP_; k++) { vals[k] = -1.f; ids[k] = 0x7fffffff; }

    int cnt = cand_cnt[row];
    if (cnt <= CAP) {
        for (int k = tid; k < cnt; k += blockDim.x) {
            float cv = cand_v[(size_t)row * CAP + k];
            int ci = cand_i[(size_t)row * CAP + k];
#pragma unroll
            for (int q = 0; q < KTOP_; q++) {
                bool better = (cv > vals[q]) || ((cv == vals[q]) && (ci < ids[q]));
                float tv = better ? cv : vals[q]; int ti = better ? ci : ids[q];
                cv = better ? vals[q] : cv; ci = better ? ids[q] : ci;
                vals[q] = tv; ids[q] = ti;
            }
        }
    } else {
        // deterministic fallback: full rescan of this row (overflowed candidate buffer)
        float tx1 = targets[(size_t)row * 5 + 0], ty1 = targets[(size_t)row * 5 + 1];
        float tx2 = targets[(size_t)row * 5 + 2], ty2 = targets[(size_t)row * 5 + 3];
        float ta = (tx2 - tx1) * (ty2 - ty1);
        for (int i = tid; i < P; i += blockDim.x) {
            float4 pr = priors4[i];
            size_t bp = (size_t)b * P + i;
            float4 lc = loc4[bp];
            float dcx = pr.x + lc.x * VAR0_ * pr.z;
            float dcy = pr.y + lc.y * VAR0_ * pr.w;
            float dw = pr.z * expf(lc.z * VAR1_);
            float dh = pr.w * expf(lc.w * VAR1_);
            float dx1 = dcx - dw * 0.5f, dy1 = dcy - dh * 0.5f;
            float dx2 = dcx + dw * 0.5f, dy2 = dcy + dh * 0.5f;
            float lx = fmaxf(tx1, dx1), ly = fmaxf(ty1, dy1);
            float rx = fminf(tx2, dx2), ry = fminf(ty2, dy2);
            float w = fmaxf(rx - lx, 0.f), h = fmaxf(ry - ly, 0.f);
            float inter = w * h;
            float uni = ta + (dx2 - dx1) * (dy2 - dy1) - inter;
            if (inter >= uni * 0.4999990f) {
                float v = inter / uni;
                if (v >= T2_) {
                    float cv = v; int ci = i;
#pragma unroll
                    for (int q = 0; q < KTOP_; q++) {
                        bool better = (cv > vals[q]) || ((cv == vals[q]) && (ci < ids[q]));
                        float tv = better ? cv : vals[q]; int ti = better ? ci : ids[q];
                        cv = better ? vals[q] : cv; ci = better ? ids[q] : ci;
                        vals[q] = tv; ids[q] = ti;
                    }
                }
            }
        }
    }

    __shared__ float mv[BS * KTOP_];
    __shared__ int mi[BS * KTOP_];
#pragma unroll
    for (int k = 0; k < KTOP_; k++) { mv[tid * KTOP_ + k] = vals[k]; mi[tid * KTOP_ + k] = ids[k]; }
    __syncthreads();
    for (int s = BS / 2; s > 0; s >>= 1) {
        if (tid < s) {
#pragma unroll
            for (int j = 0; j < KTOP_; j++) {
                float cv = mv[(tid + s) * KTOP_ + j];
                int ci = mi[(tid + s) * KTOP_ + j];
#pragma unroll
                for (int q = 0; q < KTOP_; q++) {
                    bool better = (cv > vals[q]) || ((cv == vals[q]) && (ci < ids[q]));
                    float tv = better ? cv : vals[q]; int ti = better ? ci : ids[q];
                    cv = better ? vals[q] : cv; ci = better ? ids[q] : ci;
                    vals[q] = tv; ids[q] = ti;
                }
            }
#pragma unroll
            for (int k = 0; k < KTOP_; k++) { mv[tid * KTOP_ + k] = vals[k]; mi[tid * KTOP_ + k] = ids[k]; }
        }
        __syncthreads();
    }
    if (tid == 0) {
#pragma unroll
        for (int k = 0; k < KTOP_; k++) {
            tk_s[(size_t)row * KTOP_ + k] = (vals[k] > 0.f) ? vals[k] : 0.f;
            tk_i[(size_t)row * KTOP_ + k] = (ids[k] == 0x7fffffff) ? 0 : ids[k];
        }
    }
}

// ---------------- K3b: assign loop, parallel last-writer-wins ----------------
__global__ void k_assign(const float* __restrict__ targets,
                         const float* __restrict__ tk_s, const int* __restrict__ tk_i,
                         float* __restrict__ recs, int P, int N) {
    int b = blockIdx.x;
    int tid = threadIdx.x;
    int T = N * KTOP_;  // 160
    __shared__ int sh_p[512];
    __shared__ float sh_s[512];
    __shared__ int sh_c[512];
    if (tid < T) {
        int i = tid / KTOP_, j = tid % KTOP_;
        int p = tk_i[(size_t)(b * N + i) * KTOP_ + j];
        float s = tk_s[(size_t)(b * N + i) * KTOP_ + j];
        const float* base = recs + 4 * ((size_t)b * P + p);
        float bs = base[0];
        int bj = __float_as_int(base[1]) & 0xFFFF;
        float conf1 = (bs < T1_) ? 0.f : targets[(size_t)(b * N + bj) * 5 + 4];
        sh_p[tid] = p; sh_s[tid] = s;
        sh_c[tid] = (conf1 < 1.f && s > 0.f) ? 1 : 0;
    }
    __syncthreads();
    if (tid < T && sh_c[tid]) {
        int p = sh_p[tid];
        bool last = true;
        for (int t2 = tid + 1; t2 < T; t2++) {
            if (sh_c[t2] && sh_p[t2] == p) { last = false; break; }
        }
        if (last) {
            float* base = recs + 4 * ((size_t)b * P + p);
            base[2] = __int_as_float(tid / KTOP_);
            base[3] = sh_s[tid];
        }
    }
}

// ---------------- K4: per-element losses + block partial sums ----------------
__global__ void k_loss(const float4* __restrict__ loc4, const float* __restrict__ conf,
                       const float4* __restrict__ priors4, const float* __restrict__ targets,
                       const float4* __restrict__ recs4,
                       double* __restrict__ partials,
                       int P, int N, int C) {
    int b = blockIdx.y;
    int i = blockIdx.x * blockDim.x + threadIdx.x;
    double l1 = 0.0, l2 = 0.0, f1 = 0.0, f2 = 0.0;
    int n1 = 0, n2 = 0;
    if (i < P) {
        size_t bp = (size_t)b * P + i;
        float4 r = recs4[bp];             // one 16B load: {bt_score, btcb, cb_idx2, c_score}
        float bs = r.x;
        int widx = __float_as_int(r.y);
        int bj = widx & 0xFFFF;
        int hadCand = (widx >> 16) & 1;   // == (c_bp_score >= T2)
        float cs = r.w;
        int cj = (cs > 0.f) ? __float_as_int(r.z) : 0;
        float lab1 = targets[(size_t)(b * N + bj) * 5 + 4];
        float conf1 = (bs < T1_) ? 0.f : lab1;
        if ((bs < T1_) && hadCand && (cs < T2_)) conf1 = -1.f;
        float lab2 = targets[(size_t)(b * N + cj) * 5 + 4];
        float conf2 = (cs < T2_) ? -1.f : lab2;
        bool m1 = conf1 > 0.f, m2 = conf2 > 0.f;
        n1 = m1 ? 1 : 0; n2 = m2 ? 1 : 0;

        float4 pr = priors4[i];
        float pcx = pr.x, pcy = pr.y, pw = pr.z, ph = pr.w;
        float4 lc = loc4[bp];
        float p0 = lc.x, p1 = lc.y, p2 = lc.z, p3 = lc.w;

        if (m1) {
            const float* tb = &targets[(size_t)(b * N + bj) * 5];
            float gx = ((tb[0] + tb[2]) * 0.5f - pcx) / (VAR0_ * pw);
            float gy = ((tb[1] + tb[3]) * 0.5f - pcy) / (VAR0_ * ph);
            float gw = logf((tb[2] - tb[0]) / pw) / VAR1_;
            float gh = logf((tb[3] - tb[1]) / ph) / VAR1_;
            l1 = (double)(sl1(p0 - gx) + sl1(p1 - gy) + sl1(p2 - gw) + sl1(p3 - gh));
        }
        if (m2) {
            const float* tb = &targets[(size_t)(b * N + cj) * 5];
            float gx = ((tb[0] + tb[2]) * 0.5f - pcx) / (VAR0_ * pw);
            float gy = ((tb[1] + tb[3]) * 0.5f - pcy) / (VAR0_ * ph);
            float gw = logf((tb[2] - tb[0]) / pw) / VAR1_;
            float gh = logf((tb[3] - tb[1]) / ph) / VAR1_;
            l2 = (double)(sl1(p0 - gx) + sl1(p1 - gy) + sl1(p2 - gw) + sl1(p3 - gh));
        }
        float x0, x1v;
        if (C == 2) {
            float2 cv2 = ((const float2*)conf)[bp];
            x0 = cv2.x; x1v = cv2.y;
        } else {
            x0 = conf[bp * C + 0]; x1v = conf[bp * C + 1];
        }
        {   // focal 1
            float t = fmaxf(conf1, 0.f);
            float keep = (conf1 >= 0.f) ? 1.f : 0.f;
            float x = (t >= 1.f) ? x1v : x0;
            float ce = fmaxf(x, 0.f) - x * t + log1pf(expf(-fabsf(x)));
            float a = t * ALPHA_ + (1.f - t) * (1.f - ALPHA_);
            float pr_ = 1.f / (1.f + expf(-x));
            float pt = (t == 1.f) ? pr_ : (1.f - pr_);
            float om = 1.f - pt;
            f1 = (double)(a * om * om * ce * keep);
        }
        {   // focal 2 (iou-weighted)
            float t = fmaxf(conf2, 0.f);
            float keep = (conf2 >= 0.f) ? 1.f : 0.f;
            float x = (t >= 1.f) ? x1v : x0;
            float ce = fmaxf(x, 0.f) - x * t + log1pf(expf(-fabsf(x)));
            float a = cs * (t * ALPHA_ + (1.f - t) * (1.f - ALPHA_));
            float pr_ = 1.f / (1.f + expf(-x));
            float pt = (t == 1.f) ? pr_ : (1.f - pr_);
            float om = 1.f - pt;
            f2 = (double)(a * om * om * ce * keep);
        }
    }
    int tid = threadIdx.x;
    int lane = tid & 63, wid = tid >> 6;
#pragma unroll
    for (int off = 32; off > 0; off >>= 1) {
        l1 += __shfl_xor(l1, off);
        l2 += __shfl_xor(l2, off);
        f1 += __shfl_xor(f1, off);
        f2 += __shfl_xor(f2, off);
        n1 += __shfl_xor(n1, off);
        n2 += __shfl_xor(n2, off);
    }
    __shared__ double swd[BS / 64][4];
    __shared__ int swn[BS / 64][2];
    if (lane == 0) {
        swd[wid][0] = l1; swd[wid][1] = l2; swd[wid][2] = f1; swd[wid][3] = f2;
        swn[wid][0] = n1; swn[wid][1] = n2;
    }
    __syncthreads();
    if (tid == 0) {
        double a0 = 0, a1 = 0, a2 = 0, a3 = 0; int b0 = 0, b1 = 0;
        for (int wv = 0; wv < BS / 64; wv++) {
            a0 += swd[wv][0]; a1 += swd[wv][1]; a2 += swd[wv][2]; a3 += swd[wv][3];
            b0 += swn[wv][0]; b1 += swn[wv][1];
        }
        int blk = blockIdx.y * gridDim.x + blockIdx.x;
        partials[(size_t)blk * 6 + 0] = a0;
        partials[(size_t)blk * 6 + 1] = a1;
        partials[(size_t)blk * 6 + 2] = a2;
        partials[(size_t)blk * 6 + 3] = a3;
        partials[(size_t)blk * 6 + 4] = (double)b0;
        partials[(size_t)blk * 6 + 5] = (double)b1;
    }
}

// ---------------- K5: final reduction + loss assembly ----------------
__global__ void k_final(const double* __restrict__ partials, int nPart, float* __restrict__ out) {
    int tid = threadIdx.x;
    double a[6] = {0, 0, 0, 0, 0, 0};
    for (int k = tid; k < nPart; k += BS) {
#pragma unroll
        for (int j = 0; j < 6; j++) a[j] += partials[(size_t)k * 6 + j];
    }
    __shared__ double sd[BS * 6];
#pragma unroll
    for (int j = 0; j < 6; j++) sd[tid * 6 + j] = a[j];
    __syncthreads();
    for (int s = BS / 2; s > 0; s >>= 1) {
        if (tid < s) {
#pragma unroll
            for (int j = 0; j < 6; j++) sd[tid * 6 + j] += sd[(tid + s) * 6 + j];
        }
        __syncthreads();
    }
    if (tid == 0) {
        double L1 = sd[0], L2 = sd[1], F1 = sd[2], F2 = sd[3], N1 = sd[4], N2 = sd[5];
        double l1v = L1 / fmax(N1, 1.0), l2v = L2 / fmax(N2, 1.0);
        double f1v = F1 / fmax(N1, 1.0), f2v = F2 / fmax(N2, 1.0);
        double locl = (N1 > 0 ? l1v : 0.0) + (N2 > 0 ? l2v : 0.0);
        double clsl = (N1 > 0 ? f1v : 0.0) + (N2 > 0 ? f2v : 0.0);
        if (N1 == 0 && N2 == 0) { locl = 1e-4; clsl = 1e-4; }
        out[0] = (float)locl;
        out[1] = (float)clsl;
    }
}

extern "C" void kernel_launch(void* const* d_in, const int* in_sizes, int n_in,
                              void* d_out, int out_size, void* d_ws, size_t ws_size,
                              hipStream_t stream) {
    const float* targets = (const float*)d_in[3];
    const float* conf = (const float*)d_in[1];
    const float4* loc4 = (const float4*)d_in[0];
    const float4* priors4 = (const float4*)d_in[2];

    int P = in_sizes[2] / 4;
    int B = in_sizes[0] / (P * 4);
    int N = in_sizes[3] / (B * 5);
    int C = in_sizes[1] / (B * P);
    const int CAP = 2048;
    size_t BP = (size_t)B * P;

    unsigned char* ws = (unsigned char*)d_ws;
    size_t off = 0;
    auto alloc = [&](size_t bytes) { size_t cur = off; off += (bytes + 255) & ~(size_t)255; return cur; };
    float* recs = (float*)(ws + alloc(BP * 16));      // packed {bt_score, btcb, cb_idx2, c_score}
    float* part_max = (float*)(ws + alloc((size_t)B * N * RSPLIT * 4));
    int* part_arg = (int*)(ws + alloc((size_t)B * N * RSPLIT * 4));
    float* tk_s = (float*)(ws + alloc((size_t)B * N * KTOP_ * 4));
    int* tk_i = (int*)(ws + alloc((size_t)B * N * KTOP_ * 4));
    float* cand_v = (float*)(ws + alloc((size_t)B * N * CAP * 4));
    int* cand_i = (int*)(ws + alloc((size_t)B * N * CAP * 4));
    int* cand_cnt = (int*)(ws + alloc((size_t)B * N * 4));
    int bx = (P + BS - 1) / BS;
    double* partials = (double*)(ws + alloc((size_t)bx * B * 6 * 8));
    float* out = (float*)d_out;

    k_init<<<dim3((B * N + BS - 1) / BS), dim3(BS), 0, stream>>>(cand_cnt, B * N);
    int bx4 = (P + BS * ILP - 1) / (BS * ILP);
    k_per_prior<<<dim3(bx4, B), BS, 0, stream>>>(loc4, priors4, targets, (float4*)recs,
                                                 cand_v, cand_i, cand_cnt, P, N, CAP);
    k_row_max_part<<<dim3(N, B, RSPLIT), BS, 0, stream>>>(priors4, targets,
                                                          part_max, part_arg, P, N);
    int maskWords = (P + 31) / 32;
    size_t shmem = (size_t)maskWords * 4;
    k_greedy<<<dim3(B), 64, shmem, stream>>>(priors4, targets, part_max, part_arg,
                                             recs, P, N);
    k_topk<<<dim3(N, B), BS, 0, stream>>>(loc4, priors4, targets, cand_v, cand_i, cand_cnt,
                                          tk_s, tk_i, P, N, CAP);
    k_assign<<<dim3(B), BS, 0, stream>>>(targets, tk_s, tk_i, recs, P, N);
    k_loss<<<dim3(bx, B), BS, 0, stream>>>(loc4, conf, priors4, targets, (const float4*)recs,
                                           partials, P, N, C);
    k_final<<<1, BS, 0, stream>>>(partials, bx * B, out);
}

// Round 10
// 213.559 us; speedup vs baseline: 2.6036x; 1.0381x over previous
//
#include <hip/hip_runtime.h>
#include <cstdint>
#include <cstddef>

#define VAR0_ 0.1f
#define VAR1_ 0.2f
#define KTOP_ 5
#define T1_ 0.35f
#define T2_ 0.5f
#define ALPHA_ 0.25f
#define BETA_ 0.11f
#define BS 256
#define BSK 128        // k_per_prior block size (finer blocks -> better CU balance)
#define NSPLIT 16      // row-max P splits
#define ILP 4

__device__ __forceinline__ float sl1(float d) {
    float x = fabsf(d);
    return (x >= BETA_) ? (x - 0.5f * BETA_) : (0.5f * x * x / BETA_);
}

// ---------------- K1: per-prior stage-1 argmax + deferred harvest, ILP=4, two-phase ----------------
// BS=128: 3200 blocks (12.5/CU) vs round-9's 1600 (6.25/CU, 40% occ, imbalance).
// Pretest: inter >= (ta+da)*0.33330f (conservative form of v>=0.5);
// exact divide re-test in deferred harvest keeps candidate set bit-identical.
__global__ void k_per_prior(const float4* __restrict__ loc4, const float4* __restrict__ priors4,
                            const float* __restrict__ targets,
                            float4* __restrict__ recs4,
                            float* __restrict__ cand_v, int* __restrict__ cand_i,
                            int* __restrict__ cand_cnt,
                            int P, int N, int CAP) {
    int b = blockIdx.y;
    int tid = threadIdx.x;
    int base = blockIdx.x * (BSK * ILP) + tid;
    __shared__ float4 tr4[64];
    __shared__ float trA[64];
    __shared__ float trT[64];   // trA * 0.33330f
    for (int t = tid; t < N; t += BSK) {
        float x1 = targets[(size_t)(b * N + t) * 5 + 0];
        float y1 = targets[(size_t)(b * N + t) * 5 + 1];
        float x2 = targets[(size_t)(b * N + t) * 5 + 2];
        float y2 = targets[(size_t)(b * N + t) * 5 + 3];
        tr4[t] = make_float4(x1, y1, x2, y2);
        float a = (x2 - x1) * (y2 - y1);
        trA[t] = a;
        trT[t] = a * 0.33330f;
    }
    __syncthreads();
    if (base >= P) return;

    int iv[ILP]; int val[ILP];
    float px1[ILP], py1[ILP], px2[ILP], py2[ILP], pa[ILP];
#pragma unroll
    for (int k = 0; k < ILP; k++) {
        int i = base + k * BSK; iv[k] = i; val[k] = (i < P);
        float4 pr = val[k] ? priors4[i] : make_float4(0.f, 0.f, 1.f, 1.f);
        px1[k] = pr.x - pr.z * 0.5f; py1[k] = pr.y - pr.w * 0.5f;
        px2[k] = pr.x + pr.z * 0.5f; py2[k] = pr.y + pr.w * 0.5f;
        pa[k] = (px2[k] - px1[k]) * (py2[k] - py1[k]);
    }

    // phase A: stage-1 argmax (divide-free, first-max tiebreak)
    float bi[ILP], bu[ILP]; int bn[ILP];
#pragma unroll
    for (int k = 0; k < ILP; k++) { bi[k] = -1.f; bu[k] = 1.f; bn[k] = 0; }
#pragma unroll 2
    for (int n = 0; n < N; n++) {
        float4 t4 = tr4[n];
        float ta = trA[n];
#pragma unroll
        for (int k = 0; k < ILP; k++) {
            float lx = fmaxf(t4.x, px1[k]), ly = fmaxf(t4.y, py1[k]);
            float rx = fminf(t4.z, px2[k]), ry = fminf(t4.w, py2[k]);
            float w = fmaxf(rx - lx, 0.f), h = fmaxf(ry - ly, 0.f);
            float inter = w * h, uni = ta + pa[k] - inter;
            bool bet = inter * bu[k] > bi[k] * uni;
            bi[k] = bet ? inter : bi[k]; bu[k] = bet ? uni : bu[k]; bn[k] = bet ? n : bn[k];
        }
    }
    float bv[ILP];
#pragma unroll
    for (int k = 0; k < ILP; k++) bv[k] = bi[k] / bu[k];

    // phase B: decode (reload priors/locs; corner regs reused)
    float dx1[ILP], dy1[ILP], dx2[ILP], dy2[ILP], da[ILP], daC[ILP];
#pragma unroll
    for (int k = 0; k < ILP; k++) {
        float4 pr = val[k] ? priors4[iv[k]] : make_float4(0.f, 0.f, 1.f, 1.f);
        float4 lc = val[k] ? loc4[(size_t)b * P + iv[k]] : make_float4(0.f, 0.f, 0.f, 0.f);
        float dcx = pr.x + lc.x * VAR0_ * pr.z;
        float dcy = pr.y + lc.y * VAR0_ * pr.w;
        float dw = pr.z * expf(lc.z * VAR1_);
        float dh = pr.w * expf(lc.w * VAR1_);
        dx1[k] = dcx - dw * 0.5f; dy1[k] = dcy - dh * 0.5f;
        dx2[k] = dcx + dw * 0.5f; dy2[k] = dcy + dh * 0.5f;
        da[k] = (dx2[k] - dx1[k]) * (dy2[k] - dy1[k]);
        daC[k] = da[k] * 0.33330f;
    }
    unsigned long long hm[ILP];
#pragma unroll
    for (int k = 0; k < ILP; k++) hm[k] = 0ull;
#pragma unroll 2
    for (int n = 0; n < N; n++) {
        float4 t4 = tr4[n];
        float tt = trT[n];
#pragma unroll
        for (int k = 0; k < ILP; k++) {
            float lx = fmaxf(t4.x, dx1[k]), ly = fmaxf(t4.y, dy1[k]);
            float rx = fminf(t4.z, dx2[k]), ry = fminf(t4.w, dy2[k]);
            float w = fmaxf(rx - lx, 0.f), h = fmaxf(ry - ly, 0.f);
            float inter = w * h;
            if (inter >= tt + daC[k]) hm[k] |= (1ull << n);
        }
    }

    // deferred harvest (exact divide + atomic) + packed store
#pragma unroll
    for (int k = 0; k < ILP; k++) {
        if (!val[k]) continue;
        int had = 0;
        unsigned long long m = hm[k];
        while (m) {
            int n = __ffsll((long long)m) - 1;
            m &= m - 1;
            float4 t4 = tr4[n];
            float lx = fmaxf(t4.x, dx1[k]), ly = fmaxf(t4.y, dy1[k]);
            float rx = fminf(t4.z, dx2[k]), ry = fminf(t4.w, dy2[k]);
            float w = fmaxf(rx - lx, 0.f), h = fmaxf(ry - ly, 0.f);
            float inter = w * h;
            float v = inter / (trA[n] + da[k] - inter);
            if (v >= T2_) {
                had = 1;
                int pos = atomicAdd(&cand_cnt[b * N + n], 1);
                if (pos < CAP) {
                    size_t o = (size_t)(b * N + n) * CAP + pos;
                    cand_v[o] = v; cand_i[o] = iv[k];
                }
            }
        }
        recs4[(size_t)b * P + iv[k]] =
            make_float4(bv[k], __int_as_float(bn[k] | (had << 16)), __int_as_float(0), 0.f);
    }
}

// ---------------- K1b: row max/argmax — block owns 4 truths x one P-chunk ----------------
// Round-10 restructure: each prior load feeds 4 indep IoU chains (was 1);
// prior L2 traffic /4 vs round-9 (each chunk read by B*ceil(N/4) blocks, not B*N).
__global__ void k_row_max_part(const float4* __restrict__ priors4, const float* __restrict__ targets,
                               float* __restrict__ part_max, int* __restrict__ part_arg,
                               int P, int N) {
    int s = blockIdx.x, b = blockIdx.y, g = blockIdx.z;
    int n0 = g * 4;
    int chunk = (P + NSPLIT - 1) / NSPLIT;
    int i0 = s * chunk;
    int i1 = min(P, i0 + chunk);
    float tx1[4], ty1[4], tx2[4], ty2[4], ta[4];
#pragma unroll
    for (int k = 0; k < 4; k++) {
        int n = min(n0 + k, N - 1);   // clamp; dup rows are discarded by guard below
        tx1[k] = targets[(size_t)(b * N + n) * 5 + 0];
        ty1[k] = targets[(size_t)(b * N + n) * 5 + 1];
        tx2[k] = targets[(size_t)(b * N + n) * 5 + 2];
        ty2[k] = targets[(size_t)(b * N + n) * 5 + 3];
        ta[k] = (tx2[k] - tx1[k]) * (ty2[k] - ty1[k]);
    }
    float cI[4], cU[4]; int cX[4];
#pragma unroll
    for (int k = 0; k < 4; k++) { cI[k] = -1.f; cU[k] = 1.f; cX[k] = 0x7fffffff; }
    for (int i = i0 + threadIdx.x; i < i1; i += BS) {
        float4 pr = priors4[i];
        float px1 = pr.x - pr.z * 0.5f, py1 = pr.y - pr.w * 0.5f;
        float px2 = pr.x + pr.z * 0.5f, py2 = pr.y + pr.w * 0.5f;
        float pa = (px2 - px1) * (py2 - py1);
#pragma unroll
        for (int k = 0; k < 4; k++) {
            float lx = fmaxf(tx1[k], px1), ly = fmaxf(ty1[k], py1);
            float rx = fminf(tx2[k], px2), ry = fminf(ty2[k], py2);
            float w = fmaxf(rx - lx, 0.f), h = fmaxf(ry - ly, 0.f);
            float inter = w * h;
            float uni = ta[k] + pa - inter;
            bool bet = inter * cU[k] > cI[k] * uni;  // strict >, i ascending -> smallest idx
            cI[k] = bet ? inter : cI[k]; cU[k] = bet ? uni : cU[k]; cX[k] = bet ? i : cX[k];
        }
    }
    int tid = threadIdx.x;
    int lane = tid & 63, wid = tid >> 6;
    __shared__ float swv[BS / 64];
    __shared__ int swi[BS / 64];
#pragma unroll
    for (int k = 0; k < 4; k++) {
        if (n0 + k >= N) break;
        float bv = cI[k] / cU[k];   // one divide; cross-thread merge on rounded (ref semantics)
        int bx = cX[k];
#pragma unroll
        for (int off = 32; off > 0; off >>= 1) {
            float ov = __shfl_xor(bv, off);
            int oi = __shfl_xor(bx, off);
            if (ov > bv || (ov == bv && oi < bx)) { bv = ov; bx = oi; }
        }
        if (lane == 0) { swv[wid] = bv; swi[wid] = bx; }
        __syncthreads();
        if (tid == 0) {
            float fv = swv[0]; int fi = swi[0];
            for (int wv = 1; wv < BS / 64; wv++) {
                if (swv[wv] > fv || (swv[wv] == fv && swi[wv] < fi)) { fv = swv[wv]; fi = swi[wv]; }
            }
            int o = (b * N + (n0 + k)) * NSPLIT + s;
            part_max[o] = fv; part_arg[o] = fi;
        }
        __syncthreads();
    }
}

// ---------------- K2: greedy matching — ONE WAVE per image; merges partials inline ----------------
__global__ void k_greedy(const float4* __restrict__ priors4, const float* __restrict__ targets,
                         const float* __restrict__ part_max, const int* __restrict__ part_arg,
                         float* __restrict__ recs, int P, int N) {
    int b = blockIdx.x;
    int lane = threadIdx.x;  // block == 1 wave of 64
    extern __shared__ unsigned int mask[];
    int maskWords = (P + 31) >> 5;
    for (int w = lane; w < maskWords; w += 64) mask[w] = 0u;

    float rmax = -2.f; int rarg = 0x7fffffff; int alive = 0;
    float tx1 = 0.f, ty1 = 0.f, tx2 = 0.f, ty2 = 0.f, ta = 0.f;
    if (lane < N) {
        float bv = -2.f; int bi = 0x7fffffff;
        for (int s = 0; s < NSPLIT; s++) {
            int o = (b * N + lane) * NSPLIT + s;
            float v = part_max[o]; int ix = part_arg[o];
            if (v > bv || (v == bv && ix < bi)) { bv = v; bi = ix; }
        }
        rmax = bv; rarg = bi;
        alive = 1;
        tx1 = targets[(size_t)(b * N + lane) * 5 + 0];
        ty1 = targets[(size_t)(b * N + lane) * 5 + 1];
        tx2 = targets[(size_t)(b * N + lane) * 5 + 2];
        ty2 = targets[(size_t)(b * N + lane) * 5 + 3];
        ta = (tx2 - tx1) * (ty2 - ty1);
    }
    __syncthreads();

    for (int it = 0; it < N; it++) {
        float v = (lane < N && alive) ? rmax : -3.f;
        int idx = lane;
#pragma unroll
        for (int off = 32; off > 0; off >>= 1) {
            float ov = __shfl_xor(v, off);
            int oi = __shfl_xor(idx, off);
            if (ov > v || (ov == v && oi < idx)) { v = ov; idx = oi; }
        }
        int bj = idx;
        float bv = v;
        int sel = __shfl(rarg, bj);
        if (lane == bj) alive = 0;
        if (lane == 0) {
            float* base = recs + 4 * ((size_t)b * P + sel);
            int wrd = __float_as_int(base[1]);
            base[0] = bv;
            base[1] = __int_as_float((wrd & ~0xFFFF) | bj);  // preserve hadCand bit 16
            mask[sel >> 5] |= (1u << (sel & 31));
        }
        __syncthreads();

        unsigned long long coll = __ballot(lane < N && alive && rarg == sel);
        while (coll) {
            int r = __ffsll((long long)coll) - 1;
            coll &= coll - 1;
            float rx1 = __shfl(tx1, r), ry1 = __shfl(ty1, r);
            float rx2 = __shfl(tx2, r), ry2 = __shfl(ty2, r);
            float ra = __shfl(ta, r);
            float n_i = -2.f, n_u = 1.f; int ni = 0x7fffffff;
            for (int i = lane; i < P; i += 64) {
                if (mask[i >> 5] & (1u << (i & 31))) continue;
                float4 pr = priors4[i];
                float px1 = pr.x - pr.z * 0.5f, py1 = pr.y - pr.w * 0.5f;
                float px2 = pr.x + pr.z * 0.5f, py2 = pr.y + pr.w * 0.5f;
                float lx = fmaxf(rx1, px1), ly = fmaxf(ry1, py1);
                float rx = fminf(rx2, px2), ry = fminf(ry2, py2);
                float w = fmaxf(rx - lx, 0.f), h = fmaxf(ry - ly, 0.f);
                float inter = w * h;
                float uni = ra + (px2 - px1) * (py2 - py1) - inter;
                bool better = inter * n_u > n_i * uni;
                n_i = better ? inter : n_i; n_u = better ? uni : n_u; ni = better ? i : ni;
            }
            float nv = n_i / n_u;
#pragma unroll
            for (int off = 32; off > 0; off >>= 1) {
                float ov = __shfl_xor(nv, off);
                int oi = __shfl_xor(ni, off);
                if (ov > nv || (ov == nv && oi < ni)) { nv = ov; ni = oi; }
            }
            if (lane == r) { rmax = nv; rarg = ni; }
        }
        __syncthreads();
    }
}

// ---------------- K3: per-(b,n) top-5 of thresholded c_iou (lax.top_k semantics) ----------------
__global__ void k_topk(const float4* __restrict__ loc4, const float4* __restrict__ priors4,
                       const float* __restrict__ targets,
                       const float* __restrict__ cand_v, const int* __restrict__ cand_i,
                       const int* __restrict__ cand_cnt,
                       float* __restrict__ tk_s, int* __restrict__ tk_i,
                       int P, int N, int CAP) {
    int n = blockIdx.x, b = blockIdx.y;
    int row = b * N + n;
    int tid = threadIdx.x;

    float vals[KTOP_]; int ids[KTOP_];
#pragma unroll
    for (int k = 0; k < KTOP_; k++) { vals[k] = -1.f; ids[k] = 0x7fffffff; }

    int cnt = cand_cnt[row];
    if (cnt <= CAP) {
        for (int k = tid; k < cnt; k += blockDim.x) {
            float cv = cand_v[(size_t)row * CAP + k];
            int ci = cand_i[(size_t)row * CAP + k];
#pragma unroll
            for (int q = 0; q < KTOP_; q++) {
                bool better = (cv > vals[q]) || ((cv == vals[q]) && (ci < ids[q]));
                float tv = better ? cv : vals[q]; int ti = better ? ci : ids[q];
                cv = better ? vals[q] : cv; ci = better ? ids[q] : ci;
                vals[q] = tv; ids[q] = ti;
            }
        }
    } else {
        // deterministic fallback: full rescan of this row (overflowed candidate buffer)
        float tx1 = targets[(size_t)row * 5 + 0], ty1 = targets[(size_t)row * 5 + 1];
        float tx2 = targets[(size_t)row * 5 + 2], ty2 = targets[(size_t)row * 5 + 3];
        float ta = (tx2 - tx1) * (ty2 - ty1);
        for (int i = tid; i < P; i += blockDim.x) {
            float4 pr = priors4[i];
            size_t bp = (size_t)b * P + i;
            float4 lc = loc4[bp];
            float dcx = pr.x + lc.x * VAR0_ * pr.z;
            float dcy = pr.y + lc.y * VAR0_ * pr.w;
            float dw = pr.z * expf(lc.z * VAR1_);
            float dh = pr.w * expf(lc.w * VAR1_);
            float dx1 = dcx - dw * 0.5f, dy1 = dcy - dh * 0.5f;
            float dx2 = dcx + dw * 0.5f, dy2 = dcy + dh * 0.5f;
            float lx = fmaxf(tx1, dx1), ly = fmaxf(ty1, dy1);
            float rx = fminf(tx2, dx2), ry = fminf(ty2, dy2);
            float w = fmaxf(rx - lx, 0.f), h = fmaxf(ry - ly, 0.f);
            float inter = w * h;
            float uni = ta + (dx2 - dx1) * (dy2 - dy1) - inter;
            if (inter >= uni * 0.4999990f) {
                float v = inter / uni;
                if (v >= T2_) {
                    float cv = v; int ci = i;
#pragma unroll
                    for (int q = 0; q < KTOP_; q++) {
                        bool better = (cv > vals[q]) || ((cv == vals[q]) && (ci < ids[q]));
                        float tv = better ? cv : vals[q]; int ti = better ? ci : ids[q];
                        cv = better ? vals[q] : cv; ci = better ? ids[q] : ci;
                        vals[q] = tv; ids[q] = ti;
                    }
                }
            }
        }
    }

    __shared__ float mv[BS * KTOP_];
    __shared__ int mi[BS * KTOP_];
#pragma unroll
    for (int k = 0; k < KTOP_; k++) { mv[tid * KTOP_ + k] = vals[k]; mi[tid * KTOP_ + k] = ids[k]; }
    __syncthreads();
    for (int s = BS / 2; s > 0; s >>= 1) {
        if (tid < s) {
#pragma unroll
            for (int j = 0; j < KTOP_; j++) {
                float cv = mv[(tid + s) * KTOP_ + j];
                int ci = mi[(tid + s) * KTOP_ + j];
#pragma unroll
                for (int q = 0; q < KTOP_; q++) {
                    bool better = (cv > vals[q]) || ((cv == vals[q]) && (ci < ids[q]));
                    float tv = better ? cv : vals[q]; int ti = better ? ci : ids[q];
                    cv = better ? vals[q] : cv; ci = better ? ids[q] : ci;
                    vals[q] = tv; ids[q] = ti;
                }
            }
#pragma unroll
            for (int k = 0; k < KTOP_; k++) { mv[tid * KTOP_ + k] = vals[k]; mi[tid * KTOP_ + k] = ids[k]; }
        }
        __syncthreads();
    }
    if (tid == 0) {
#pragma unroll
        for (int k = 0; k < KTOP_; k++) {
            tk_s[(size_t)row * KTOP_ + k] = (vals[k] > 0.f) ? vals[k] : 0.f;
            tk_i[(size_t)row * KTOP_ + k] = (ids[k] == 0x7fffffff) ? 0 : ids[k];
        }
    }
}

// ---------------- K3b: assign loop, parallel last-writer-wins ----------------
__global__ void k_assign(const float* __restrict__ targets,
                         const float* __restrict__ tk_s, const int* __restrict__ tk_i,
                         float* __restrict__ recs, int P, int N) {
    int b = blockIdx.x;
    int tid = threadIdx.x;
    int T = N * KTOP_;  // 160
    __shared__ int sh_p[512];
    __shared__ float sh_s[512];
    __shared__ int sh_c[512];
    if (tid < T) {
        int i = tid / KTOP_, j = tid % KTOP_;
        int p = tk_i[(size_t)(b * N + i) * KTOP_ + j];
        float s = tk_s[(size_t)(b * N + i) * KTOP_ + j];
        const float* base = recs + 4 * ((size_t)b * P + p);
        float bs = base[0];
        int bj = __float_as_int(base[1]) & 0xFFFF;
        float conf1 = (bs < T1_) ? 0.f : targets[(size_t)(b * N + bj) * 5 + 4];
        sh_p[tid] = p; sh_s[tid] = s;
        sh_c[tid] = (conf1 < 1.f && s > 0.f) ? 1 : 0;
    }
    __syncthreads();
    if (tid < T && sh_c[tid]) {
        int p = sh_p[tid];
        bool last = true;
        for (int t2 = tid + 1; t2 < T; t2++) {
            if (sh_c[t2] && sh_p[t2] == p) { last = false; break; }
        }
        if (last) {
            float* base = recs + 4 * ((size_t)b * P + p);
            base[2] = __int_as_float(tid / KTOP_);
            base[3] = sh_s[tid];
        }
    }
}

// ---------------- K4: per-element losses + block partial sums ----------------
__global__ void k_loss(const float4* __restrict__ loc4, const float* __restrict__ conf,
                       const float4* __restrict__ priors4, const float* __restrict__ targets,
                       const float4* __restrict__ recs4,
                       double* __restrict__ partials,
                       int P, int N, int C) {
    int b = blockIdx.y;
    int i = blockIdx.x * blockDim.x + threadIdx.x;
    double l1 = 0.0, l2 = 0.0, f1 = 0.0, f2 = 0.0;
    int n1 = 0, n2 = 0;
    if (i < P) {
        size_t bp = (size_t)b * P + i;
        float4 r = recs4[bp];             // one 16B load: {bt_score, btcb, cb_idx2, c_score}
        float bs = r.x;
        int widx = __float_as_int(r.y);
        int bj = widx & 0xFFFF;
        int hadCand = (widx >> 16) & 1;   // == (c_bp_score >= T2)
        float cs = r.w;
        int cj = (cs > 0.f) ? __float_as_int(r.z) : 0;
        float lab1 = targets[(size_t)(b * N + bj) * 5 + 4];
        float conf1 = (bs < T1_) ? 0.f : lab1;
        if ((bs < T1_) && hadCand && (cs < T2_)) conf1 = -1.f;
        float lab2 = targets[(size_t)(b * N + cj) * 5 + 4];
        float conf2 = (cs < T2_) ? -1.f : lab2;
        bool m1 = conf1 > 0.f, m2 = conf2 > 0.f;
        n1 = m1 ? 1 : 0; n2 = m2 ? 1 : 0;

        if (m1 || m2) {   // loc/priors only needed for smooth-l1 of matched priors (~2%)
            float4 pr = priors4[i];
            float pcx = pr.x, pcy = pr.y, pw = pr.z, ph = pr.w;
            float4 lc = loc4[bp];
            float p0 = lc.x, p1 = lc.y, p2 = lc.z, p3 = lc.w;
            if (m1) {
                const float* tb = &targets[(size_t)(b * N + bj) * 5];
                float gx = ((tb[0] + tb[2]) * 0.5f - pcx) / (VAR0_ * pw);
                float gy = ((tb[1] + tb[3]) * 0.5f - pcy) / (VAR0_ * ph);
                float gw = logf((tb[2] - tb[0]) / pw) / VAR1_;
                float gh = logf((tb[3] - tb[1]) / ph) / VAR1_;
                l1 = (double)(sl1(p0 - gx) + sl1(p1 - gy) + sl1(p2 - gw) + sl1(p3 - gh));
            }
            if (m2) {
                const float* tb = &targets[(size_t)(b * N + cj) * 5];
                float gx = ((tb[0] + tb[2]) * 0.5f - pcx) / (VAR0_ * pw);
                float gy = ((tb[1] + tb[3]) * 0.5f - pcy) / (VAR0_ * ph);
                float gw = logf((tb[2] - tb[0]) / pw) / VAR1_;
                float gh = logf((tb[3] - tb[1]) / ph) / VAR1_;
                l2 = (double)(sl1(p0 - gx) + sl1(p1 - gy) + sl1(p2 - gw) + sl1(p3 - gh));
            }
        }
        float x0, x1v;
        if (C == 2) {
            float2 cv2 = ((const float2*)conf)[bp];
            x0 = cv2.x; x1v = cv2.y;
        } else {
            x0 = conf[bp * C + 0]; x1v = conf[bp * C + 1];
        }
        {   // focal 1
            float t = fmaxf(conf1, 0.f);
            float keep = (conf1 >= 0.f) ? 1.f : 0.f;
            float x = (t >= 1.f) ? x1v : x0;
            float ce = fmaxf(x, 0.f) - x * t + log1pf(expf(-fabsf(x)));
            float a = t * ALPHA_ + (1.f - t) * (1.f - ALPHA_);
            float pr_ = 1.f / (1.f + expf(-x));
            float pt = (t == 1.f) ? pr_ : (1.f - pr_);
            float om = 1.f - pt;
            f1 = (double)(a * om * om * ce * keep);
        }
        {   // focal 2 (iou-weighted)
            float t = fmaxf(conf2, 0.f);
            float keep = (conf2 >= 0.f) ? 1.f : 0.f;
            float x = (t >= 1.f) ? x1v : x0;
            float ce = fmaxf(x, 0.f) - x * t + log1pf(expf(-fabsf(x)));
            float a = cs * (t * ALPHA_ + (1.f - t) * (1.f - ALPHA_));
            float pr_ = 1.f / (1.f + expf(-x));
            float pt = (t == 1.f) ? pr_ : (1.f - pr_);
            float om = 1.f - pt;
            f2 = (double)(a * om * om * ce * keep);
        }
    }
    int tid = threadIdx.x;
    int lane = tid & 63, wid = tid >> 6;
#pragma unroll
    for (int off = 32; off > 0; off >>= 1) {
        l1 += __shfl_xor(l1, off);
        l2 += __shfl_xor(l2, off);
        f1 += __shfl_xor(f1, off);
        f2 += __shfl_xor(f2, off);
        n1 += __shfl_xor(n1, off);
        n2 += __shfl_xor(n2, off);
    }
    __shared__ double swd[BS / 64][4];
    __shared__ int swn[BS / 64][2];
    if (lane == 0) {
        swd[wid][0] = l1; swd[wid][1] = l2; swd[wid][2] = f1; swd[wid][3] = f2;
        swn[wid][0] = n1; swn[wid][1] = n2;
    }
    __syncthreads();
    if (tid == 0) {
        double a0 = 0, a1 = 0, a2 = 0, a3 = 0; int b0 = 0, b1 = 0;
        for (int wv = 0; wv < BS / 64; wv++) {
            a0 += swd[wv][0]; a1 += swd[wv][1]; a2 += swd[wv][2]; a3 += swd[wv][3];
            b0 += swn[wv][0]; b1 += swn[wv][1];
        }
        int blk = blockIdx.y * gridDim.x + blockIdx.x;
        partials[(size_t)blk * 6 + 0] = a0;
        partials[(size_t)blk * 6 + 1] = a1;
        partials[(size_t)blk * 6 + 2] = a2;
        partials[(size_t)blk * 6 + 3] = a3;
        partials[(size_t)blk * 6 + 4] = (double)b0;
        partials[(size_t)blk * 6 + 5] = (double)b1;
    }
}

// ---------------- K5: final reduction + loss assembly ----------------
__global__ void k_final(const double* __restrict__ partials, int nPart, float* __restrict__ out) {
    int tid = threadIdx.x;
    double a[6] = {0, 0, 0, 0, 0, 0};
    for (int k = tid; k < nPart; k += BS) {
#pragma unroll
        for (int j = 0; j < 6; j++) a[j] += partials[(size_t)k * 6 + j];
    }
    __shared__ double sd[BS * 6];
#pragma unroll
    for (int j = 0; j < 6; j++) sd[tid * 6 + j] = a[j];
    __syncthreads();
    for (int s = BS / 2; s > 0; s >>= 1) {
        if (tid < s) {
#pragma unroll
            for (int j = 0; j < 6; j++) sd[tid * 6 + j] += sd[(tid + s) * 6 + j];
        }
        __syncthreads();
    }
    if (tid == 0) {
        double L1 = sd[0], L2 = sd[1], F1 = sd[2], F2 = sd[3], N1 = sd[4], N2 = sd[5];
        double l1v = L1 / fmax(N1, 1.0), l2v = L2 / fmax(N2, 1.0);
        double f1v = F1 / fmax(N1, 1.0), f2v = F2 / fmax(N2, 1.0);
        double locl = (N1 > 0 ? l1v : 0.0) + (N2 > 0 ? l2v : 0.0);
        double clsl = (N1 > 0 ? f1v : 0.0) + (N2 > 0 ? f2v : 0.0);
        if (N1 == 0 && N2 == 0) { locl = 1e-4; clsl = 1e-4; }
        out[0] = (float)locl;
        out[1] = (float)clsl;
    }
}

extern "C" void kernel_launch(void* const* d_in, const int* in_sizes, int n_in,
                              void* d_out, int out_size, void* d_ws, size_t ws_size,
                              hipStream_t stream) {
    const float* targets = (const float*)d_in[3];
    const float* conf = (const float*)d_in[1];
    const float4* loc4 = (const float4*)d_in[0];
    const float4* priors4 = (const float4*)d_in[2];

    int P = in_sizes[2] / 4;
    int B = in_sizes[0] / (P * 4);
    int N = in_sizes[3] / (B * 5);
    int C = in_sizes[1] / (B * P);
    const int CAP = 2048;
    size_t BP = (size_t)B * P;

    unsigned char* ws = (unsigned char*)d_ws;
    size_t off = 0;
    auto alloc = [&](size_t bytes) { size_t cur = off; off += (bytes + 255) & ~(size_t)255; return cur; };
    float* recs = (float*)(ws + alloc(BP * 16));      // packed {bt_score, btcb, cb_idx2, c_score}
    float* part_max = (float*)(ws + alloc((size_t)B * N * NSPLIT * 4));
    int* part_arg = (int*)(ws + alloc((size_t)B * N * NSPLIT * 4));
    float* tk_s = (float*)(ws + alloc((size_t)B * N * KTOP_ * 4));
    int* tk_i = (int*)(ws + alloc((size_t)B * N * KTOP_ * 4));
    float* cand_v = (float*)(ws + alloc((size_t)B * N * CAP * 4));
    int* cand_i = (int*)(ws + alloc((size_t)B * N * CAP * 4));
    int* cand_cnt = (int*)(ws + alloc((size_t)B * N * 4));
    int bx = (P + BS - 1) / BS;
    double* partials = (double*)(ws + alloc((size_t)bx * B * 6 * 8));
    float* out = (float*)d_out;

    hipMemsetAsync(cand_cnt, 0, (size_t)B * N * 4, stream);
    int bx4 = (P + BSK * ILP - 1) / (BSK * ILP);
    k_per_prior<<<dim3(bx4, B), BSK, 0, stream>>>(loc4, priors4, targets, (float4*)recs,
                                                  cand_v, cand_i, cand_cnt, P, N, CAP);
    int ngroup = (N + 3) / 4;
    k_row_max_part<<<dim3(NSPLIT, B, ngroup), BS, 0, stream>>>(priors4, targets,
                                                               part_max, part_arg, P, N);
    int maskWords = (P + 31) / 32;
    size_t shmem = (size_t)maskWords * 4;
    k_greedy<<<dim3(B), 64, shmem, stream>>>(priors4, targets, part_max, part_arg,
                                             recs, P, N);
    k_topk<<<dim3(N, B), BS, 0, stream>>>(loc4, priors4, targets, cand_v, cand_i, cand_cnt,
                                          tk_s, tk_i, P, N, CAP);
    k_assign<<<dim3(B), BS, 0, stream>>>(targets, tk_s, tk_i, recs, P, N);
    k_loss<<<dim3(bx, B), BS, 0, stream>>>(loc4, conf, priors4, targets, (const float4*)recs,
                                           partials, P, N, C);
    k_final<<<1, BS, 0, stream>>>(partials, bx * B, out);
}

// Round 11
// 213.557 us; speedup vs baseline: 2.6036x; 1.0000x over previous
//
#include <hip/hip_runtime.h>
#include <cstdint>
#include <cstddef>

#define VAR0_ 0.1f
#define VAR1_ 0.2f
#define KTOP_ 5
#define T1_ 0.35f
#define T2_ 0.5f
#define ALPHA_ 0.25f
#define BETA_ 0.11f
#define BS 256
#define BSK 128        // fat1 block size
#define NSPLIT 16      // row-max P splits
#define ILP 4

__device__ __forceinline__ float sl1(float d) {
    float x = fabsf(d);
    return (x >= BETA_) ? (x - 0.5f * BETA_) : (0.5f * x * x / BETA_);
}

// ---------------- FAT1: per_prior (blocks [0,bxPP)) ∥ row_max_part (rest) ----------------
// The two stages are data-independent; co-scheduling fills per_prior's idle
// issue slots (VALUBusy 59%) with row_max's memory-bound waves.
__global__ void k_fat1(const float4* __restrict__ loc4, const float4* __restrict__ priors4,
                       const float* __restrict__ targets,
                       float4* __restrict__ recs4,
                       float* __restrict__ cand_v, int* __restrict__ cand_i,
                       int* __restrict__ cand_cnt,
                       float* __restrict__ part_max, int* __restrict__ part_arg,
                       int P, int N, int CAP, int bxPP) {
    int b = blockIdx.y;
    int tid = threadIdx.x;
    if (blockIdx.x < bxPP) {
        // ===== per-prior: stage-1 argmax + deferred harvest, ILP=4, two-phase =====
        int base = blockIdx.x * (BSK * ILP) + tid;
        __shared__ float4 tr4[64];
        __shared__ float trA[64];
        __shared__ float trT[64];   // trA * 0.33330f
        for (int t = tid; t < N; t += BSK) {
            float x1 = targets[(size_t)(b * N + t) * 5 + 0];
            float y1 = targets[(size_t)(b * N + t) * 5 + 1];
            float x2 = targets[(size_t)(b * N + t) * 5 + 2];
            float y2 = targets[(size_t)(b * N + t) * 5 + 3];
            tr4[t] = make_float4(x1, y1, x2, y2);
            float a = (x2 - x1) * (y2 - y1);
            trA[t] = a;
            trT[t] = a * 0.33330f;
        }
        __syncthreads();
        if (base >= P) return;

        int iv[ILP]; int val[ILP];
        float px1[ILP], py1[ILP], px2[ILP], py2[ILP], pa[ILP];
#pragma unroll
        for (int k = 0; k < ILP; k++) {
            int i = base + k * BSK; iv[k] = i; val[k] = (i < P);
            float4 pr = val[k] ? priors4[i] : make_float4(0.f, 0.f, 1.f, 1.f);
            px1[k] = pr.x - pr.z * 0.5f; py1[k] = pr.y - pr.w * 0.5f;
            px2[k] = pr.x + pr.z * 0.5f; py2[k] = pr.y + pr.w * 0.5f;
            pa[k] = (px2[k] - px1[k]) * (py2[k] - py1[k]);
        }
        float bi[ILP], bu[ILP]; int bn[ILP];
#pragma unroll
        for (int k = 0; k < ILP; k++) { bi[k] = -1.f; bu[k] = 1.f; bn[k] = 0; }
#pragma unroll 2
        for (int n = 0; n < N; n++) {
            float4 t4 = tr4[n];
            float ta = trA[n];
#pragma unroll
            for (int k = 0; k < ILP; k++) {
                float lx = fmaxf(t4.x, px1[k]), ly = fmaxf(t4.y, py1[k]);
                float rx = fminf(t4.z, px2[k]), ry = fminf(t4.w, py2[k]);
                float w = fmaxf(rx - lx, 0.f), h = fmaxf(ry - ly, 0.f);
                float inter = w * h, uni = ta + pa[k] - inter;
                bool bet = inter * bu[k] > bi[k] * uni;
                bi[k] = bet ? inter : bi[k]; bu[k] = bet ? uni : bu[k]; bn[k] = bet ? n : bn[k];
            }
        }
        float bv[ILP];
#pragma unroll
        for (int k = 0; k < ILP; k++) bv[k] = bi[k] / bu[k];

        float dx1[ILP], dy1[ILP], dx2[ILP], dy2[ILP], da[ILP], daC[ILP];
#pragma unroll
        for (int k = 0; k < ILP; k++) {
            float4 pr = val[k] ? priors4[iv[k]] : make_float4(0.f, 0.f, 1.f, 1.f);
            float4 lc = val[k] ? loc4[(size_t)b * P + iv[k]] : make_float4(0.f, 0.f, 0.f, 0.f);
            float dcx = pr.x + lc.x * VAR0_ * pr.z;
            float dcy = pr.y + lc.y * VAR0_ * pr.w;
            float dw = pr.z * expf(lc.z * VAR1_);
            float dh = pr.w * expf(lc.w * VAR1_);
            dx1[k] = dcx - dw * 0.5f; dy1[k] = dcy - dh * 0.5f;
            dx2[k] = dcx + dw * 0.5f; dy2[k] = dcy + dh * 0.5f;
            da[k] = (dx2[k] - dx1[k]) * (dy2[k] - dy1[k]);
            daC[k] = da[k] * 0.33330f;
        }
        unsigned long long hm[ILP];
#pragma unroll
        for (int k = 0; k < ILP; k++) hm[k] = 0ull;
#pragma unroll 2
        for (int n = 0; n < N; n++) {
            float4 t4 = tr4[n];
            float tt = trT[n];
#pragma unroll
            for (int k = 0; k < ILP; k++) {
                float lx = fmaxf(t4.x, dx1[k]), ly = fmaxf(t4.y, dy1[k]);
                float rx = fminf(t4.z, dx2[k]), ry = fminf(t4.w, dy2[k]);
                float w = fmaxf(rx - lx, 0.f), h = fmaxf(ry - ly, 0.f);
                float inter = w * h;
                if (inter >= tt + daC[k]) hm[k] |= (1ull << n);
            }
        }
#pragma unroll
        for (int k = 0; k < ILP; k++) {
            if (!val[k]) continue;
            int had = 0;
            unsigned long long m = hm[k];
            while (m) {
                int n = __ffsll((long long)m) - 1;
                m &= m - 1;
                float4 t4 = tr4[n];
                float lx = fmaxf(t4.x, dx1[k]), ly = fmaxf(t4.y, dy1[k]);
                float rx = fminf(t4.z, dx2[k]), ry = fminf(t4.w, dy2[k]);
                float w = fmaxf(rx - lx, 0.f), h = fmaxf(ry - ly, 0.f);
                float inter = w * h;
                float v = inter / (trA[n] + da[k] - inter);
                if (v >= T2_) {
                    had = 1;
                    int pos = atomicAdd(&cand_cnt[b * N + n], 1);
                    if (pos < CAP) {
                        size_t o = (size_t)(b * N + n) * CAP + pos;
                        cand_v[o] = v; cand_i[o] = iv[k];
                    }
                }
            }
            recs4[(size_t)b * P + iv[k]] =
                make_float4(bv[k], __int_as_float(bn[k] | (had << 16)), __int_as_float(0), 0.f);
        }
    } else {
        // ===== row max/argmax: block owns 4 truths x one P-chunk, 4 indep chains =====
        int idx = blockIdx.x - bxPP;
        int s = idx % NSPLIT, g = idx / NSPLIT;
        int n0 = g * 4;
        int chunk = (P + NSPLIT - 1) / NSPLIT;
        int i0 = s * chunk;
        int i1 = min(P, i0 + chunk);
        float tx1[4], ty1[4], tx2[4], ty2[4], ta[4];
#pragma unroll
        for (int k = 0; k < 4; k++) {
            int n = min(n0 + k, N - 1);
            tx1[k] = targets[(size_t)(b * N + n) * 5 + 0];
            ty1[k] = targets[(size_t)(b * N + n) * 5 + 1];
            tx2[k] = targets[(size_t)(b * N + n) * 5 + 2];
            ty2[k] = targets[(size_t)(b * N + n) * 5 + 3];
            ta[k] = (tx2[k] - tx1[k]) * (ty2[k] - ty1[k]);
        }
        float cI[4], cU[4]; int cX[4];
#pragma unroll
        for (int k = 0; k < 4; k++) { cI[k] = -1.f; cU[k] = 1.f; cX[k] = 0x7fffffff; }
        for (int i = i0 + tid; i < i1; i += BSK) {
            float4 pr = priors4[i];
            float px1 = pr.x - pr.z * 0.5f, py1 = pr.y - pr.w * 0.5f;
            float px2 = pr.x + pr.z * 0.5f, py2 = pr.y + pr.w * 0.5f;
            float pa = (px2 - px1) * (py2 - py1);
#pragma unroll
            for (int k = 0; k < 4; k++) {
                float lx = fmaxf(tx1[k], px1), ly = fmaxf(ty1[k], py1);
                float rx = fminf(tx2[k], px2), ry = fminf(ty2[k], py2);
                float w = fmaxf(rx - lx, 0.f), h = fmaxf(ry - ly, 0.f);
                float inter = w * h;
                float uni = ta[k] + pa - inter;
                bool bet = inter * cU[k] > cI[k] * uni;  // strict >, i asc -> smallest idx
                cI[k] = bet ? inter : cI[k]; cU[k] = bet ? uni : cU[k]; cX[k] = bet ? i : cX[k];
            }
        }
        int lane = tid & 63, wid = tid >> 6;
        __shared__ float swv[BSK / 64];
        __shared__ int swi[BSK / 64];
#pragma unroll
        for (int k = 0; k < 4; k++) {
            if (n0 + k >= N) break;
            float bv = cI[k] / cU[k];   // one divide; merge on rounded values (ref semantics)
            int bx = cX[k];
#pragma unroll
            for (int off = 32; off > 0; off >>= 1) {
                float ov = __shfl_xor(bv, off);
                int oi = __shfl_xor(bx, off);
                if (ov > bv || (ov == bv && oi < bx)) { bv = ov; bx = oi; }
            }
            if (lane == 0) { swv[wid] = bv; swi[wid] = bx; }
            __syncthreads();
            if (tid == 0) {
                float fv = swv[0]; int fi = swi[0];
                for (int wv = 1; wv < BSK / 64; wv++) {
                    if (swv[wv] > fv || (swv[wv] == fv && swi[wv] < fi)) { fv = swv[wv]; fi = swi[wv]; }
                }
                int o = (b * N + (n0 + k)) * NSPLIT + s;
                part_max[o] = fv; part_arg[o] = fi;
            }
            __syncthreads();
        }
    }
}

// ---------------- FAT2: topk (blocks [0,N)) ∥ greedy (block N) ----------------
// Independent: topk reads cand buffers; greedy reads part_max, writes recs[0..1].
__global__ void k_fat2(const float4* __restrict__ loc4, const float4* __restrict__ priors4,
                       const float* __restrict__ targets,
                       const float* __restrict__ cand_v, const int* __restrict__ cand_i,
                       const int* __restrict__ cand_cnt,
                       float* __restrict__ tk_s, int* __restrict__ tk_i,
                       const float* __restrict__ part_max, const int* __restrict__ part_arg,
                       float* __restrict__ recs,
                       int P, int N, int CAP) {
    int b = blockIdx.y;
    int tid = threadIdx.x;
    if ((int)blockIdx.x < N) {
        // ===== top-5 of thresholded c_iou (lax.top_k semantics) =====
        int n = blockIdx.x;
        int row = b * N + n;
        float vals[KTOP_]; int ids[KTOP_];
#pragma unroll
        for (int k = 0; k < KTOP_; k++) { vals[k] = -1.f; ids[k] = 0x7fffffff; }
        int cnt = cand_cnt[row];
        if (cnt <= CAP) {
            for (int k = tid; k < cnt; k += blockDim.x) {
                float cv = cand_v[(size_t)row * CAP + k];
                int ci = cand_i[(size_t)row * CAP + k];
#pragma unroll
                for (int q = 0; q < KTOP_; q++) {
                    bool better = (cv > vals[q]) || ((cv == vals[q]) && (ci < ids[q]));
                    float tv = better ? cv : vals[q]; int ti = better ? ci : ids[q];
                    cv = better ? vals[q] : cv; ci = better ? ids[q] : ci;
                    vals[q] = tv; ids[q] = ti;
                }
            }
        } else {
            // deterministic fallback: full rescan (overflowed candidate buffer)
            float tx1 = targets[(size_t)row * 5 + 0], ty1 = targets[(size_t)row * 5 + 1];
            float tx2 = targets[(size_t)row * 5 + 2], ty2 = targets[(size_t)row * 5 + 3];
            float ta = (tx2 - tx1) * (ty2 - ty1);
            for (int i = tid; i < P; i += blockDim.x) {
                float4 pr = priors4[i];
                size_t bp = (size_t)b * P + i;
                float4 lc = loc4[bp];
                float dcx = pr.x + lc.x * VAR0_ * pr.z;
                float dcy = pr.y + lc.y * VAR0_ * pr.w;
                float dw = pr.z * expf(lc.z * VAR1_);
                float dh = pr.w * expf(lc.w * VAR1_);
                float dx1 = dcx - dw * 0.5f, dy1 = dcy - dh * 0.5f;
                float dx2 = dcx + dw * 0.5f, dy2 = dcy + dh * 0.5f;
                float lx = fmaxf(tx1, dx1), ly = fmaxf(ty1, dy1);
                float rx = fminf(tx2, dx2), ry = fminf(ty2, dy2);
                float w = fmaxf(rx - lx, 0.f), h = fmaxf(ry - ly, 0.f);
                float inter = w * h;
                float uni = ta + (dx2 - dx1) * (dy2 - dy1) - inter;
                if (inter >= uni * 0.4999990f) {
                    float v = inter / uni;
                    if (v >= T2_) {
                        float cv = v; int ci = i;
#pragma unroll
                        for (int q = 0; q < KTOP_; q++) {
                            bool better = (cv > vals[q]) || ((cv == vals[q]) && (ci < ids[q]));
                            float tv = better ? cv : vals[q]; int ti = better ? ci : ids[q];
                            cv = better ? vals[q] : cv; ci = better ? ids[q] : ci;
                            vals[q] = tv; ids[q] = ti;
                        }
                    }
                }
            }
        }
        __shared__ float mv[BS * KTOP_];
        __shared__ int mi[BS * KTOP_];
#pragma unroll
        for (int k = 0; k < KTOP_; k++) { mv[tid * KTOP_ + k] = vals[k]; mi[tid * KTOP_ + k] = ids[k]; }
        __syncthreads();
        for (int s = BS / 2; s > 0; s >>= 1) {
            if (tid < s) {
#pragma unroll
                for (int j = 0; j < KTOP_; j++) {
                    float cv = mv[(tid + s) * KTOP_ + j];
                    int ci = mi[(tid + s) * KTOP_ + j];
#pragma unroll
                    for (int q = 0; q < KTOP_; q++) {
                        bool better = (cv > vals[q]) || ((cv == vals[q]) && (ci < ids[q]));
                        float tv = better ? cv : vals[q]; int ti = better ? ci : ids[q];
                        cv = better ? vals[q] : cv; ci = better ? ids[q] : ci;
                        vals[q] = tv; ids[q] = ti;
                    }
                }
#pragma unroll
                for (int k = 0; k < KTOP_; k++) { mv[tid * KTOP_ + k] = vals[k]; mi[tid * KTOP_ + k] = ids[k]; }
            }
            __syncthreads();
        }
        if (tid == 0) {
#pragma unroll
            for (int k = 0; k < KTOP_; k++) {
                tk_s[(size_t)row * KTOP_ + k] = (vals[k] > 0.f) ? vals[k] : 0.f;
                tk_i[(size_t)row * KTOP_ + k] = (ids[k] == 0x7fffffff) ? 0 : ids[k];
            }
        }
    } else {
        // ===== greedy bipartite matching: wave 0 works, waves 1-3 mirror barriers =====
        int lane = tid & 63, wid = tid >> 6;
        extern __shared__ unsigned int mask[];
        int maskWords = (P + 31) >> 5;
        for (int w = tid; w < maskWords; w += BS) mask[w] = 0u;

        float rmax = -2.f; int rarg = 0x7fffffff; int alive = 0;
        float tx1 = 0.f, ty1 = 0.f, tx2 = 0.f, ty2 = 0.f, ta = 0.f;
        if (wid == 0 && lane < N) {
            float bv = -2.f; int bi = 0x7fffffff;
            for (int s = 0; s < NSPLIT; s++) {
                int o = (b * N + lane) * NSPLIT + s;
                float v = part_max[o]; int ix = part_arg[o];
                if (v > bv || (v == bv && ix < bi)) { bv = v; bi = ix; }
            }
            rmax = bv; rarg = bi;
            alive = 1;
            tx1 = targets[(size_t)(b * N + lane) * 5 + 0];
            ty1 = targets[(size_t)(b * N + lane) * 5 + 1];
            tx2 = targets[(size_t)(b * N + lane) * 5 + 2];
            ty2 = targets[(size_t)(b * N + lane) * 5 + 3];
            ta = (tx2 - tx1) * (ty2 - ty1);
        }
        __syncthreads();

        for (int it = 0; it < N; it++) {
            int sel = 0;
            if (wid == 0) {
                float v = (lane < N && alive) ? rmax : -3.f;
                int idx = lane;
#pragma unroll
                for (int off = 32; off > 0; off >>= 1) {
                    float ov = __shfl_xor(v, off);
                    int oi = __shfl_xor(idx, off);
                    if (ov > v || (ov == v && oi < idx)) { v = ov; idx = oi; }
                }
                int bj = idx;
                float bv = v;
                sel = __shfl(rarg, bj);
                if (lane == bj) alive = 0;
                if (lane == 0) {
                    float* base = recs + 4 * ((size_t)b * P + sel);
                    int wrd = __float_as_int(base[1]);
                    base[0] = bv;
                    base[1] = __int_as_float((wrd & ~0xFFFF) | bj);  // preserve hadCand bit 16
                    mask[sel >> 5] |= (1u << (sel & 31));
                }
            }
            __syncthreads();
            if (wid == 0) {
                unsigned long long coll = __ballot(lane < N && alive && rarg == sel);
                while (coll) {
                    int r = __ffsll((long long)coll) - 1;
                    coll &= coll - 1;
                    float rx1 = __shfl(tx1, r), ry1 = __shfl(ty1, r);
                    float rx2 = __shfl(tx2, r), ry2 = __shfl(ty2, r);
                    float ra = __shfl(ta, r);
                    float n_i = -2.f, n_u = 1.f; int ni = 0x7fffffff;
                    for (int i = lane; i < P; i += 64) {
                        if (mask[i >> 5] & (1u << (i & 31))) continue;
                        float4 pr = priors4[i];
                        float px1 = pr.x - pr.z * 0.5f, py1 = pr.y - pr.w * 0.5f;
                        float px2 = pr.x + pr.z * 0.5f, py2 = pr.y + pr.w * 0.5f;
                        float lx = fmaxf(rx1, px1), ly = fmaxf(ry1, py1);
                        float rx = fminf(rx2, px2), ry = fminf(ry2, py2);
                        float w = fmaxf(rx - lx, 0.f), h = fmaxf(ry - ly, 0.f);
                        float inter = w * h;
                        float uni = ra + (px2 - px1) * (py2 - py1) - inter;
                        bool better = inter * n_u > n_i * uni;
                        n_i = better ? inter : n_i; n_u = better ? uni : n_u; ni = better ? i : ni;
                    }
                    float nv = n_i / n_u;
#pragma unroll
                    for (int off = 32; off > 0; off >>= 1) {
                        float ov = __shfl_xor(nv, off);
                        int oi = __shfl_xor(ni, off);
                        if (ov > nv || (ov == nv && oi < ni)) { nv = ov; ni = oi; }
                    }
                    if (lane == r) { rmax = nv; rarg = ni; }
                }
            }
            __syncthreads();
        }
    }
}

// ---------------- K3b: assign loop, parallel last-writer-wins ----------------
__global__ void k_assign(const float* __restrict__ targets,
                         const float* __restrict__ tk_s, const int* __restrict__ tk_i,
                         float* __restrict__ recs, int P, int N) {
    int b = blockIdx.x;
    int tid = threadIdx.x;
    int T = N * KTOP_;  // 160
    __shared__ int sh_p[512];
    __shared__ float sh_s[512];
    __shared__ int sh_c[512];
    if (tid < T) {
        int i = tid / KTOP_, j = tid % KTOP_;
        int p = tk_i[(size_t)(b * N + i) * KTOP_ + j];
        float s = tk_s[(size_t)(b * N + i) * KTOP_ + j];
        const float* base = recs + 4 * ((size_t)b * P + p);
        float bs = base[0];
        int bj = __float_as_int(base[1]) & 0xFFFF;
        float conf1 = (bs < T1_) ? 0.f : targets[(size_t)(b * N + bj) * 5 + 4];
        sh_p[tid] = p; sh_s[tid] = s;
        sh_c[tid] = (conf1 < 1.f && s > 0.f) ? 1 : 0;
    }
    __syncthreads();
    if (tid < T && sh_c[tid]) {
        int p = sh_p[tid];
        bool last = true;
        for (int t2 = tid + 1; t2 < T; t2++) {
            if (sh_c[t2] && sh_p[t2] == p) { last = false; break; }
        }
        if (last) {
            float* base = recs + 4 * ((size_t)b * P + p);
            base[2] = __int_as_float(tid / KTOP_);
            base[3] = sh_s[tid];
        }
    }
}

// ---------------- K4: per-element losses + block partial sums ----------------
__global__ void k_loss(const float4* __restrict__ loc4, const float* __restrict__ conf,
                       const float4* __restrict__ priors4, const float* __restrict__ targets,
                       const float4* __restrict__ recs4,
                       double* __restrict__ partials,
                       int P, int N, int C) {
    int b = blockIdx.y;
    int i = blockIdx.x * blockDim.x + threadIdx.x;
    double l1 = 0.0, l2 = 0.0, f1 = 0.0, f2 = 0.0;
    int n1 = 0, n2 = 0;
    if (i < P) {
        size_t bp = (size_t)b * P + i;
        float4 r = recs4[bp];             // one 16B load: {bt_score, btcb, cb_idx2, c_score}
        float bs = r.x;
        int widx = __float_as_int(r.y);
        int bj = widx & 0xFFFF;
        int hadCand = (widx >> 16) & 1;   // == (c_bp_score >= T2)
        float cs = r.w;
        int cj = (cs > 0.f) ? __float_as_int(r.z) : 0;
        float lab1 = targets[(size_t)(b * N + bj) * 5 + 4];
        float conf1 = (bs < T1_) ? 0.f : lab1;
        if ((bs < T1_) && hadCand && (cs < T2_)) conf1 = -1.f;
        float lab2 = targets[(size_t)(b * N + cj) * 5 + 4];
        float conf2 = (cs < T2_) ? -1.f : lab2;
        bool m1 = conf1 > 0.f, m2 = conf2 > 0.f;
        n1 = m1 ? 1 : 0; n2 = m2 ? 1 : 0;

        if (m1 || m2) {   // loc/priors only needed for smooth-l1 of matched priors (~2%)
            float4 pr = priors4[i];
            float pcx = pr.x, pcy = pr.y, pw = pr.z, ph = pr.w;
            float4 lc = loc4[bp];
            float p0 = lc.x, p1 = lc.y, p2 = lc.z, p3 = lc.w;
            if (m1) {
                const float* tb = &targets[(size_t)(b * N + bj) * 5];
                float gx = ((tb[0] + tb[2]) * 0.5f - pcx) / (VAR0_ * pw);
                float gy = ((tb[1] + tb[3]) * 0.5f - pcy) / (VAR0_ * ph);
                float gw = logf((tb[2] - tb[0]) / pw) / VAR1_;
                float gh = logf((tb[3] - tb[1]) / ph) / VAR1_;
                l1 = (double)(sl1(p0 - gx) + sl1(p1 - gy) + sl1(p2 - gw) + sl1(p3 - gh));
            }
            if (m2) {
                const float* tb = &targets[(size_t)(b * N + cj) * 5];
                float gx = ((tb[0] + tb[2]) * 0.5f - pcx) / (VAR0_ * pw);
                float gy = ((tb[1] + tb[3]) * 0.5f - pcy) / (VAR0_ * ph);
                float gw = logf((tb[2] - tb[0]) / pw) / VAR1_;
                float gh = logf((tb[3] - tb[1]) / ph) / VAR1_;
                l2 = (double)(sl1(p0 - gx) + sl1(p1 - gy) + sl1(p2 - gw) + sl1(p3 - gh));
            }
        }
        float x0, x1v;
        if (C == 2) {
            float2 cv2 = ((const float2*)conf)[bp];
            x0 = cv2.x; x1v = cv2.y;
        } else {
            x0 = conf[bp * C + 0]; x1v = conf[bp * C + 1];
        }
        {   // focal 1
            float t = fmaxf(conf1, 0.f);
            float keep = (conf1 >= 0.f) ? 1.f : 0.f;
            float x = (t >= 1.f) ? x1v : x0;
            float ce = fmaxf(x, 0.f) - x * t + log1pf(expf(-fabsf(x)));
            float a = t * ALPHA_ + (1.f - t) * (1.f - ALPHA_);
            float pr_ = 1.f / (1.f + expf(-x));
            float pt = (t == 1.f) ? pr_ : (1.f - pr_);
            float om = 1.f - pt;
            f1 = (double)(a * om * om * ce * keep);
        }
        {   // focal 2 (iou-weighted)
            float t = fmaxf(conf2, 0.f);
            float keep = (conf2 >= 0.f) ? 1.f : 0.f;
            float x = (t >= 1.f) ? x1v : x0;
            float ce = fmaxf(x, 0.f) - x * t + log1pf(expf(-fabsf(x)));
            float a = cs * (t * ALPHA_ + (1.f - t) * (1.f - ALPHA_));
            float pr_ = 1.f / (1.f + expf(-x));
            float pt = (t == 1.f) ? pr_ : (1.f - pr_);
            float om = 1.f - pt;
            f2 = (double)(a * om * om * ce * keep);
        }
    }
    int tid = threadIdx.x;
    int lane = tid & 63, wid = tid >> 6;
#pragma unroll
    for (int off = 32; off > 0; off >>= 1) {
        l1 += __shfl_xor(l1, off);
        l2 += __shfl_xor(l2, off);
        f1 += __shfl_xor(f1, off);
        f2 += __shfl_xor(f2, off);
        n1 += __shfl_xor(n1, off);
        n2 += __shfl_xor(n2, off);
    }
    __shared__ double swd[BS / 64][4];
    __shared__ int swn[BS / 64][2];
    if (lane == 0) {
        swd[wid][0] = l1; swd[wid][1] = l2; swd[wid][2] = f1; swd[wid][3] = f2;
        swn[wid][0] = n1; swn[wid][1] = n2;
    }
    __syncthreads();
    if (tid == 0) {
        double a0 = 0, a1 = 0, a2 = 0, a3 = 0; int b0 = 0, b1 = 0;
        for (int wv = 0; wv < BS / 64; wv++) {
            a0 += swd[wv][0]; a1 += swd[wv][1]; a2 += swd[wv][2]; a3 += swd[wv][3];
            b0 += swn[wv][0]; b1 += swn[wv][1];
        }
        int blk = blockIdx.y * gridDim.x + blockIdx.x;
        partials[(size_t)blk * 6 + 0] = a0;
        partials[(size_t)blk * 6 + 1] = a1;
        partials[(size_t)blk * 6 + 2] = a2;
        partials[(size_t)blk * 6 + 3] = a3;
        partials[(size_t)blk * 6 + 4] = (double)b0;
        partials[(size_t)blk * 6 + 5] = (double)b1;
    }
}

// ---------------- K5: final reduction + loss assembly ----------------
__global__ void k_final(const double* __restrict__ partials, int nPart, float* __restrict__ out) {
    int tid = threadIdx.x;
    double a[6] = {0, 0, 0, 0, 0, 0};
    for (int k = tid; k < nPart; k += BS) {
#pragma unroll
        for (int j = 0; j < 6; j++) a[j] += partials[(size_t)k * 6 + j];
    }
    __shared__ double sd[BS * 6];
#pragma unroll
    for (int j = 0; j < 6; j++) sd[tid * 6 + j] = a[j];
    __syncthreads();
    for (int s = BS / 2; s > 0; s >>= 1) {
        if (tid < s) {
#pragma unroll
            for (int j = 0; j < 6; j++) sd[tid * 6 + j] += sd[(tid + s) * 6 + j];
        }
        __syncthreads();
    }
    if (tid == 0) {
        double L1 = sd[0], L2 = sd[1], F1 = sd[2], F2 = sd[3], N1 = sd[4], N2 = sd[5];
        double l1v = L1 / fmax(N1, 1.0), l2v = L2 / fmax(N2, 1.0);
        double f1v = F1 / fmax(N1, 1.0), f2v = F2 / fmax(N2, 1.0);
        double locl = (N1 > 0 ? l1v : 0.0) + (N2 > 0 ? l2v : 0.0);
        double clsl = (N1 > 0 ? f1v : 0.0) + (N2 > 0 ? f2v : 0.0);
        if (N1 == 0 && N2 == 0) { locl = 1e-4; clsl = 1e-4; }
        out[0] = (float)locl;
        out[1] = (float)clsl;
    }
}

extern "C" void kernel_launch(void* const* d_in, const int* in_sizes, int n_in,
                              void* d_out, int out_size, void* d_ws, size_t ws_size,
                              hipStream_t stream) {
    const float* targets = (const float*)d_in[3];
    const float* conf = (const float*)d_in[1];
    const float4* loc4 = (const float4*)d_in[0];
    const float4* priors4 = (const float4*)d_in[2];

    int P = in_sizes[2] / 4;
    int B = in_sizes[0] / (P * 4);
    int N = in_sizes[3] / (B * 5);
    int C = in_sizes[1] / (B * P);
    const int CAP = 2048;
    size_t BP = (size_t)B * P;

    unsigned char* ws = (unsigned char*)d_ws;
    size_t off = 0;
    auto alloc = [&](size_t bytes) { size_t cur = off; off += (bytes + 255) & ~(size_t)255; return cur; };
    float* recs = (float*)(ws + alloc(BP * 16));      // packed {bt_score, btcb, cb_idx2, c_score}
    float* part_max = (float*)(ws + alloc((size_t)B * N * NSPLIT * 4));
    int* part_arg = (int*)(ws + alloc((size_t)B * N * NSPLIT * 4));
    float* tk_s = (float*)(ws + alloc((size_t)B * N * KTOP_ * 4));
    int* tk_i = (int*)(ws + alloc((size_t)B * N * KTOP_ * 4));
    float* cand_v = (float*)(ws + alloc((size_t)B * N * CAP * 4));
    int* cand_i = (int*)(ws + alloc((size_t)B * N * CAP * 4));
    int* cand_cnt = (int*)(ws + alloc((size_t)B * N * 4));
    int bx = (P + BS - 1) / BS;
    double* partials = (double*)(ws + alloc((size_t)bx * B * 6 * 8));
    float* out = (float*)d_out;

    hipMemsetAsync(cand_cnt, 0, (size_t)B * N * 4, stream);

    int bxPP = (P + BSK * ILP - 1) / (BSK * ILP);          // per-prior blocks per image
    int ngroup = (N + 3) / 4;
    int bxRM = NSPLIT * ngroup;                            // row-max blocks per image
    k_fat1<<<dim3(bxPP + bxRM, B), BSK, 0, stream>>>(loc4, priors4, targets, (float4*)recs,
                                                     cand_v, cand_i, cand_cnt,
                                                     part_max, part_arg, P, N, CAP, bxPP);

    int maskWords = (P + 31) / 32;
    size_t shmem = (size_t)maskWords * 4;
    k_fat2<<<dim3(N + 1, B), BS, shmem, stream>>>(loc4, priors4, targets,
                                                  cand_v, cand_i, cand_cnt, tk_s, tk_i,
                                                  part_max, part_arg, recs, P, N, CAP);

    k_assign<<<dim3(B), BS, 0, stream>>>(targets, tk_s, tk_i, recs, P, N);
    k_loss<<<dim3(bx, B), BS, 0, stream>>>(loc4, conf, priors4, targets, (const float4*)recs,
                                           partials, P, N, C);
    k_final<<<1, BS, 0, stream>>>(partials, bx * B, out);
}